// Round 10
// baseline (1150.960 us; speedup 1.0000x reference)
//
#include <hip/hip_runtime.h>
#include <math.h>
#include <cstdio>
#include <cstdint>

typedef unsigned short u16;
typedef __attribute__((ext_vector_type(8))) short bfrag;   // 8 bf16 (MFMA A/B operand)
typedef __attribute__((ext_vector_type(4))) float ffrag;   // MFMA C/D

#define IMGPIX 50176      // 224*224
#define MTOT   401408     // 8*IMGPIX
#define BAND   6272       // 28*224 (one pool row-band per batch)
#define TT     86
#define EPSV   1e-5f

__device__ __forceinline__ float b2f(u16 v) {
  union { unsigned u; float f; } x; x.u = ((unsigned)v) << 16; return x.f;
}
__device__ __forceinline__ u16 f2b(float f) {
  union { float f; unsigned u; } x; x.f = f;
  unsigned r = (x.u + 0x7FFFu + ((x.u >> 16) & 1u)) >> 16;
  return (u16)r;
}

typedef const unsigned int __attribute__((address_space(1)))* as1cu32;
typedef unsigned int __attribute__((address_space(3)))* as3u32;

__device__ __forceinline__ void async16(const u16* g, u16* l) {
  __builtin_amdgcn_global_load_lds((as1cu32)g, (as3u32)l, 16, 0, 0);
}

// swizzled fragment read from LDS tile with row stride 64 u16
#define RD(buf, r, ks) (*(const bfrag*)&(buf)[(r)*64 + ((((ks)*4 + (lane>>4)) ^ ((r)&7)) << 3)])

// ---------------- conv1: direct 3->32 (fp32 in), bf16 NHWC out + fused stats --
__global__ __launch_bounds__(256) void k_conv1(const float* __restrict__ img,
    const float* __restrict__ w, u16* __restrict__ X1, float* __restrict__ st)
{
  int blk = blockIdx.x;
  int b = blk / 196, tile = blk % 196;
  int ty0 = (tile / 14) * 16, tx0 = (tile % 14) * 16;
  __shared__ float timg[3][18][18];
  __shared__ float tw[32][27];
  int tid = threadIdx.x;
  for (int i = tid; i < 864; i += 256) tw[i / 27][i % 27] = w[i];
  for (int i = tid; i < 972; i += 256) {
    int c = i / 324, rem = i % 324, yy = rem / 18, xx = rem % 18;
    int y = ty0 + yy - 1, x = tx0 + xx - 1;
    float v = 0.f;
    if ((unsigned)y < 224u && (unsigned)x < 224u)
      v = img[((size_t)(b * 3 + c) * 224 + y) * 224 + x];
    timg[c][yy][xx] = v;
  }
  __syncthreads();
  int ly = tid / 16, lx = tid % 16;
  float acc[32];
  #pragma unroll
  for (int o = 0; o < 32; o++) acc[o] = 0.f;
  #pragma unroll
  for (int c = 0; c < 3; c++)
    #pragma unroll
    for (int ky = 0; ky < 3; ky++)
      #pragma unroll
      for (int kx = 0; kx < 3; kx++) {
        float t = timg[c][ly + ky][lx + kx];
        int tap = c * 9 + ky * 3 + kx;
        #pragma unroll
        for (int o = 0; o < 32; o++) acc[o] += t * tw[o][tap];
      }
  int m = b * IMGPIX + (ty0 + ly) * 224 + (tx0 + lx);
  uint4* dst = (uint4*)(X1 + (size_t)m * 32);
  #pragma unroll
  for (int q = 0; q < 4; q++) {
    uint4 pk;
    pk.x = (unsigned)f2b(acc[q*8+0]) | ((unsigned)f2b(acc[q*8+1]) << 16);
    pk.y = (unsigned)f2b(acc[q*8+2]) | ((unsigned)f2b(acc[q*8+3]) << 16);
    pk.z = (unsigned)f2b(acc[q*8+4]) | ((unsigned)f2b(acc[q*8+5]) << 16);
    pk.w = (unsigned)f2b(acc[q*8+6]) | ((unsigned)f2b(acc[q*8+7]) << 16);
    dst[q] = pk;
  }
  __syncthreads();
  float* red = &timg[0][0][0];
  int wave = tid >> 6, lane = tid & 63;
  #pragma unroll
  for (int c = 0; c < 32; c++) {
    float s = acc[c], q = acc[c] * acc[c];
    #pragma unroll
    for (int o2 = 1; o2 < 64; o2 <<= 1) { s += __shfl_xor(s, o2, 64); q += __shfl_xor(q, o2, 64); }
    if (lane == 0) { red[wave * 64 + c] = s; red[wave * 64 + 32 + c] = q; }
  }
  __syncthreads();
  if (tid < 32) {
    float s = red[tid] + red[64 + tid] + red[128 + tid] + red[192 + tid];
    float q = red[32 + tid] + red[96 + tid] + red[160 + tid] + red[224 + tid];
    int slot = blockIdx.x & 7;
    atomicAdd(&st[slot * 64 + tid], s);
    atomicAdd(&st[slot * 64 + 32 + tid], q);
  }
}

// ---------------- finalize bn scale/shift from 8-slot stats ----------------
__global__ void k_bnfin(const float* __restrict__ st, const float* __restrict__ g,
                        const float* __restrict__ beta, float* __restrict__ sc,
                        float* __restrict__ sh, int C, float invN)
{
  int c = threadIdx.x;
  if (c >= C) return;
  float s = 0.f, q = 0.f;
  for (int k = 0; k < 8; k++) { s += st[k * 2 * C + c]; q += st[k * 2 * C + C + c]; }
  float mean = s * invN;
  float var = fmaxf(q * invN - mean * mean, 0.f);
  float sv = g[c] / sqrtf(var + EPSV);
  sc[c] = sv;
  sh[c] = beta[c] - mean * sv;
}

// ---------------- in-place bn+relu normalize of bf16 NHWC ----------------
template<int C>
__global__ __launch_bounds__(256) void k_norm(u16* __restrict__ X,
    const float* __restrict__ sc, const float* __restrict__ sh)
{
  size_t i = (size_t)blockIdx.x * 256 + threadIdx.x;   // unit = 8 elems
  size_t tot = (size_t)MTOT * C / 8;
  if (i >= tot) return;
  uint4 v = ((uint4*)X)[i];
  int c0 = (int)((i * 8) % C);
  u16* e = (u16*)&v;
  #pragma unroll
  for (int k = 0; k < 8; k++) {
    float f = b2f(e[k]) * sc[c0 + k] + sh[c0 + k];
    e[k] = f2b(fmaxf(f, 0.f));
  }
  ((uint4*)X)[i] = v;
}

// ---------------- weight reorder: w[oc][ic][ky][kx] f32 -> wr[oc][tap][ic] bf16
__global__ void k_wreord(const float* __restrict__ w, u16* __restrict__ wr, int COUT, int CIN)
{
  int i = blockIdx.x * 256 + threadIdx.x;
  int tot = COUT * CIN * 9;
  if (i >= tot) return;
  int rem = i % (CIN * 9);
  int oc = i / (CIN * 9);
  int tap = rem / CIN, ic = rem % CIN;
  wr[i] = f2b(w[(oc * CIN + ic) * 9 + tap]);
}

// ---------------- halo implicit-GEMM conv (bf16 MFMA) ----------------
template<int CIN, int COUT, int BN, int WGN, int TY, int TX, int STATS, int STORE>
__global__ __launch_bounds__(256) void k_convhalo(
    const u16* __restrict__ Xin, const u16* __restrict__ wr,
    u16* __restrict__ Xout, const u16* __restrict__ zbuf, float* __restrict__ st)
{
  constexpr int CRA = CIN / 8;
  constexpr int BM  = (4 / WGN) * 64;
  constexpr int HX  = TX + 2, HY = TY + 2;
  constexpr int HPIX = HX * HY;
  constexpr int HITER = (HPIX * CRA + 255) / 256;
  constexpr int HP  = HITER * 256 / CRA;
  constexpr int IB  = BN * CRA / 256;
  constexpr int NT  = COUT / BN;
  constexpr int TGX = 224 / TX, TGY = 224 / TY;

  __shared__ u16 Ah[HP * CIN];
  __shared__ u16 Bs[2][BN * CIN];

  const int tid = threadIdx.x;
  const int lane = tid & 63, wave = tid >> 6;
  const int nt = blockIdx.x % NT, mt = blockIdx.x / NT;
  const int b = mt / (TGX * TGY);
  const int tr = mt % (TGX * TGY);
  const int ty0 = (tr / TGX) * TY, tx0 = (tr % TGX) * TX;
  const int n0 = nt * BN;

  #pragma unroll
  for (int it = 0; it < HITER; it++) {
    int c = (wave * HITER + it) * 64 + lane;
    int pix = c / CRA, s = c % CRA;
    int hy = pix / HX, hx = pix % HX;
    int y = ty0 + hy - 1, x = tx0 + hx - 1;
    int swz = (CRA == 8) ? (pix & 7) : ((pix >> 1) & 3);
    const u16* g = (pix < HPIX && (unsigned)y < 224u && (unsigned)x < 224u)
        ? (Xin + ((size_t)(b * IMGPIX + y * 224 + x)) * CIN + ((s ^ swz) << 3))
        : zbuf;
    async16(g, &Ah[(size_t)c * 8]);
  }
  #pragma unroll
  for (int i = 0; i < IB; i++) {
    int c = (wave * IB + i) * 64 + lane;
    int row = c / CRA, s = c % CRA;
    int swz = (CRA == 8) ? (row & 7) : ((row >> 1) & 3);
    async16(wr + ((size_t)(n0 + row) * 9 + 0) * CIN + ((s ^ swz) << 3),
            &Bs[0][(size_t)c * 8]);
  }
  __syncthreads();

  const int wm = (wave / WGN) * 64;
  const int wn = (wave % WGN) * 64;
  int hbase[4];
  #pragma unroll
  for (int i = 0; i < 4; i++) {
    int row = wm + i * 16 + (lane & 15);
    hbase[i] = ((row / TX) + 1) * HX + (row % TX) + 1;
  }

  ffrag acc[4][4];
  #pragma unroll
  for (int i = 0; i < 4; i++)
    #pragma unroll
    for (int j = 0; j < 4; j++)
      #pragma unroll
      for (int e = 0; e < 4; e++) acc[i][j][e] = 0.f;

  for (int tap = 0; tap < 9; tap++) {
    if (tap < 8) {
      #pragma unroll
      for (int i = 0; i < IB; i++) {
        int c = (wave * IB + i) * 64 + lane;
        int row = c / CRA, s = c % CRA;
        int swz = (CRA == 8) ? (row & 7) : ((row >> 1) & 3);
        async16(wr + ((size_t)(n0 + row) * 9 + tap + 1) * CIN + ((s ^ swz) << 3),
                &Bs[(tap + 1) & 1][(size_t)c * 8]);
      }
    }
    const int doff = (tap / 3 - 1) * HX + (tap % 3 - 1);
    const u16* bb = Bs[tap & 1];
    #pragma unroll
    for (int ks = 0; ks < CIN / 32; ks++) {
      const int sub = ks * 4 + (lane >> 4);
      bfrag af[4], bfr[4];
      #pragma unroll
      for (int i = 0; i < 4; i++) {
        int hp = hbase[i] + doff;
        int swz = (CRA == 8) ? (hp & 7) : ((hp >> 1) & 3);
        af[i] = *(const bfrag*)&Ah[hp * CIN + ((sub ^ swz) << 3)];
      }
      #pragma unroll
      for (int j = 0; j < 4; j++) {
        int r = wn + j * 16 + (lane & 15);
        int swz = (CRA == 8) ? (r & 7) : ((r >> 1) & 3);
        bfr[j] = *(const bfrag*)&bb[r * CIN + ((sub ^ swz) << 3)];
      }
      #pragma unroll
      for (int i = 0; i < 4; i++)
        #pragma unroll
        for (int j = 0; j < 4; j++)
          acc[i][j] = __builtin_amdgcn_mfma_f32_16x16x32_bf16(af[i], bfr[j], acc[i][j], 0, 0, 0);
    }
    __syncthreads();
  }

  if (STORE) {
    #pragma unroll
    for (int i = 0; i < 4; i++)
      #pragma unroll
      for (int r = 0; r < 4; r++) {
        int row = wm + i * 16 + (lane >> 4) * 4 + r;
        int m = b * IMGPIX + (ty0 + row / TX) * 224 + tx0 + row % TX;
        u16* orow = Xout + (size_t)m * COUT + n0 + wn + (lane & 15);
        #pragma unroll
        for (int j = 0; j < 4; j++) orow[j * 16] = f2b(acc[i][j][r]);
      }
  }

  if (STATS) {
    float s[4], q[4];
    #pragma unroll
    for (int j = 0; j < 4; j++) {
      s[j] = 0.f; q[j] = 0.f;
      #pragma unroll
      for (int i = 0; i < 4; i++)
        #pragma unroll
        for (int r = 0; r < 4; r++) { float v = acc[i][j][r]; s[j] += v; q[j] += v * v; }
    }
    #pragma unroll
    for (int j = 0; j < 4; j++)
      #pragma unroll
      for (int o2 = 16; o2 < 64; o2 <<= 1) {
        s[j] += __shfl_xor(s[j], o2, 64);
        q[j] += __shfl_xor(q[j], o2, 64);
      }
    float* red = (float*)Ah;
    if (lane < 16) {
      #pragma unroll
      for (int j = 0; j < 4; j++) {
        red[(wave * 2 + 0) * 64 + j * 16 + lane] = s[j];
        red[(wave * 2 + 1) * 64 + j * 16 + lane] = q[j];
      }
    }
    __syncthreads();
    int slot = blockIdx.x & 7;
    for (int c = tid; c < BN; c += 256) {
      int grp = c >> 6, idx = c & 63;
      float ss = 0.f, qq = 0.f;
      for (int w = grp; w < 4; w += WGN) {
        ss += red[(w * 2 + 0) * 64 + idx];
        qq += red[(w * 2 + 1) * 64 + idx];
      }
      atomicAdd(&st[slot * 2 * COUT + n0 + c], ss);
      atomicAdd(&st[slot * 2 * COUT + COUT + n0 + c], qq);
    }
  }
}

// ---------------- legacy implicit-GEMM conv (plan-T chunked passes only) ------
template<int CIN, int COUT, int BM, int BN, int WGN, int STATS, int STORE, int CHUNK>
__global__ __launch_bounds__(256) void k_convgemm(
    const u16* __restrict__ Xin, const u16* __restrict__ wr,
    u16* __restrict__ Xout, const u16* __restrict__ zbuf,
    float* __restrict__ st, int cy)
{
  constexpr int CRA = CIN / 8;
  constexpr int IA  = BM * CRA / 256;
  constexpr int IB  = BN * CRA / 256;
  constexpr int NT  = COUT / BN;

  __shared__ u16 As[BM * CIN];
  __shared__ u16 Bs[BN * CIN];

  const int tid = threadIdx.x;
  const int lane = tid & 63, wave = tid >> 6;
  const int nt = blockIdx.x % NT, mt = blockIdx.x / NT;
  const int m0 = mt * BM, n0 = nt * BN;

  int am[IA], ay[IA], ax[IA], asub[IA];
  #pragma unroll
  for (int i = 0; i < IA; i++) {
    int c = (wave * IA + i) * 64 + lane;
    int row = c / CRA, s = c % CRA;
    int swz = ((CRA == 8) ? row : (row >> 1)) & (CRA - 1);
    asub[i] = s ^ swz;
    int ml = m0 + row;
    int b, y, x;
    if (CHUNK) {
      b = ml / BAND; int rem = ml % BAND;
      y = cy * 28 + rem / 224; x = rem % 224;
    } else {
      b = ml / IMGPIX; int rem = ml % IMGPIX;
      y = rem / 224; x = rem % 224;
    }
    am[i] = b * IMGPIX + y * 224 + x;
    ay[i] = y; ax[i] = x;
  }
  int bn_[IB], bsub[IB];
  #pragma unroll
  for (int i = 0; i < IB; i++) {
    int c = (wave * IB + i) * 64 + lane;
    int row = c / CRA, s = c % CRA;
    int swz = ((CRA == 8) ? row : (row >> 1)) & (CRA - 1);
    bn_[i] = n0 + row;
    bsub[i] = s ^ swz;
  }

  ffrag acc[4][4];
  #pragma unroll
  for (int i = 0; i < 4; i++)
    #pragma unroll
    for (int j = 0; j < 4; j++)
      #pragma unroll
      for (int e = 0; e < 4; e++) acc[i][j][e] = 0.f;

  const int wm = (wave / WGN) * 64;
  const int wn = (wave % WGN) * 64;

  for (int tap = 0; tap < 9; tap++) {
    const int dy = tap / 3 - 1, dx = tap % 3 - 1;
    const int doff = dy * 224 + dx;
    #pragma unroll
    for (int i = 0; i < IA; i++) {
      unsigned yy = (unsigned)(ay[i] + dy), xx = (unsigned)(ax[i] + dx);
      const u16* g = (yy < 224u && xx < 224u)
          ? (Xin + (size_t)(am[i] + doff) * CIN + asub[i] * 8)
          : zbuf;
      async16(g, &As[(size_t)((wave * IA + i) * 64 + lane) * 8]);
    }
    #pragma unroll
    for (int i = 0; i < IB; i++) {
      const u16* g = wr + ((size_t)bn_[i] * 9 + tap) * CIN + bsub[i] * 8;
      async16(g, &Bs[(size_t)((wave * IB + i) * 64 + lane) * 8]);
    }
    __syncthreads();
    #pragma unroll
    for (int ks = 0; ks < CIN / 32; ks++) {
      bfrag af[4], bfr[4];
      #pragma unroll
      for (int i = 0; i < 4; i++) {
        int r = wm + i * 16 + (lane & 15);
        int sub = ks * 4 + (lane >> 4);
        int swz = ((CRA == 8) ? r : (r >> 1)) & (CRA - 1);
        af[i] = *(const bfrag*)&As[r * CIN + (sub ^ swz) * 8];
      }
      #pragma unroll
      for (int j = 0; j < 4; j++) {
        int r = wn + j * 16 + (lane & 15);
        int sub = ks * 4 + (lane >> 4);
        int swz = ((CRA == 8) ? r : (r >> 1)) & (CRA - 1);
        bfr[j] = *(const bfrag*)&Bs[r * CIN + (sub ^ swz) * 8];
      }
      #pragma unroll
      for (int i = 0; i < 4; i++)
        #pragma unroll
        for (int j = 0; j < 4; j++)
          acc[i][j] = __builtin_amdgcn_mfma_f32_16x16x32_bf16(af[i], bfr[j], acc[i][j], 0, 0, 0);
    }
    __syncthreads();
  }

  if (STORE) {
    #pragma unroll
    for (int i = 0; i < 4; i++)
      #pragma unroll
      for (int r = 0; r < 4; r++) {
        int m = m0 + wm + i * 16 + (lane >> 4) * 4 + r;
        u16* orow = Xout + (size_t)m * COUT + n0 + wn + (lane & 15);
        #pragma unroll
        for (int j = 0; j < 4; j++) orow[j * 16] = f2b(acc[i][j][r]);
      }
  }

  if (STATS) {
    float s[4], q[4];
    #pragma unroll
    for (int j = 0; j < 4; j++) {
      s[j] = 0.f; q[j] = 0.f;
      #pragma unroll
      for (int i = 0; i < 4; i++)
        #pragma unroll
        for (int r = 0; r < 4; r++) { float v = acc[i][j][r]; s[j] += v; q[j] += v * v; }
    }
    #pragma unroll
    for (int j = 0; j < 4; j++)
      #pragma unroll
      for (int o2 = 16; o2 < 64; o2 <<= 1) {
        s[j] += __shfl_xor(s[j], o2, 64);
        q[j] += __shfl_xor(q[j], o2, 64);
      }
    float* red = (float*)As;
    if (lane < 16) {
      #pragma unroll
      for (int j = 0; j < 4; j++) {
        red[(wave * 2 + 0) * 64 + j * 16 + lane] = s[j];
        red[(wave * 2 + 1) * 64 + j * 16 + lane] = q[j];
      }
    }
    __syncthreads();
    int slot = blockIdx.x & 7;
    for (int c = tid; c < BN; c += 256) {
      int grp = c >> 6, idx = c & 63;
      float ss = 0.f, qq = 0.f;
      for (int w = grp; w < 4; w += WGN) {
        ss += red[(w * 2 + 0) * 64 + idx];
        qq += red[(w * 2 + 1) * 64 + idx];
      }
      atomicAdd(&st[slot * 2 * COUT + n0 + c], ss);
      atomicAdd(&st[slot * 2 * COUT + COUT + n0 + c], qq);
    }
  }
}

// ---------------- SPP pool (vectorized): bn3+relu then 8x8 cell sums ----------
template<int CHUNK>
__global__ __launch_bounds__(256) void k_pool2(const u16* __restrict__ X3,
    const float* __restrict__ sc, const float* __restrict__ sh,
    float* __restrict__ grid8, int cy_arg)
{
  int b, cy, cx;
  if (CHUNK) { b = blockIdx.x >> 3; cy = cy_arg; cx = blockIdx.x & 7; }
  else { b = blockIdx.x >> 6; cy = (blockIdx.x >> 3) & 7; cx = blockIdx.x & 7; }
  const int tid = threadIdx.x;
  const int cslot = tid & 31, prow = tid >> 5;
  const int ch = cslot * 8;
  float s[8], hh[8], acc[8];
  #pragma unroll
  for (int e = 0; e < 8; e++) { s[e] = sc[ch + e]; hh[e] = sh[ch + e]; acc[e] = 0.f; }
  for (int yy = prow; yy < 28; yy += 8) {
    size_t pix;
    if (CHUNK) pix = (size_t)b * BAND + (size_t)yy * 224 + cx * 28;
    else       pix = (size_t)b * IMGPIX + (size_t)(cy * 28 + yy) * 224 + cx * 28;
    for (int xx = 0; xx < 28; xx++) {
      uint4 v = *(const uint4*)&X3[(pix + xx) * 256 + ch];
      u16* e = (u16*)&v;
      #pragma unroll
      for (int k = 0; k < 8; k++)
        acc[k] += fmaxf(b2f(e[k]) * s[k] + hh[k], 0.f);
    }
  }
  __shared__ float red[8][256];
  #pragma unroll
  for (int e = 0; e < 8; e++) red[prow][ch + e] = acc[e];
  __syncthreads();
  float t = 0.f;
  #pragma unroll
  for (int p = 0; p < 8; p++) t += red[p][tid];
  grid8[(size_t)((b * 8 + cy) * 8 + cx) * 256 + tid] = t;
}

// ---------------- build tokens x[8][86][256] (fp32 + bf16) ----------------
__global__ __launch_bounds__(256) void k_tokens(const float* __restrict__ grid8,
    const float* __restrict__ cls, float* __restrict__ x, u16* __restrict__ xb)
{
  int b = blockIdx.x / 86, t = blockIdx.x % 86, d = threadIdx.x;
  float v;
  if (t == 0) v = cls[d];
  else {
    int u = t - 1, l;
    if (u < 1) { l = 1; }
    else if (u < 5) { u -= 1; l = 2; }
    else if (u < 21) { u -= 5; l = 4; }
    else { u -= 21; l = 8; }
    int i = u / l, j = u % l, span = 8 / l;
    float s = 0.f;
    for (int cy = i * span; cy < (i + 1) * span; cy++)
      for (int cx = j * span; cx < (j + 1) * span; cx++)
        s += grid8[(size_t)((b * 8 + cy) * 8 + cx) * 256 + d];
    v = s / (float)(span * span * 784);
  }
  size_t o = ((size_t)b * 86 + t) * 256 + d;
  x[o] = v;
  xb[o] = f2b(v);
}

// ---------------- one-time weight prep (tiled, coalesced transpose) ----------
__global__ __launch_bounds__(256) void k_trans2(const float* __restrict__ src,
    u16* __restrict__ dst, int K, int N, size_t sStride, size_t dStride,
    int tilesK, int tilesN)
{
  const int tpm = tilesK * tilesN;
  const int mat = blockIdx.x / tpm;
  const int t = blockIdx.x % tpm;
  const int k0 = (t % tilesK) * 64, n0 = (t / tilesK) * 64;
  const float* s = src + (size_t)mat * sStride;
  u16* d = dst + (size_t)mat * dStride;
  __shared__ u16 tile[64][65];
  const int tid = threadIdx.x;
  const int col = tid & 63, rowb = tid >> 6;
  #pragma unroll
  for (int r = 0; r < 16; r++) {
    int kk = r * 4 + rowb;
    tile[kk][col] = f2b(s[(size_t)(k0 + kk) * N + n0 + col]);
  }
  __syncthreads();
  #pragma unroll
  for (int r = 0; r < 16; r++) {
    int nn = r * 4 + rowb;
    d[(size_t)(n0 + nn) * K + k0 + col] = tile[col][nn];
  }
}

__global__ void k_cvt(const float* __restrict__ src, u16* __restrict__ dst, int n)
{
  int i = blockIdx.x * 256 + threadIdx.x;
  if (i < n) dst[i] = f2b(src[i]);
}

// ---------------- fused QKV + relative attention per (b,h) ----------------
// phase a computes Q|K|V (N=192) in one GEMM with reg-prefetch pipelined
// staging; V kept in registers, written as V^T after Qs dies (post phase d).
__global__ __launch_bounds__(256) void k_qkvattn(
    const u16* __restrict__ xbf, const u16* __restrict__ wqkv,
    const u16* __restrict__ relb, const float* __restrict__ bq,
    const float* __restrict__ bk, const float* __restrict__ bv,
    const u16* __restrict__ zbuf, u16* __restrict__ Obb)
{
  const int bh = blockIdx.x, b = bh >> 3, h = bh & 7;
  const int tid = threadIdx.x, lane = tid & 63, wave = tid >> 6;
  __shared__ float S[9600];
  __shared__ u16 Qs[96 * 64];
  __shared__ u16 Ks[96 * 64];
  u16* Ast = (u16*)S;                 // 96*64 u16
  u16* Bst = (u16*)S + 96 * 64;       // 192*64 u16
  const u16* wblk = wqkv + (size_t)h * 3 * 64 * 256;
  const u16* relh = relb + (size_t)h * TT * 64;
  const int wm = (wave >> 1) * 48;
  const int wnA = (wave & 1) * 96;

  for (int i = tid; i < 640; i += 256) { Qs[86 * 64 + i] = 0; Ks[86 * 64 + i] = 0; }

  // ---- phase a: [Q|K|V] = x @ W (M=96, N=192, K=256), pipelined staging ----
  ffrag accA[3][6];
  #pragma unroll
  for (int i = 0; i < 3; i++)
    #pragma unroll
    for (int j = 0; j < 6; j++)
      #pragma unroll
      for (int e = 0; e < 4; e++) accA[i][j][e] = 0.f;
  {
    const int arow[3] = { (tid + 0) >> 3, (tid + 256) >> 3, (tid + 512) >> 3 };
    const int asub = tid & 7;
    uint4 pa[3], pb[6];
    #pragma unroll
    for (int i = 0; i < 3; i++)
      pa[i] = (arow[i] < TT)
          ? *(const uint4*)&xbf[((size_t)(b * TT + arow[i])) * 256 + asub * 8]
          : make_uint4(0, 0, 0, 0);
    #pragma unroll
    for (int i = 0; i < 6; i++) {
      int c = tid + i * 256; int row = c >> 3, sub = c & 7;
      pb[i] = *(const uint4*)&wblk[(size_t)row * 256 + sub * 8];
    }
    for (int kc = 0; kc < 4; kc++) {
      #pragma unroll
      for (int i = 0; i < 3; i++) {
        int c = tid + i * 256; int row = c >> 3, sub = c & 7;
        *(uint4*)&Ast[row * 64 + ((sub ^ (row & 7)) << 3)] = pa[i];
      }
      #pragma unroll
      for (int i = 0; i < 6; i++) {
        int c = tid + i * 256; int row = c >> 3, sub = c & 7;
        *(uint4*)&Bst[row * 64 + ((sub ^ (row & 7)) << 3)] = pb[i];
      }
      __syncthreads();
      if (kc < 3) {
        #pragma unroll
        for (int i = 0; i < 3; i++)
          pa[i] = (arow[i] < TT)
              ? *(const uint4*)&xbf[((size_t)(b * TT + arow[i])) * 256 + (kc + 1) * 64 + asub * 8]
              : make_uint4(0, 0, 0, 0);
        #pragma unroll
        for (int i = 0; i < 6; i++) {
          int c = tid + i * 256; int row = c >> 3, sub = c & 7;
          pb[i] = *(const uint4*)&wblk[(size_t)row * 256 + (kc + 1) * 64 + sub * 8];
        }
      }
      #pragma unroll
      for (int ks = 0; ks < 2; ks++) {
        bfrag af[3], bf[6];
        #pragma unroll
        for (int i = 0; i < 3; i++) af[i] = RD(Ast, wm + i * 16 + (lane & 15), ks);
        #pragma unroll
        for (int j = 0; j < 6; j++) bf[j] = RD(Bst, wnA + j * 16 + (lane & 15), ks);
        #pragma unroll
        for (int i = 0; i < 3; i++)
          #pragma unroll
          for (int j = 0; j < 6; j++)
            accA[i][j] = __builtin_amdgcn_mfma_f32_16x16x32_bf16(af[i], bf[j], accA[i][j], 0, 0, 0);
      }
      __syncthreads();
    }
  }
  // epilogue: Q,K (+bias) into Qs/Ks; V (cols 128..191) stays in registers
  #pragma unroll
  for (int i = 0; i < 3; i++)
    #pragma unroll
    for (int j = 0; j < 6; j++) {
      int c = wnA + j * 16 + (lane & 15);
      if (c < 128) {
        int mat = c >> 6, d = c & 63;
        float bias = mat ? bk[h * 64 + d] : bq[h * 64 + d];
        u16* dstb = mat ? Ks : Qs;
        #pragma unroll
        for (int r = 0; r < 4; r++) {
          int t = wm + i * 16 + (lane >> 4) * 4 + r;
          if (t < TT)
            dstb[t * 64 + (((d >> 3) ^ (t & 7)) << 3) + (d & 7)] = f2b(accA[i][j][r] + bias);
        }
      }
    }
  __syncthreads();

  const int wn = (wave & 1) * 48;
  // ---- phase b: QK^T in registers ----
  ffrag accQK[3][3];
  #pragma unroll
  for (int i = 0; i < 3; i++)
    #pragma unroll
    for (int j = 0; j < 3; j++)
      #pragma unroll
      for (int e = 0; e < 4; e++) accQK[i][j][e] = 0.f;
  #pragma unroll
  for (int ks = 0; ks < 2; ks++) {
    bfrag af[3], bf[3];
    #pragma unroll
    for (int i = 0; i < 3; i++) af[i] = RD(Qs, wm + i * 16 + (lane & 15), ks);
    #pragma unroll
    for (int j = 0; j < 3; j++) bf[j] = RD(Ks, wn + j * 16 + (lane & 15), ks);
    #pragma unroll
    for (int i = 0; i < 3; i++)
      #pragma unroll
      for (int j = 0; j < 3; j++)
        accQK[i][j] = __builtin_amdgcn_mfma_f32_16x16x32_bf16(af[i], bf[j], accQK[i][j], 0, 0, 0);
  }
  __syncthreads();
  // ---- phase c: stage rel over Ks (async DMA; rows>=TT read zeros) ----
  #pragma unroll
  for (int i = 0; i < 3; i++) {
    int c = tid + i * 256; int row = c >> 3, sub = c & 7;
    const u16* g = (row < TT)
        ? relh + (size_t)row * 64 + ((sub ^ (row & 7)) << 3)
        : zbuf;
    async16(g, &Ks[c * 8]);
  }
  __syncthreads();
  // ---- phase d: qrel + skew scatter into S ----
  {
    ffrag accR[3][3];
    #pragma unroll
    for (int i = 0; i < 3; i++)
      #pragma unroll
      for (int j = 0; j < 3; j++)
        #pragma unroll
        for (int e = 0; e < 4; e++) accR[i][j][e] = 0.f;
    #pragma unroll
    for (int ks = 0; ks < 2; ks++) {
      bfrag af[3], bf[3];
      #pragma unroll
      for (int i = 0; i < 3; i++) af[i] = RD(Qs, wm + i * 16 + (lane & 15), ks);
      #pragma unroll
      for (int j = 0; j < 3; j++) bf[j] = RD(Ks, wn + j * 16 + (lane & 15), ks);
      #pragma unroll
      for (int i = 0; i < 3; i++)
        #pragma unroll
        for (int j = 0; j < 3; j++)
          accR[i][j] = __builtin_amdgcn_mfma_f32_16x16x32_bf16(af[i], bf[j], accR[i][j], 0, 0, 0);
    }
    #pragma unroll
    for (int i = 0; i < 3; i++)
      #pragma unroll
      for (int j = 0; j < 3; j++)
        #pragma unroll
        for (int r = 0; r < 4; r++) {
          int t = wm + i * 16 + (lane >> 4) * 4 + r;
          int l = wn + j * 16 + (lane & 15);
          if (t < TT && l < TT) {
            int jj = t * (TT + 1) + l + 1;
            if (jj >= TT) S[(jj / TT - 1) * 100 + (jj % TT)] = accR[i][j][r];
          }
        }
    for (int t = 1 + tid; t < TT; t += 256) {
      int jj = t * (TT + 1);
      S[(jj / TT - 1) * 100 + (jj % TT)] = 0.f;
    }
  }
  __syncthreads();
  // ---- phase e: logits = (S + QK^T)/8; Qs now dead -> write V^T there ----
  #pragma unroll
  for (int i = 0; i < 3; i++)
    #pragma unroll
    for (int j = 0; j < 3; j++)
      #pragma unroll
      for (int r = 0; r < 4; r++) {
        int t = wm + i * 16 + (lane >> 4) * 4 + r;
        int s2 = wn + j * 16 + (lane & 15);
        if (t < TT && s2 < TT) {
          int o = t * 100 + s2;
          S[o] = (S[o] + accQK[i][j][r]) * 0.125f;
        }
      }
  // V^T into Qs (Vt[d][t]); stale entries at t>=TT are multiplied by P==0.
  if (wnA == 96) {
    #pragma unroll
    for (int i = 0; i < 3; i++)
      #pragma unroll
      for (int j = 2; j < 6; j++) {
        int d = (wnA + j * 16 + (lane & 15)) - 128;
        float bias = bv[h * 64 + d];
        #pragma unroll
        for (int r = 0; r < 4; r++) {
          int t = wm + i * 16 + (lane >> 4) * 4 + r;
          if (t < TT) Qs[d * 96 + t] = f2b(accA[i][j][r] + bias);
        }
      }
  }
  __syncthreads();
  // ---- softmax rows; zero pads ----
  for (int t = wave; t < TT; t += 4) {
    float v0 = S[t * 100 + lane];
    float v1 = (lane + 64 < TT) ? S[t * 100 + lane + 64] : -3.0e38f;
    float mx = fmaxf(v0, v1);
    #pragma unroll
    for (int m = 1; m < 64; m <<= 1) mx = fmaxf(mx, __shfl_xor(mx, m, 64));
    float e0 = expf(v0 - mx);
    float e1 = (lane + 64 < TT) ? expf(v1 - mx) : 0.f;
    float sm = e0 + e1;
    #pragma unroll
    for (int m = 1; m < 64; m <<= 1) sm += __shfl_xor(sm, m, 64);
    float inv = 1.f / sm;
    S[t * 100 + lane] = e0 * inv;
    if (lane + 64 < 96) S[t * 100 + lane + 64] = (lane + 64 < TT) ? e1 * inv : 0.f;
  }
  for (int idx = tid; idx < 1000; idx += 256)
    S[(86 + idx / 100) * 100 + idx % 100] = 0.f;
  __syncthreads();
  // ---- PV ----
  {
    const int wn2 = (wave & 1) * 32;
    ffrag accO[3][2];
    #pragma unroll
    for (int i = 0; i < 3; i++)
      #pragma unroll
      for (int j = 0; j < 2; j++)
        #pragma unroll
        for (int e = 0; e < 4; e++) accO[i][j][e] = 0.f;
    #pragma unroll
    for (int ks = 0; ks < 3; ks++) {
      bfrag af[3], bf[2];
      #pragma unroll
      for (int i = 0; i < 3; i++) {
        const float* sp = &S[(wm + i * 16 + (lane & 15)) * 100 + ks * 32 + (lane >> 4) * 8];
        bfrag v;
        #pragma unroll
        for (int e = 0; e < 8; e++) v[e] = (short)f2b(sp[e]);
        af[i] = v;
      }
      #pragma unroll
      for (int j = 0; j < 2; j++)
        bf[j] = *(const bfrag*)&Qs[(wn2 + j * 16 + (lane & 15)) * 96 + ks * 32 + (lane >> 4) * 8];
      #pragma unroll
      for (int i = 0; i < 3; i++)
        #pragma unroll
        for (int j = 0; j < 2; j++)
          accO[i][j] = __builtin_amdgcn_mfma_f32_16x16x32_bf16(af[i], bf[j], accO[i][j], 0, 0, 0);
    }
    #pragma unroll
    for (int i = 0; i < 3; i++)
      #pragma unroll
      for (int j = 0; j < 2; j++)
        #pragma unroll
        for (int r = 0; r < 4; r++) {
          int t = wm + i * 16 + (lane >> 4) * 4 + r;
          int d = wn2 + j * 16 + (lane & 15);
          if (t < TT)
            Obb[((size_t)(b * TT + t)) * 512 + h * 64 + d] = f2b(accO[i][j][r]);
        }
  }
}

// ---------------- proj + residual + LN (pipelined staging) ----------------
__global__ __launch_bounds__(256) void k_projln(
    const u16* __restrict__ Obb, const u16* __restrict__ Wob,
    const float* __restrict__ bo, const float* __restrict__ lg,
    const float* __restrict__ lb, float* __restrict__ xtok, u16* __restrict__ hb)
{
  const int m0 = blockIdx.x * 16;
  const int tid = threadIdx.x, lane = tid & 63, wave = tid >> 6;
  __shared__ u16 Ast[16 * 64];
  __shared__ u16 Bst[256 * 64];
  __shared__ float rowbuf[16 * 256];
  const int wn = wave * 64;
  ffrag acc[4];
  #pragma unroll
  for (int j = 0; j < 4; j++)
    #pragma unroll
    for (int e = 0; e < 4; e++) acc[j][e] = 0.f;

  uint4 pa, pb[8];
  const int arow = tid >> 3, asub = tid & 7;
  if (tid < 128) pa = *(const uint4*)&Obb[(size_t)(m0 + arow) * 512 + asub * 8];
  #pragma unroll
  for (int i = 0; i < 8; i++) {
    int c = tid + i * 256; int row = c >> 3, sub = c & 7;
    pb[i] = *(const uint4*)&Wob[(size_t)row * 512 + sub * 8];
  }
  for (int kc = 0; kc < 8; kc++) {
    if (tid < 128)
      *(uint4*)&Ast[arow * 64 + ((asub ^ (arow & 7)) << 3)] = pa;
    #pragma unroll
    for (int i = 0; i < 8; i++) {
      int c = tid + i * 256; int row = c >> 3, sub = c & 7;
      *(uint4*)&Bst[row * 64 + ((sub ^ (row & 7)) << 3)] = pb[i];
    }
    __syncthreads();
    if (kc < 7) {
      if (tid < 128)
        pa = *(const uint4*)&Obb[(size_t)(m0 + arow) * 512 + (kc + 1) * 64 + asub * 8];
      #pragma unroll
      for (int i = 0; i < 8; i++) {
        int c = tid + i * 256; int row = c >> 3, sub = c & 7;
        pb[i] = *(const uint4*)&Wob[(size_t)row * 512 + (kc + 1) * 64 + sub * 8];
      }
    }
    #pragma unroll
    for (int ks = 0; ks < 2; ks++) {
      bfrag a = RD(Ast, lane & 15, ks);
      #pragma unroll
      for (int j = 0; j < 4; j++) {
        bfrag bj = RD(Bst, wn + j * 16 + (lane & 15), ks);
        acc[j] = __builtin_amdgcn_mfma_f32_16x16x32_bf16(a, bj, acc[j], 0, 0, 0);
      }
    }
    __syncthreads();
  }
  #pragma unroll
  for (int j = 0; j < 4; j++) {
    int c = wn + j * 16 + (lane & 15);
    #pragma unroll
    for (int r = 0; r < 4; r++) {
      int t = (lane >> 4) * 4 + r;
      rowbuf[t * 256 + c] = acc[j][r] + bo[c] + xtok[(size_t)(m0 + t) * 256 + c];
    }
  }
  __syncthreads();
  for (int row = wave; row < 16; row += 4) {
    float v0 = rowbuf[row * 256 + lane];
    float v1 = rowbuf[row * 256 + 64 + lane];
    float v2 = rowbuf[row * 256 + 128 + lane];
    float v3 = rowbuf[row * 256 + 192 + lane];
    float s = v0 + v1 + v2 + v3;
    float q = v0 * v0 + v1 * v1 + v2 * v2 + v3 * v3;
    #pragma unroll
    for (int m = 1; m < 64; m <<= 1) { s += __shfl_xor(s, m, 64); q += __shfl_xor(q, m, 64); }
    float mean = s * (1.f / 256.f);
    float var = fmaxf(q * (1.f / 256.f) - mean * mean, 0.f);
    float inv = 1.f / sqrtf(var + EPSV);
    size_t base = (size_t)(m0 + row) * 256;
    float vv[4] = {v0, v1, v2, v3};
    #pragma unroll
    for (int k = 0; k < 4; k++) {
      int c = lane + 64 * k;
      xtok[base + c] = vv[k];
      hb[base + c] = f2b((vv[k] - mean) * inv * lg[c] + lb[c]);
    }
  }
}

// ---------------- MLP1: h2 = gelu(h @ W1 + b1) (pipelined staging) ------------
__global__ __launch_bounds__(256) void k_mlp1(
    const u16* __restrict__ hb, const u16* __restrict__ W1b,
    const float* __restrict__ b1, u16* __restrict__ h2b)
{
  const int m0 = blockIdx.x * 64, n0 = blockIdx.y * 128;
  const int tid = threadIdx.x, lane = tid & 63, wave = tid >> 6;
  __shared__ u16 Ast[64 * 64];
  __shared__ u16 Bst[128 * 64];
  const int wm = (wave >> 1) * 32, wn = (wave & 1) * 64;
  ffrag acc[2][4];
  #pragma unroll
  for (int i = 0; i < 2; i++)
    #pragma unroll
    for (int j = 0; j < 4; j++)
      #pragma unroll
      for (int e = 0; e < 4; e++) acc[i][j][e] = 0.f;

  uint4 pa[2], pb[4];
  #pragma unroll
  for (int i = 0; i < 2; i++) {
    int c = tid + i * 256; int row = c >> 3, sub = c & 7;
    int gm = m0 + row;
    pa[i] = (gm < 688) ? *(const uint4*)&hb[(size_t)gm * 256 + sub * 8]
                       : make_uint4(0, 0, 0, 0);
  }
  #pragma unroll
  for (int i = 0; i < 4; i++) {
    int c = tid + i * 256; int row = c >> 3, sub = c & 7;
    pb[i] = *(const uint4*)&W1b[(size_t)(n0 + row) * 256 + sub * 8];
  }
  for (int kc = 0; kc < 4; kc++) {
    #pragma unroll
    for (int i = 0; i < 2; i++) {
      int c = tid + i * 256; int row = c >> 3, sub = c & 7;
      *(uint4*)&Ast[row * 64 + ((sub ^ (row & 7)) << 3)] = pa[i];
    }
    #pragma unroll
    for (int i = 0; i < 4; i++) {
      int c = tid + i * 256; int row = c >> 3, sub = c & 7;
      *(uint4*)&Bst[row * 64 + ((sub ^ (row & 7)) << 3)] = pb[i];
    }
    __syncthreads();
    if (kc < 3) {
      #pragma unroll
      for (int i = 0; i < 2; i++) {
        int c = tid + i * 256; int row = c >> 3, sub = c & 7;
        int gm = m0 + row;
        pa[i] = (gm < 688)
            ? *(const uint4*)&hb[(size_t)gm * 256 + (kc + 1) * 64 + sub * 8]
            : make_uint4(0, 0, 0, 0);
      }
      #pragma unroll
      for (int i = 0; i < 4; i++) {
        int c = tid + i * 256; int row = c >> 3, sub = c & 7;
        pb[i] = *(const uint4*)&W1b[(size_t)(n0 + row) * 256 + (kc + 1) * 64 + sub * 8];
      }
    }
    #pragma unroll
    for (int ks = 0; ks < 2; ks++) {
      bfrag af[2], bf[4];
      #pragma unroll
      for (int i = 0; i < 2; i++) af[i] = RD(Ast, wm + i * 16 + (lane & 15), ks);
      #pragma unroll
      for (int j = 0; j < 4; j++) bf[j] = RD(Bst, wn + j * 16 + (lane & 15), ks);
      #pragma unroll
      for (int i = 0; i < 2; i++)
        #pragma unroll
        for (int j = 0; j < 4; j++)
          acc[i][j] = __builtin_amdgcn_mfma_f32_16x16x32_bf16(af[i], bf[j], acc[i][j], 0, 0, 0);
    }
    __syncthreads();
  }
  #pragma unroll
  for (int i = 0; i < 2; i++)
    #pragma unroll
    for (int j = 0; j < 4; j++) {
      int n = n0 + wn + j * 16 + (lane & 15);
      float bias = b1[n];
      #pragma unroll
      for (int r = 0; r < 4; r++) {
        int m = m0 + wm + i * 16 + (lane >> 4) * 4 + r;
        if (m < 688) {
          float v = acc[i][j][r] + bias;
          v = 0.5f * v * (1.f + erff(v * 0.7071067811865475f));
          h2b[(size_t)m * 1024 + n] = f2b(v);
        }
      }
    }
}

// ---------------- MLP2 + residual (pipelined staging) ----------------
__global__ __launch_bounds__(256) void k_mlp2(
    const u16* __restrict__ h2b, const u16* __restrict__ W2b,
    const float* __restrict__ b2, float* __restrict__ xtok, u16* __restrict__ xbf)
{
  const int m0 = blockIdx.x * 16;
  const int tid = threadIdx.x, lane = tid & 63, wave = tid >> 6;
  __shared__ u16 Ast[16 * 64];
  __shared__ u16 Bst[256 * 64];
  const int wn = wave * 64;
  ffrag acc[4];
  #pragma unroll
  for (int j = 0; j < 4; j++)
    #pragma unroll
    for (int e = 0; e < 4; e++) acc[j][e] = 0.f;

  uint4 pa, pb[8];
  const int arow = tid >> 3, asub = tid & 7;
  if (tid < 128) pa = *(const uint4*)&h2b[(size_t)(m0 + arow) * 1024 + asub * 8];
  #pragma unroll
  for (int i = 0; i < 8; i++) {
    int c = tid + i * 256; int row = c >> 3, sub = c & 7;
    pb[i] = *(const uint4*)&W2b[(size_t)row * 1024 + sub * 8];
  }
  for (int kc = 0; kc < 16; kc++) {
    if (tid < 128)
      *(uint4*)&Ast[arow * 64 + ((asub ^ (arow & 7)) << 3)] = pa;
    #pragma unroll
    for (int i = 0; i < 8; i++) {
      int c = tid + i * 256; int row = c >> 3, sub = c & 7;
      *(uint4*)&Bst[row * 64 + ((sub ^ (row & 7)) << 3)] = pb[i];
    }
    __syncthreads();
    if (kc < 15) {
      if (tid < 128)
        pa = *(const uint4*)&h2b[(size_t)(m0 + arow) * 1024 + (kc + 1) * 64 + asub * 8];
      #pragma unroll
      for (int i = 0; i < 8; i++) {
        int c = tid + i * 256; int row = c >> 3, sub = c & 7;
        pb[i] = *(const uint4*)&W2b[(size_t)row * 1024 + (kc + 1) * 64 + sub * 8];
      }
    }
    #pragma unroll
    for (int ks = 0; ks < 2; ks++) {
      bfrag a = RD(Ast, lane & 15, ks);
      #pragma unroll
      for (int j = 0; j < 4; j++) {
        bfrag bj = RD(Bst, wn + j * 16 + (lane & 15), ks);
        acc[j] = __builtin_amdgcn_mfma_f32_16x16x32_bf16(a, bj, acc[j], 0, 0, 0);
      }
    }
    __syncthreads();
  }
  #pragma unroll
  for (int j = 0; j < 4; j++) {
    int c = wn + j * 16 + (lane & 15);
    float bias = b2[c];
    #pragma unroll
    for (int r = 0; r < 4; r++) {
      int t = (lane >> 4) * 4 + r;
      size_t o = (size_t)(m0 + t) * 256 + c;
      float v = acc[j][r] + bias + xtok[o];
      xtok[o] = v;
      xbf[o] = f2b(v);
    }
  }
}

// ---------------- final LN(cls) @ Wh + bh ----------------
__global__ __launch_bounds__(256) void k_head(const float* __restrict__ x,
    const float* __restrict__ g, const float* __restrict__ bb,
    const float* __restrict__ Wh, const float* __restrict__ bh, float* __restrict__ out)
{
  int bidx = blockIdx.x >> 2, nc = blockIdx.x & 3;
  int tid = threadIdx.x;
  const float* xr = x + (size_t)bidx * TT * 256;
  float v = xr[tid];
  float s = v, q = v * v;
  #pragma unroll
  for (int m = 1; m < 64; m <<= 1) { s += __shfl_xor(s, m, 64); q += __shfl_xor(q, m, 64); }
  __shared__ float ps[4], pq[4];
  __shared__ float h[256];
  if ((tid & 63) == 0) { ps[tid >> 6] = s; pq[tid >> 6] = q; }
  __syncthreads();
  float S = ps[0] + ps[1] + ps[2] + ps[3];
  float Q = pq[0] + pq[1] + pq[2] + pq[3];
  float mean = S * (1.f / 256.f);
  float var = fmaxf(Q * (1.f / 256.f) - mean * mean, 0.f);
  float inv = 1.f / sqrtf(var + EPSV);
  h[tid] = (v - mean) * inv * g[tid] + bb[tid];
  __syncthreads();
  int n = nc * 256 + tid;
  if (n < 1000) {
    float acc = bh[n];
    for (int k = 0; k < 256; k++) acc += h[k] * Wh[(size_t)k * 1000 + n];
    out[bidx * 1000 + n] = acc;
  }
}

extern "C" void kernel_launch(void* const* d_in, const int* in_sizes, int n_in,
                              void* d_out, int out_size, void* d_ws, size_t ws_size,
                              hipStream_t stream)
{
  (void)in_sizes; (void)n_in; (void)out_size;
  const float* img     = (const float*)d_in[0];
  const float* conv1_w = (const float*)d_in[1];
  const float* bn1_g   = (const float*)d_in[3];
  const float* bn1_b   = (const float*)d_in[4];
  const float* conv2_w = (const float*)d_in[5];
  const float* bn2_g   = (const float*)d_in[7];
  const float* bn2_b   = (const float*)d_in[8];
  const float* conv3_w = (const float*)d_in[9];
  const float* bn3_g   = (const float*)d_in[11];
  const float* bn3_b   = (const float*)d_in[12];
  const float* cls     = (const float*)d_in[13];
  const float* Wq      = (const float*)d_in[14];
  const float* bq      = (const float*)d_in[15];
  const float* Wk      = (const float*)d_in[16];
  const float* bk      = (const float*)d_in[17];
  const float* Wv      = (const float*)d_in[18];
  const float* bv      = (const float*)d_in[19];
  const float* rel     = (const float*)d_in[20];
  const float* Wo      = (const float*)d_in[21];
  const float* bo      = (const float*)d_in[22];
  const float* ln_g    = (const float*)d_in[23];
  const float* ln_b    = (const float*)d_in[24];
  const float* W1      = (const float*)d_in[25];
  const float* b1      = (const float*)d_in[26];
  const float* W2      = (const float*)d_in[27];
  const float* b2      = (const float*)d_in[28];
  const float* hln_g   = (const float*)d_in[29];
  const float* hln_b   = (const float*)d_in[30];
  const float* Wh      = (const float*)d_in[31];
  const float* bhp     = (const float*)d_in[32];

  char* base = (char*)d_ws;
  size_t off = 0;
  auto alloc = [&](size_t bytes) -> void* {
    void* p = base + off;
    off = (off + bytes + 255) & ~(size_t)255;
    return p;
  };
  // ---- region A: small persistent ----
  u16* wr2 = (u16*)alloc((size_t)64 * 288 * 2);
  u16* wr3 = (u16*)alloc((size_t)256 * 576 * 2);
  float* stats = (float*)alloc(5696 * 4);
  float* st1 = stats;
  float* st2 = stats + 512;
  float* st3 = stats + 1536;
  u16* zbuf = (u16*)(stats + 5632);
  float* scsh = (float*)alloc(704 * 4);
  float* sc1 = scsh,        *sh1 = scsh + 32;
  float* sc2 = scsh + 64,   *sh2 = scsh + 128;
  float* sc3 = scsh + 192,  *sh3 = scsh + 448;
  float* grid8 = (float*)alloc((size_t)8 * 64 * 256 * 4);
  float* xtok  = (float*)alloc((size_t)688 * 256 * 4);
  u16* xbf   = (u16*)alloc((size_t)688 * 256 * 2);
  u16* hbb   = (u16*)alloc((size_t)688 * 256 * 2);
  u16* Obb   = (u16*)alloc((size_t)688 * 512 * 2);
  u16* h2b   = (u16*)alloc((size_t)688 * 1024 * 2);
  u16* relbuf= (u16*)alloc((size_t)6 * 8 * TT * 64 * 2);
  // ---- region B: X2 ----
  u16* X2  = (u16*)alloc((size_t)MTOT * 64 * 2);
  // ---- region C: X1 | X3 (or X3c) | transformer weights (lifetimes disjoint)
  size_t offC = off;
  const size_t sizeX1  = (size_t)MTOT * 32 * 2;
  const size_t sizeX3  = (size_t)MTOT * 256 * 2;
  const size_t sizeX3c = (size_t)8 * BAND * 256 * 2;
  const size_t sizeW   = (size_t)(2359296 + 786432 + 1572864 + 1572864) * 2;
  size_t cT = sizeX1 > sizeX3c ? sizeX1 : sizeX3c;
  if (cT < sizeW) cT = sizeW;
  const size_t needS = offC + sizeX3;
  const size_t needT = offC + cT;
  const bool planS = ws_size >= needS;
  u16* X1    = (u16*)(base + offC);
  u16* X3    = (u16*)(base + offC);
  u16* X3c   = (u16*)(base + offC);
  u16* Wqkvb = (u16*)(base + offC);                  // written AFTER pool (X3 dead)
  u16* Wob   = Wqkvb + (size_t)2359296;
  u16* W1b   = Wob   + (size_t)786432;
  u16* W2b   = W1b   + (size_t)1572864;
  if (ws_size < needT)
    fprintf(stderr, "ATHENA-HIP: ws too small, need %zu have %zu\n", needT, ws_size);

  (void)hipMemsetAsync(stats, 0, 5696 * 4, stream);

  // conv stem
  k_conv1<<<1568, 256, 0, stream>>>(img, conv1_w, X1, st1);
  k_bnfin<<<1, 256, 0, stream>>>(st1, bn1_g, bn1_b, sc1, sh1, 32, 1.f / (float)MTOT);
  k_norm<32><<<6272, 256, 0, stream>>>(X1, sc1, sh1);
  k_wreord<<<(64 * 288 + 255) / 256, 256, 0, stream>>>(conv2_w, wr2, 64, 32);
  k_convhalo<32, 64, 64, 1, 16, 16, 1, 1><<<1568, 256, 0, stream>>>(
      X1, wr2, X2, zbuf, st2);
  k_bnfin<<<1, 256, 0, stream>>>(st2, bn2_g, bn2_b, sc2, sh2, 64, 1.f / (float)MTOT);
  k_norm<64><<<12544, 256, 0, stream>>>(X2, sc2, sh2);
  k_wreord<<<(256 * 576 + 255) / 256, 256, 0, stream>>>(conv3_w, wr3, 256, 64);
  if (planS) {
    k_convhalo<64, 256, 128, 2, 8, 16, 1, 1><<<6272, 256, 0, stream>>>(
        X2, wr3, X3, zbuf, st3);
    k_bnfin<<<1, 256, 0, stream>>>(st3, bn3_g, bn3_b, sc3, sh3, 256, 1.f / (float)MTOT);
    k_pool2<0><<<512, 256, 0, stream>>>(X3, sc3, sh3, grid8, 0);
  } else {
    k_convhalo<64, 256, 128, 2, 8, 16, 1, 0><<<6272, 256, 0, stream>>>(
        X2, wr3, X3c, zbuf, st3);
    k_bnfin<<<1, 256, 0, stream>>>(st3, bn3_g, bn3_b, sc3, sh3, 256, 1.f / (float)MTOT);
    for (int cy = 0; cy < 8; cy++) {
      k_convgemm<64, 256, 128, 128, 2, 0, 1, 1><<<784, 256, 0, stream>>>(
          X2, wr3, X3c, zbuf, st3, cy);
      k_pool2<1><<<64, 256, 0, stream>>>(X3c, sc3, sh3, grid8, cy);
    }
  }
  k_tokens<<<688, 256, 0, stream>>>(grid8, cls, xtok, xbf);

  // weight prep AFTER pool: region C reuse (X3 dead)
  k_trans2<<<192, 256, 0, stream>>>(Wq, Wqkvb,         256, 64,  16384, 49152, 4, 1);
  k_trans2<<<192, 256, 0, stream>>>(Wk, Wqkvb + 16384, 256, 64,  16384, 49152, 4, 1);
  k_trans2<<<192, 256, 0, stream>>>(Wv, Wqkvb + 32768, 256, 64,  16384, 49152, 4, 1);
  k_trans2<<<192, 256, 0, stream>>>(Wo, Wob, 512, 256,  131072, 131072, 8, 4);
  k_trans2<<<384, 256, 0, stream>>>(W1, W1b, 256, 1024, 262144, 262144, 4, 16);
  k_trans2<<<384, 256, 0, stream>>>(W2, W2b, 1024, 256, 262144, 262144, 16, 4);
  k_cvt<<<(6 * 8 * TT * 64 + 255) / 256, 256, 0, stream>>>(rel, relbuf, 6 * 8 * TT * 64);

  // transformer
  for (int l = 0; l < 6; l++) {
    k_qkvattn<<<64, 256, 0, stream>>>(
        xbf, Wqkvb + (size_t)l * 8 * 3 * 64 * 256,
        relbuf + (size_t)l * 8 * TT * 64,
        bq + l * 512, bk + l * 512, bv + l * 512, zbuf, Obb);
    k_projln<<<43, 256, 0, stream>>>(
        Obb, Wob + (size_t)l * 131072, bo + l * 256,
        ln_g + l * 256, ln_b + l * 256, xtok, hbb);
    k_mlp1<<<dim3(11, 8), 256, 0, stream>>>(
        hbb, W1b + (size_t)l * 262144, b1 + l * 1024, h2b);
    k_mlp2<<<43, 256, 0, stream>>>(
        h2b, W2b + (size_t)l * 262144, b2 + l * 256, xtok, xbf);
  }
  k_head<<<32, 256, 0, stream>>>(xtok, hln_g, hln_b, Wh, bhp, (float*)d_out);
}

// Round 11
// 912.333 us; speedup vs baseline: 1.2616x; 1.2616x over previous
//
#include <hip/hip_runtime.h>
#include <math.h>
#include <cstdio>
#include <cstdint>

typedef unsigned short u16;
typedef __attribute__((ext_vector_type(8))) short bfrag;   // 8 bf16 (MFMA A/B operand)
typedef __attribute__((ext_vector_type(4))) float ffrag;   // MFMA C/D

#define IMGPIX 50176      // 224*224
#define MTOT   401408     // 8*IMGPIX
#define BAND   6272       // 28*224 (one pool row-band per batch)
#define TT     86
#define EPSV   1e-5f

__device__ __forceinline__ float b2f(u16 v) {
  union { unsigned u; float f; } x; x.u = ((unsigned)v) << 16; return x.f;
}
__device__ __forceinline__ u16 f2b(float f) {
  union { float f; unsigned u; } x; x.f = f;
  unsigned r = (x.u + 0x7FFFu + ((x.u >> 16) & 1u)) >> 16;
  return (u16)r;
}

typedef const unsigned int __attribute__((address_space(1)))* as1cu32;
typedef unsigned int __attribute__((address_space(3)))* as3u32;

__device__ __forceinline__ void async16(const u16* g, u16* l) {
  __builtin_amdgcn_global_load_lds((as1cu32)g, (as3u32)l, 16, 0, 0);
}

// swizzled fragment read from LDS tile with row stride 64 u16
#define RD(buf, r, ks) (*(const bfrag*)&(buf)[(r)*64 + ((((ks)*4 + (lane>>4)) ^ ((r)&7)) << 3)])

// ---------------- conv1: direct 3->32 (fp32 in), bf16 NHWC out + fused stats --
__global__ __launch_bounds__(256) void k_conv1(const float* __restrict__ img,
    const float* __restrict__ w, u16* __restrict__ X1, float* __restrict__ st)
{
  int blk = blockIdx.x;
  int b = blk / 196, tile = blk % 196;
  int ty0 = (tile / 14) * 16, tx0 = (tile % 14) * 16;
  __shared__ float timg[3][18][18];
  __shared__ float tw[32][27];
  int tid = threadIdx.x;
  for (int i = tid; i < 864; i += 256) tw[i / 27][i % 27] = w[i];
  for (int i = tid; i < 972; i += 256) {
    int c = i / 324, rem = i % 324, yy = rem / 18, xx = rem % 18;
    int y = ty0 + yy - 1, x = tx0 + xx - 1;
    float v = 0.f;
    if ((unsigned)y < 224u && (unsigned)x < 224u)
      v = img[((size_t)(b * 3 + c) * 224 + y) * 224 + x];
    timg[c][yy][xx] = v;
  }
  __syncthreads();
  int ly = tid / 16, lx = tid % 16;
  float acc[32];
  #pragma unroll
  for (int o = 0; o < 32; o++) acc[o] = 0.f;
  #pragma unroll
  for (int c = 0; c < 3; c++)
    #pragma unroll
    for (int ky = 0; ky < 3; ky++)
      #pragma unroll
      for (int kx = 0; kx < 3; kx++) {
        float t = timg[c][ly + ky][lx + kx];
        int tap = c * 9 + ky * 3 + kx;
        #pragma unroll
        for (int o = 0; o < 32; o++) acc[o] += t * tw[o][tap];
      }
  int m = b * IMGPIX + (ty0 + ly) * 224 + (tx0 + lx);
  uint4* dst = (uint4*)(X1 + (size_t)m * 32);
  #pragma unroll
  for (int q = 0; q < 4; q++) {
    uint4 pk;
    pk.x = (unsigned)f2b(acc[q*8+0]) | ((unsigned)f2b(acc[q*8+1]) << 16);
    pk.y = (unsigned)f2b(acc[q*8+2]) | ((unsigned)f2b(acc[q*8+3]) << 16);
    pk.z = (unsigned)f2b(acc[q*8+4]) | ((unsigned)f2b(acc[q*8+5]) << 16);
    pk.w = (unsigned)f2b(acc[q*8+6]) | ((unsigned)f2b(acc[q*8+7]) << 16);
    dst[q] = pk;
  }
  __syncthreads();
  float* red = &timg[0][0][0];
  int wave = tid >> 6, lane = tid & 63;
  #pragma unroll
  for (int c = 0; c < 32; c++) {
    float s = acc[c], q = acc[c] * acc[c];
    #pragma unroll
    for (int o2 = 1; o2 < 64; o2 <<= 1) { s += __shfl_xor(s, o2, 64); q += __shfl_xor(q, o2, 64); }
    if (lane == 0) { red[wave * 64 + c] = s; red[wave * 64 + 32 + c] = q; }
  }
  __syncthreads();
  if (tid < 32) {
    float s = red[tid] + red[64 + tid] + red[128 + tid] + red[192 + tid];
    float q = red[32 + tid] + red[96 + tid] + red[160 + tid] + red[224 + tid];
    int slot = blockIdx.x & 7;
    atomicAdd(&st[slot * 64 + tid], s);
    atomicAdd(&st[slot * 64 + 32 + tid], q);
  }
}

// ---------------- finalize bn scale/shift from 8-slot stats ----------------
__global__ void k_bnfin(const float* __restrict__ st, const float* __restrict__ g,
                        const float* __restrict__ beta, float* __restrict__ sc,
                        float* __restrict__ sh, int C, float invN)
{
  int c = threadIdx.x;
  if (c >= C) return;
  float s = 0.f, q = 0.f;
  for (int k = 0; k < 8; k++) { s += st[k * 2 * C + c]; q += st[k * 2 * C + C + c]; }
  float mean = s * invN;
  float var = fmaxf(q * invN - mean * mean, 0.f);
  float sv = g[c] / sqrtf(var + EPSV);
  sc[c] = sv;
  sh[c] = beta[c] - mean * sv;
}

// ---------------- in-place bn+relu normalize of bf16 NHWC ----------------
template<int C>
__global__ __launch_bounds__(256) void k_norm(u16* __restrict__ X,
    const float* __restrict__ sc, const float* __restrict__ sh)
{
  size_t i = (size_t)blockIdx.x * 256 + threadIdx.x;   // unit = 8 elems
  size_t tot = (size_t)MTOT * C / 8;
  if (i >= tot) return;
  uint4 v = ((uint4*)X)[i];
  int c0 = (int)((i * 8) % C);
  u16* e = (u16*)&v;
  #pragma unroll
  for (int k = 0; k < 8; k++) {
    float f = b2f(e[k]) * sc[c0 + k] + sh[c0 + k];
    e[k] = f2b(fmaxf(f, 0.f));
  }
  ((uint4*)X)[i] = v;
}

// ---------------- weight reorder: w[oc][ic][ky][kx] f32 -> wr[oc][tap][ic] bf16
__global__ void k_wreord(const float* __restrict__ w, u16* __restrict__ wr, int COUT, int CIN)
{
  int i = blockIdx.x * 256 + threadIdx.x;
  int tot = COUT * CIN * 9;
  if (i >= tot) return;
  int rem = i % (CIN * 9);
  int oc = i / (CIN * 9);
  int tap = rem / CIN, ic = rem % CIN;
  wr[i] = f2b(w[(oc * CIN + ic) * 9 + tap]);
}

// ---------------- halo implicit-GEMM conv (bf16 MFMA) ----------------
template<int CIN, int COUT, int BN, int WGN, int TY, int TX, int STATS, int STORE>
__global__ __launch_bounds__(256) void k_convhalo(
    const u16* __restrict__ Xin, const u16* __restrict__ wr,
    u16* __restrict__ Xout, const u16* __restrict__ zbuf, float* __restrict__ st)
{
  constexpr int CRA = CIN / 8;
  constexpr int BM  = (4 / WGN) * 64;
  constexpr int HX  = TX + 2, HY = TY + 2;
  constexpr int HPIX = HX * HY;
  constexpr int HITER = (HPIX * CRA + 255) / 256;
  constexpr int HP  = HITER * 256 / CRA;
  constexpr int IB  = BN * CRA / 256;
  constexpr int NT  = COUT / BN;
  constexpr int TGX = 224 / TX, TGY = 224 / TY;

  __shared__ u16 Ah[HP * CIN];
  __shared__ u16 Bs[2][BN * CIN];

  const int tid = threadIdx.x;
  const int lane = tid & 63, wave = tid >> 6;
  const int nt = blockIdx.x % NT, mt = blockIdx.x / NT;
  const int b = mt / (TGX * TGY);
  const int tr = mt % (TGX * TGY);
  const int ty0 = (tr / TGX) * TY, tx0 = (tr % TGX) * TX;
  const int n0 = nt * BN;

  #pragma unroll
  for (int it = 0; it < HITER; it++) {
    int c = (wave * HITER + it) * 64 + lane;
    int pix = c / CRA, s = c % CRA;
    int hy = pix / HX, hx = pix % HX;
    int y = ty0 + hy - 1, x = tx0 + hx - 1;
    int swz = (CRA == 8) ? (pix & 7) : ((pix >> 1) & 3);
    const u16* g = (pix < HPIX && (unsigned)y < 224u && (unsigned)x < 224u)
        ? (Xin + ((size_t)(b * IMGPIX + y * 224 + x)) * CIN + ((s ^ swz) << 3))
        : zbuf;
    async16(g, &Ah[(size_t)c * 8]);
  }
  #pragma unroll
  for (int i = 0; i < IB; i++) {
    int c = (wave * IB + i) * 64 + lane;
    int row = c / CRA, s = c % CRA;
    int swz = (CRA == 8) ? (row & 7) : ((row >> 1) & 3);
    async16(wr + ((size_t)(n0 + row) * 9 + 0) * CIN + ((s ^ swz) << 3),
            &Bs[0][(size_t)c * 8]);
  }
  __syncthreads();

  const int wm = (wave / WGN) * 64;
  const int wn = (wave % WGN) * 64;
  int hbase[4];
  #pragma unroll
  for (int i = 0; i < 4; i++) {
    int row = wm + i * 16 + (lane & 15);
    hbase[i] = ((row / TX) + 1) * HX + (row % TX) + 1;
  }

  ffrag acc[4][4];
  #pragma unroll
  for (int i = 0; i < 4; i++)
    #pragma unroll
    for (int j = 0; j < 4; j++)
      #pragma unroll
      for (int e = 0; e < 4; e++) acc[i][j][e] = 0.f;

  for (int tap = 0; tap < 9; tap++) {
    if (tap < 8) {
      #pragma unroll
      for (int i = 0; i < IB; i++) {
        int c = (wave * IB + i) * 64 + lane;
        int row = c / CRA, s = c % CRA;
        int swz = (CRA == 8) ? (row & 7) : ((row >> 1) & 3);
        async16(wr + ((size_t)(n0 + row) * 9 + tap + 1) * CIN + ((s ^ swz) << 3),
                &Bs[(tap + 1) & 1][(size_t)c * 8]);
      }
    }
    const int doff = (tap / 3 - 1) * HX + (tap % 3 - 1);
    const u16* bb = Bs[tap & 1];
    #pragma unroll
    for (int ks = 0; ks < CIN / 32; ks++) {
      const int sub = ks * 4 + (lane >> 4);
      bfrag af[4], bfr[4];
      #pragma unroll
      for (int i = 0; i < 4; i++) {
        int hp = hbase[i] + doff;
        int swz = (CRA == 8) ? (hp & 7) : ((hp >> 1) & 3);
        af[i] = *(const bfrag*)&Ah[hp * CIN + ((sub ^ swz) << 3)];
      }
      #pragma unroll
      for (int j = 0; j < 4; j++) {
        int r = wn + j * 16 + (lane & 15);
        int swz = (CRA == 8) ? (r & 7) : ((r >> 1) & 3);
        bfr[j] = *(const bfrag*)&bb[r * CIN + ((sub ^ swz) << 3)];
      }
      #pragma unroll
      for (int i = 0; i < 4; i++)
        #pragma unroll
        for (int j = 0; j < 4; j++)
          acc[i][j] = __builtin_amdgcn_mfma_f32_16x16x32_bf16(af[i], bfr[j], acc[i][j], 0, 0, 0);
    }
    __syncthreads();
  }

  if (STORE) {
    #pragma unroll
    for (int i = 0; i < 4; i++)
      #pragma unroll
      for (int r = 0; r < 4; r++) {
        int row = wm + i * 16 + (lane >> 4) * 4 + r;
        int m = b * IMGPIX + (ty0 + row / TX) * 224 + tx0 + row % TX;
        u16* orow = Xout + (size_t)m * COUT + n0 + wn + (lane & 15);
        #pragma unroll
        for (int j = 0; j < 4; j++) orow[j * 16] = f2b(acc[i][j][r]);
      }
  }

  if (STATS) {
    float s[4], q[4];
    #pragma unroll
    for (int j = 0; j < 4; j++) {
      s[j] = 0.f; q[j] = 0.f;
      #pragma unroll
      for (int i = 0; i < 4; i++)
        #pragma unroll
        for (int r = 0; r < 4; r++) { float v = acc[i][j][r]; s[j] += v; q[j] += v * v; }
    }
    #pragma unroll
    for (int j = 0; j < 4; j++)
      #pragma unroll
      for (int o2 = 16; o2 < 64; o2 <<= 1) {
        s[j] += __shfl_xor(s[j], o2, 64);
        q[j] += __shfl_xor(q[j], o2, 64);
      }
    float* red = (float*)Ah;
    if (lane < 16) {
      #pragma unroll
      for (int j = 0; j < 4; j++) {
        red[(wave * 2 + 0) * 64 + j * 16 + lane] = s[j];
        red[(wave * 2 + 1) * 64 + j * 16 + lane] = q[j];
      }
    }
    __syncthreads();
    int slot = blockIdx.x & 7;
    for (int c = tid; c < BN; c += 256) {
      int grp = c >> 6, idx = c & 63;
      float ss = 0.f, qq = 0.f;
      for (int w = grp; w < 4; w += WGN) {
        ss += red[(w * 2 + 0) * 64 + idx];
        qq += red[(w * 2 + 1) * 64 + idx];
      }
      atomicAdd(&st[slot * 2 * COUT + n0 + c], ss);
      atomicAdd(&st[slot * 2 * COUT + COUT + n0 + c], qq);
    }
  }
}

// ---------------- legacy implicit-GEMM conv (plan-T chunked passes only) ------
template<int CIN, int COUT, int BM, int BN, int WGN, int STATS, int STORE, int CHUNK>
__global__ __launch_bounds__(256) void k_convgemm(
    const u16* __restrict__ Xin, const u16* __restrict__ wr,
    u16* __restrict__ Xout, const u16* __restrict__ zbuf,
    float* __restrict__ st, int cy)
{
  constexpr int CRA = CIN / 8;
  constexpr int IA  = BM * CRA / 256;
  constexpr int IB  = BN * CRA / 256;
  constexpr int NT  = COUT / BN;

  __shared__ u16 As[BM * CIN];
  __shared__ u16 Bs[BN * CIN];

  const int tid = threadIdx.x;
  const int lane = tid & 63, wave = tid >> 6;
  const int nt = blockIdx.x % NT, mt = blockIdx.x / NT;
  const int m0 = mt * BM, n0 = nt * BN;

  int am[IA], ay[IA], ax[IA], asub[IA];
  #pragma unroll
  for (int i = 0; i < IA; i++) {
    int c = (wave * IA + i) * 64 + lane;
    int row = c / CRA, s = c % CRA;
    int swz = ((CRA == 8) ? row : (row >> 1)) & (CRA - 1);
    asub[i] = s ^ swz;
    int ml = m0 + row;
    int b, y, x;
    if (CHUNK) {
      b = ml / BAND; int rem = ml % BAND;
      y = cy * 28 + rem / 224; x = rem % 224;
    } else {
      b = ml / IMGPIX; int rem = ml % IMGPIX;
      y = rem / 224; x = rem % 224;
    }
    am[i] = b * IMGPIX + y * 224 + x;
    ay[i] = y; ax[i] = x;
  }
  int bn_[IB], bsub[IB];
  #pragma unroll
  for (int i = 0; i < IB; i++) {
    int c = (wave * IB + i) * 64 + lane;
    int row = c / CRA, s = c % CRA;
    int swz = ((CRA == 8) ? row : (row >> 1)) & (CRA - 1);
    bn_[i] = n0 + row;
    bsub[i] = s ^ swz;
  }

  ffrag acc[4][4];
  #pragma unroll
  for (int i = 0; i < 4; i++)
    #pragma unroll
    for (int j = 0; j < 4; j++)
      #pragma unroll
      for (int e = 0; e < 4; e++) acc[i][j][e] = 0.f;

  const int wm = (wave / WGN) * 64;
  const int wn = (wave % WGN) * 64;

  for (int tap = 0; tap < 9; tap++) {
    const int dy = tap / 3 - 1, dx = tap % 3 - 1;
    const int doff = dy * 224 + dx;
    #pragma unroll
    for (int i = 0; i < IA; i++) {
      unsigned yy = (unsigned)(ay[i] + dy), xx = (unsigned)(ax[i] + dx);
      const u16* g = (yy < 224u && xx < 224u)
          ? (Xin + (size_t)(am[i] + doff) * CIN + asub[i] * 8)
          : zbuf;
      async16(g, &As[(size_t)((wave * IA + i) * 64 + lane) * 8]);
    }
    #pragma unroll
    for (int i = 0; i < IB; i++) {
      const u16* g = wr + ((size_t)bn_[i] * 9 + tap) * CIN + bsub[i] * 8;
      async16(g, &Bs[(size_t)((wave * IB + i) * 64 + lane) * 8]);
    }
    __syncthreads();
    #pragma unroll
    for (int ks = 0; ks < CIN / 32; ks++) {
      bfrag af[4], bfr[4];
      #pragma unroll
      for (int i = 0; i < 4; i++) {
        int r = wm + i * 16 + (lane & 15);
        int sub = ks * 4 + (lane >> 4);
        int swz = ((CRA == 8) ? r : (r >> 1)) & (CRA - 1);
        af[i] = *(const bfrag*)&As[r * CIN + (sub ^ swz) * 8];
      }
      #pragma unroll
      for (int j = 0; j < 4; j++) {
        int r = wn + j * 16 + (lane & 15);
        int sub = ks * 4 + (lane >> 4);
        int swz = ((CRA == 8) ? r : (r >> 1)) & (CRA - 1);
        bfr[j] = *(const bfrag*)&Bs[r * CIN + (sub ^ swz) * 8];
      }
      #pragma unroll
      for (int i = 0; i < 4; i++)
        #pragma unroll
        for (int j = 0; j < 4; j++)
          acc[i][j] = __builtin_amdgcn_mfma_f32_16x16x32_bf16(af[i], bfr[j], acc[i][j], 0, 0, 0);
    }
    __syncthreads();
  }

  if (STORE) {
    #pragma unroll
    for (int i = 0; i < 4; i++)
      #pragma unroll
      for (int r = 0; r < 4; r++) {
        int m = m0 + wm + i * 16 + (lane >> 4) * 4 + r;
        u16* orow = Xout + (size_t)m * COUT + n0 + wn + (lane & 15);
        #pragma unroll
        for (int j = 0; j < 4; j++) orow[j * 16] = f2b(acc[i][j][r]);
      }
  }

  if (STATS) {
    float s[4], q[4];
    #pragma unroll
    for (int j = 0; j < 4; j++) {
      s[j] = 0.f; q[j] = 0.f;
      #pragma unroll
      for (int i = 0; i < 4; i++)
        #pragma unroll
        for (int r = 0; r < 4; r++) { float v = acc[i][j][r]; s[j] += v; q[j] += v * v; }
    }
    #pragma unroll
    for (int j = 0; j < 4; j++)
      #pragma unroll
      for (int o2 = 16; o2 < 64; o2 <<= 1) {
        s[j] += __shfl_xor(s[j], o2, 64);
        q[j] += __shfl_xor(q[j], o2, 64);
      }
    float* red = (float*)As;
    if (lane < 16) {
      #pragma unroll
      for (int j = 0; j < 4; j++) {
        red[(wave * 2 + 0) * 64 + j * 16 + lane] = s[j];
        red[(wave * 2 + 1) * 64 + j * 16 + lane] = q[j];
      }
    }
    __syncthreads();
    int slot = blockIdx.x & 7;
    for (int c = tid; c < BN; c += 256) {
      int grp = c >> 6, idx = c & 63;
      float ss = 0.f, qq = 0.f;
      for (int w = grp; w < 4; w += WGN) {
        ss += red[(w * 2 + 0) * 64 + idx];
        qq += red[(w * 2 + 1) * 64 + idx];
      }
      atomicAdd(&st[slot * 2 * COUT + n0 + c], ss);
      atomicAdd(&st[slot * 2 * COUT + COUT + n0 + c], qq);
    }
  }
}

// ---------------- SPP pool (vectorized): bn3+relu then 8x8 cell sums ----------
template<int CHUNK>
__global__ __launch_bounds__(256) void k_pool2(const u16* __restrict__ X3,
    const float* __restrict__ sc, const float* __restrict__ sh,
    float* __restrict__ grid8, int cy_arg)
{
  int b, cy, cx;
  if (CHUNK) { b = blockIdx.x >> 3; cy = cy_arg; cx = blockIdx.x & 7; }
  else { b = blockIdx.x >> 6; cy = (blockIdx.x >> 3) & 7; cx = blockIdx.x & 7; }
  const int tid = threadIdx.x;
  const int cslot = tid & 31, prow = tid >> 5;
  const int ch = cslot * 8;
  float s[8], hh[8], acc[8];
  #pragma unroll
  for (int e = 0; e < 8; e++) { s[e] = sc[ch + e]; hh[e] = sh[ch + e]; acc[e] = 0.f; }
  for (int yy = prow; yy < 28; yy += 8) {
    size_t pix;
    if (CHUNK) pix = (size_t)b * BAND + (size_t)yy * 224 + cx * 28;
    else       pix = (size_t)b * IMGPIX + (size_t)(cy * 28 + yy) * 224 + cx * 28;
    for (int xx = 0; xx < 28; xx++) {
      uint4 v = *(const uint4*)&X3[(pix + xx) * 256 + ch];
      u16* e = (u16*)&v;
      #pragma unroll
      for (int k = 0; k < 8; k++)
        acc[k] += fmaxf(b2f(e[k]) * s[k] + hh[k], 0.f);
    }
  }
  __shared__ float red[8][256];
  #pragma unroll
  for (int e = 0; e < 8; e++) red[prow][ch + e] = acc[e];
  __syncthreads();
  float t = 0.f;
  #pragma unroll
  for (int p = 0; p < 8; p++) t += red[p][tid];
  grid8[(size_t)((b * 8 + cy) * 8 + cx) * 256 + tid] = t;
}

// ---------------- build tokens x[8][86][256] (fp32 + bf16) ----------------
__global__ __launch_bounds__(256) void k_tokens(const float* __restrict__ grid8,
    const float* __restrict__ cls, float* __restrict__ x, u16* __restrict__ xb)
{
  int b = blockIdx.x / 86, t = blockIdx.x % 86, d = threadIdx.x;
  float v;
  if (t == 0) v = cls[d];
  else {
    int u = t - 1, l;
    if (u < 1) { l = 1; }
    else if (u < 5) { u -= 1; l = 2; }
    else if (u < 21) { u -= 5; l = 4; }
    else { u -= 21; l = 8; }
    int i = u / l, j = u % l, span = 8 / l;
    float s = 0.f;
    for (int cy = i * span; cy < (i + 1) * span; cy++)
      for (int cx = j * span; cx < (j + 1) * span; cx++)
        s += grid8[(size_t)((b * 8 + cy) * 8 + cx) * 256 + d];
    v = s / (float)(span * span * 784);
  }
  size_t o = ((size_t)b * 86 + t) * 256 + d;
  x[o] = v;
  xb[o] = f2b(v);
}

// ---------------- one-time weight prep (tiled, coalesced transpose) ----------
__global__ __launch_bounds__(256) void k_trans2(const float* __restrict__ src,
    u16* __restrict__ dst, int K, int N, size_t sStride, size_t dStride,
    int tilesK, int tilesN)
{
  const int tpm = tilesK * tilesN;
  const int mat = blockIdx.x / tpm;
  const int t = blockIdx.x % tpm;
  const int k0 = (t % tilesK) * 64, n0 = (t / tilesK) * 64;
  const float* s = src + (size_t)mat * sStride;
  u16* d = dst + (size_t)mat * dStride;
  __shared__ u16 tile[64][65];
  const int tid = threadIdx.x;
  const int col = tid & 63, rowb = tid >> 6;
  #pragma unroll
  for (int r = 0; r < 16; r++) {
    int kk = r * 4 + rowb;
    tile[kk][col] = f2b(s[(size_t)(k0 + kk) * N + n0 + col]);
  }
  __syncthreads();
  #pragma unroll
  for (int r = 0; r < 16; r++) {
    int nn = r * 4 + rowb;
    d[(size_t)(n0 + nn) * K + k0 + col] = tile[col][nn];
  }
}

__global__ void k_cvt(const float* __restrict__ src, u16* __restrict__ dst, int n)
{
  int i = blockIdx.x * 256 + threadIdx.x;
  if (i < n) dst[i] = f2b(src[i]);
}

// ---------------- fused QKV + relative attention per (b,h) ----------------
// phase a computes Q|K|V (N=192) in one GEMM; V kept in registers, written as
// V^T after Qs dies (post phase d). Staging via global_load_lds.
__global__ __launch_bounds__(256) void k_qkvattn(
    const u16* __restrict__ xbf, const u16* __restrict__ wqkv,
    const u16* __restrict__ relb, const float* __restrict__ bq,
    const float* __restrict__ bk, const float* __restrict__ bv,
    const u16* __restrict__ zbuf, u16* __restrict__ Obb)
{
  const int bh = blockIdx.x, b = bh >> 3, h = bh & 7;
  const int tid = threadIdx.x, lane = tid & 63, wave = tid >> 6;
  __shared__ float S[9600];
  __shared__ u16 Qs[96 * 64];
  __shared__ u16 Ks[96 * 64];
  u16* Ast = (u16*)S;                 // 96*64 u16
  u16* Bst = (u16*)S + 96 * 64;       // 192*64 u16 (total 36.9KB <= 38.4KB)
  const u16* wblk = wqkv + (size_t)h * 3 * 64 * 256;
  const u16* relh = relb + (size_t)h * TT * 64;
  const int wm = (wave >> 1) * 48;
  const int wnA = (wave & 1) * 96;

  for (int i = tid; i < 640; i += 256) { Qs[86 * 64 + i] = 0; Ks[86 * 64 + i] = 0; }

  // ---- phase a: [Q|K|V] = x @ W (M=96, N=192, K=256) ----
  ffrag accA[3][6];
  #pragma unroll
  for (int i = 0; i < 3; i++)
    #pragma unroll
    for (int j = 0; j < 6; j++)
      #pragma unroll
      for (int e = 0; e < 4; e++) accA[i][j][e] = 0.f;
  for (int kc = 0; kc < 4; kc++) {
    #pragma unroll
    for (int i = 0; i < 3; i++) {
      int c = tid + i * 256; int row = c >> 3, sub = c & 7;
      const u16* g = (row < TT)
          ? xbf + ((size_t)(b * TT + row)) * 256 + kc * 64 + ((sub ^ (row & 7)) << 3)
          : zbuf;
      async16(g, &Ast[c * 8]);
    }
    #pragma unroll
    for (int i = 0; i < 6; i++) {
      int c = tid + i * 256; int row = c >> 3, sub = c & 7;
      async16(wblk + (size_t)row * 256 + kc * 64 + ((sub ^ (row & 7)) << 3), &Bst[c * 8]);
    }
    __syncthreads();
    #pragma unroll
    for (int ks = 0; ks < 2; ks++) {
      bfrag af[3], bf[6];
      #pragma unroll
      for (int i = 0; i < 3; i++) af[i] = RD(Ast, wm + i * 16 + (lane & 15), ks);
      #pragma unroll
      for (int j = 0; j < 6; j++) bf[j] = RD(Bst, wnA + j * 16 + (lane & 15), ks);
      #pragma unroll
      for (int i = 0; i < 3; i++)
        #pragma unroll
        for (int j = 0; j < 6; j++)
          accA[i][j] = __builtin_amdgcn_mfma_f32_16x16x32_bf16(af[i], bf[j], accA[i][j], 0, 0, 0);
    }
    __syncthreads();
  }
  // epilogue: Q,K (+bias) into Qs/Ks; V (cols 128..191) stays in registers
  #pragma unroll
  for (int i = 0; i < 3; i++)
    #pragma unroll
    for (int j = 0; j < 6; j++) {
      int c = wnA + j * 16 + (lane & 15);
      if (c < 128) {
        int mat = c >> 6, d = c & 63;
        float bias = mat ? bk[h * 64 + d] : bq[h * 64 + d];
        u16* dstb = mat ? Ks : Qs;
        #pragma unroll
        for (int r = 0; r < 4; r++) {
          int t = wm + i * 16 + (lane >> 4) * 4 + r;
          if (t < TT)
            dstb[t * 64 + (((d >> 3) ^ (t & 7)) << 3) + (d & 7)] = f2b(accA[i][j][r] + bias);
        }
      }
    }
  __syncthreads();

  const int wn = (wave & 1) * 48;
  // ---- phase b: QK^T in registers ----
  ffrag accQK[3][3];
  #pragma unroll
  for (int i = 0; i < 3; i++)
    #pragma unroll
    for (int j = 0; j < 3; j++)
      #pragma unroll
      for (int e = 0; e < 4; e++) accQK[i][j][e] = 0.f;
  #pragma unroll
  for (int ks = 0; ks < 2; ks++) {
    bfrag af[3], bf[3];
    #pragma unroll
    for (int i = 0; i < 3; i++) af[i] = RD(Qs, wm + i * 16 + (lane & 15), ks);
    #pragma unroll
    for (int j = 0; j < 3; j++) bf[j] = RD(Ks, wn + j * 16 + (lane & 15), ks);
    #pragma unroll
    for (int i = 0; i < 3; i++)
      #pragma unroll
      for (int j = 0; j < 3; j++)
        accQK[i][j] = __builtin_amdgcn_mfma_f32_16x16x32_bf16(af[i], bf[j], accQK[i][j], 0, 0, 0);
  }
  __syncthreads();
  // ---- phase c: stage rel over Ks (async DMA; rows>=TT read zeros) ----
  #pragma unroll
  for (int i = 0; i < 3; i++) {
    int c = tid + i * 256; int row = c >> 3, sub = c & 7;
    const u16* g = (row < TT)
        ? relh + (size_t)row * 64 + ((sub ^ (row & 7)) << 3)
        : zbuf;
    async16(g, &Ks[c * 8]);
  }
  __syncthreads();
  // ---- phase d: qrel + skew scatter into S ----
  {
    ffrag accR[3][3];
    #pragma unroll
    for (int i = 0; i < 3; i++)
      #pragma unroll
      for (int j = 0; j < 3; j++)
        #pragma unroll
        for (int e = 0; e < 4; e++) accR[i][j][e] = 0.f;
    #pragma unroll
    for (int ks = 0; ks < 2; ks++) {
      bfrag af[3], bf[3];
      #pragma unroll
      for (int i = 0; i < 3; i++) af[i] = RD(Qs, wm + i * 16 + (lane & 15), ks);
      #pragma unroll
      for (int j = 0; j < 3; j++) bf[j] = RD(Ks, wn + j * 16 + (lane & 15), ks);
      #pragma unroll
      for (int i = 0; i < 3; i++)
        #pragma unroll
        for (int j = 0; j < 3; j++)
          accR[i][j] = __builtin_amdgcn_mfma_f32_16x16x32_bf16(af[i], bf[j], accR[i][j], 0, 0, 0);
    }
    #pragma unroll
    for (int i = 0; i < 3; i++)
      #pragma unroll
      for (int j = 0; j < 3; j++)
        #pragma unroll
        for (int r = 0; r < 4; r++) {
          int t = wm + i * 16 + (lane >> 4) * 4 + r;
          int l = wn + j * 16 + (lane & 15);
          if (t < TT && l < TT) {
            int jj = t * (TT + 1) + l + 1;
            if (jj >= TT) S[(jj / TT - 1) * 100 + (jj % TT)] = accR[i][j][r];
          }
        }
    for (int t = 1 + tid; t < TT; t += 256) {
      int jj = t * (TT + 1);
      S[(jj / TT - 1) * 100 + (jj % TT)] = 0.f;
    }
  }
  __syncthreads();
  // ---- phase e: logits = (S + QK^T)/8; Qs now dead -> write V^T there ----
  #pragma unroll
  for (int i = 0; i < 3; i++)
    #pragma unroll
    for (int j = 0; j < 3; j++)
      #pragma unroll
      for (int r = 0; r < 4; r++) {
        int t = wm + i * 16 + (lane >> 4) * 4 + r;
        int s2 = wn + j * 16 + (lane & 15);
        if (t < TT && s2 < TT) {
          int o = t * 100 + s2;
          S[o] = (S[o] + accQK[i][j][r]) * 0.125f;
        }
      }
  // V^T into Qs (Vt[d][t]); stale entries at t>=TT are multiplied by P==0.
  if (wnA == 96) {
    #pragma unroll
    for (int i = 0; i < 3; i++)
      #pragma unroll
      for (int j = 2; j < 6; j++) {
        int d = (wnA + j * 16 + (lane & 15)) - 128;
        float bias = bv[h * 64 + d];
        #pragma unroll
        for (int r = 0; r < 4; r++) {
          int t = wm + i * 16 + (lane >> 4) * 4 + r;
          if (t < TT) Qs[d * 96 + t] = f2b(accA[i][j][r] + bias);
        }
      }
  }
  __syncthreads();
  // ---- softmax rows; zero pads ----
  for (int t = wave; t < TT; t += 4) {
    float v0 = S[t * 100 + lane];
    float v1 = (lane + 64 < TT) ? S[t * 100 + lane + 64] : -3.0e38f;
    float mx = fmaxf(v0, v1);
    #pragma unroll
    for (int m = 1; m < 64; m <<= 1) mx = fmaxf(mx, __shfl_xor(mx, m, 64));
    float e0 = expf(v0 - mx);
    float e1 = (lane + 64 < TT) ? expf(v1 - mx) : 0.f;
    float sm = e0 + e1;
    #pragma unroll
    for (int m = 1; m < 64; m <<= 1) sm += __shfl_xor(sm, m, 64);
    float inv = 1.f / sm;
    S[t * 100 + lane] = e0 * inv;
    if (lane + 64 < 96) S[t * 100 + lane + 64] = (lane + 64 < TT) ? e1 * inv : 0.f;
  }
  for (int idx = tid; idx < 1000; idx += 256)
    S[(86 + idx / 100) * 100 + idx % 100] = 0.f;
  __syncthreads();
  // ---- PV ----
  {
    const int wn2 = (wave & 1) * 32;
    ffrag accO[3][2];
    #pragma unroll
    for (int i = 0; i < 3; i++)
      #pragma unroll
      for (int j = 0; j < 2; j++)
        #pragma unroll
        for (int e = 0; e < 4; e++) accO[i][j][e] = 0.f;
    #pragma unroll
    for (int ks = 0; ks < 3; ks++) {
      bfrag af[3], bf[2];
      #pragma unroll
      for (int i = 0; i < 3; i++) {
        const float* sp = &S[(wm + i * 16 + (lane & 15)) * 100 + ks * 32 + (lane >> 4) * 8];
        bfrag v;
        #pragma unroll
        for (int e = 0; e < 8; e++) v[e] = (short)f2b(sp[e]);
        af[i] = v;
      }
      #pragma unroll
      for (int j = 0; j < 2; j++)
        bf[j] = *(const bfrag*)&Qs[(wn2 + j * 16 + (lane & 15)) * 96 + ks * 32 + (lane >> 4) * 8];
      #pragma unroll
      for (int i = 0; i < 3; i++)
        #pragma unroll
        for (int j = 0; j < 2; j++)
          accO[i][j] = __builtin_amdgcn_mfma_f32_16x16x32_bf16(af[i], bf[j], accO[i][j], 0, 0, 0);
    }
    #pragma unroll
    for (int i = 0; i < 3; i++)
      #pragma unroll
      for (int j = 0; j < 2; j++)
        #pragma unroll
        for (int r = 0; r < 4; r++) {
          int t = wm + i * 16 + (lane >> 4) * 4 + r;
          int d = wn2 + j * 16 + (lane & 15);
          if (t < TT)
            Obb[((size_t)(b * TT + t)) * 512 + h * 64 + d] = f2b(accO[i][j][r]);
        }
  }
}

// ---------------- proj + residual + LN ----------------
__global__ __launch_bounds__(256) void k_projln(
    const u16* __restrict__ Obb, const u16* __restrict__ Wob,
    const float* __restrict__ bo, const float* __restrict__ lg,
    const float* __restrict__ lb, float* __restrict__ xtok, u16* __restrict__ hb)
{
  const int m0 = blockIdx.x * 16;
  const int tid = threadIdx.x, lane = tid & 63, wave = tid >> 6;
  __shared__ u16 Ast[16 * 64];
  __shared__ u16 Bst[256 * 64];
  __shared__ float rowbuf[16 * 256];
  const int wn = wave * 64;
  ffrag acc[4];
  #pragma unroll
  for (int j = 0; j < 4; j++)
    #pragma unroll
    for (int e = 0; e < 4; e++) acc[j][e] = 0.f;
  for (int kc = 0; kc < 8; kc++) {
    if (tid < 128) {
      int row = tid >> 3, sub = tid & 7;
      uint4 v = *(const uint4*)&Obb[(size_t)(m0 + row) * 512 + kc * 64 + sub * 8];
      *(uint4*)&Ast[row * 64 + ((sub ^ (row & 7)) << 3)] = v;
    }
    #pragma unroll
    for (int i = 0; i < 8; i++) {
      int u = tid + i * 256; int row = u >> 3, sub = u & 7;
      uint4 v = *(const uint4*)&Wob[(size_t)row * 512 + kc * 64 + sub * 8];
      *(uint4*)&Bst[row * 64 + ((sub ^ (row & 7)) << 3)] = v;
    }
    __syncthreads();
    #pragma unroll
    for (int ks = 0; ks < 2; ks++) {
      bfrag a = RD(Ast, lane & 15, ks);
      #pragma unroll
      for (int j = 0; j < 4; j++) {
        bfrag bj = RD(Bst, wn + j * 16 + (lane & 15), ks);
        acc[j] = __builtin_amdgcn_mfma_f32_16x16x32_bf16(a, bj, acc[j], 0, 0, 0);
      }
    }
    __syncthreads();
  }
  #pragma unroll
  for (int j = 0; j < 4; j++) {
    int c = wn + j * 16 + (lane & 15);
    #pragma unroll
    for (int r = 0; r < 4; r++) {
      int t = (lane >> 4) * 4 + r;
      rowbuf[t * 256 + c] = acc[j][r] + bo[c] + xtok[(size_t)(m0 + t) * 256 + c];
    }
  }
  __syncthreads();
  for (int row = wave; row < 16; row += 4) {
    float v0 = rowbuf[row * 256 + lane];
    float v1 = rowbuf[row * 256 + 64 + lane];
    float v2 = rowbuf[row * 256 + 128 + lane];
    float v3 = rowbuf[row * 256 + 192 + lane];
    float s = v0 + v1 + v2 + v3;
    float q = v0 * v0 + v1 * v1 + v2 * v2 + v3 * v3;
    #pragma unroll
    for (int m = 1; m < 64; m <<= 1) { s += __shfl_xor(s, m, 64); q += __shfl_xor(q, m, 64); }
    float mean = s * (1.f / 256.f);
    float var = fmaxf(q * (1.f / 256.f) - mean * mean, 0.f);
    float inv = 1.f / sqrtf(var + EPSV);
    size_t base = (size_t)(m0 + row) * 256;
    float vv[4] = {v0, v1, v2, v3};
    #pragma unroll
    for (int k = 0; k < 4; k++) {
      int c = lane + 64 * k;
      xtok[base + c] = vv[k];
      hb[base + c] = f2b((vv[k] - mean) * inv * lg[c] + lb[c]);
    }
  }
}

// ---------------- MLP1: h2 = gelu(h @ W1 + b1) ----------------
__global__ __launch_bounds__(256) void k_mlp1(
    const u16* __restrict__ hb, const u16* __restrict__ W1b,
    const float* __restrict__ b1, u16* __restrict__ h2b)
{
  const int m0 = blockIdx.x * 64, n0 = blockIdx.y * 128;
  const int tid = threadIdx.x, lane = tid & 63, wave = tid >> 6;
  __shared__ u16 Ast[64 * 64];
  __shared__ u16 Bst[128 * 64];
  const int wm = (wave >> 1) * 32, wn = (wave & 1) * 64;
  ffrag acc[2][4];
  #pragma unroll
  for (int i = 0; i < 2; i++)
    #pragma unroll
    for (int j = 0; j < 4; j++)
      #pragma unroll
      for (int e = 0; e < 4; e++) acc[i][j][e] = 0.f;
  for (int kc = 0; kc < 4; kc++) {
    #pragma unroll
    for (int i = 0; i < 2; i++) {
      int u = tid + i * 256; int row = u >> 3, sub = u & 7;
      int gm = m0 + row;
      uint4 v = make_uint4(0, 0, 0, 0);
      if (gm < 688) v = *(const uint4*)&hb[(size_t)gm * 256 + kc * 64 + sub * 8];
      *(uint4*)&Ast[row * 64 + ((sub ^ (row & 7)) << 3)] = v;
    }
    #pragma unroll
    for (int i = 0; i < 4; i++) {
      int u = tid + i * 256; int row = u >> 3, sub = u & 7;
      uint4 v = *(const uint4*)&W1b[(size_t)(n0 + row) * 256 + kc * 64 + sub * 8];
      *(uint4*)&Bst[row * 64 + ((sub ^ (row & 7)) << 3)] = v;
    }
    __syncthreads();
    #pragma unroll
    for (int ks = 0; ks < 2; ks++) {
      bfrag af[2], bf[4];
      #pragma unroll
      for (int i = 0; i < 2; i++) af[i] = RD(Ast, wm + i * 16 + (lane & 15), ks);
      #pragma unroll
      for (int j = 0; j < 4; j++) bf[j] = RD(Bst, wn + j * 16 + (lane & 15), ks);
      #pragma unroll
      for (int i = 0; i < 2; i++)
        #pragma unroll
        for (int j = 0; j < 4; j++)
          acc[i][j] = __builtin_amdgcn_mfma_f32_16x16x32_bf16(af[i], bf[j], acc[i][j], 0, 0, 0);
    }
    __syncthreads();
  }
  #pragma unroll
  for (int i = 0; i < 2; i++)
    #pragma unroll
    for (int j = 0; j < 4; j++) {
      int n = n0 + wn + j * 16 + (lane & 15);
      float bias = b1[n];
      #pragma unroll
      for (int r = 0; r < 4; r++) {
        int m = m0 + wm + i * 16 + (lane >> 4) * 4 + r;
        if (m < 688) {
          float v = acc[i][j][r] + bias;
          v = 0.5f * v * (1.f + erff(v * 0.7071067811865475f));
          h2b[(size_t)m * 1024 + n] = f2b(v);
        }
      }
    }
}

// ---------------- MLP2 + residual ----------------
__global__ __launch_bounds__(256) void k_mlp2(
    const u16* __restrict__ h2b, const u16* __restrict__ W2b,
    const float* __restrict__ b2, float* __restrict__ xtok, u16* __restrict__ xbf)
{
  const int m0 = blockIdx.x * 16;
  const int tid = threadIdx.x, lane = tid & 63, wave = tid >> 6;
  __shared__ u16 Ast[16 * 64];
  __shared__ u16 Bst[256 * 64];
  const int wn = wave * 64;
  ffrag acc[4];
  #pragma unroll
  for (int j = 0; j < 4; j++)
    #pragma unroll
    for (int e = 0; e < 4; e++) acc[j][e] = 0.f;
  for (int kc = 0; kc < 16; kc++) {
    if (tid < 128) {
      int row = tid >> 3, sub = tid & 7;
      uint4 v = *(const uint4*)&h2b[(size_t)(m0 + row) * 1024 + kc * 64 + sub * 8];
      *(uint4*)&Ast[row * 64 + ((sub ^ (row & 7)) << 3)] = v;
    }
    #pragma unroll
    for (int i = 0; i < 8; i++) {
      int u = tid + i * 256; int row = u >> 3, sub = u & 7;
      uint4 v = *(const uint4*)&W2b[(size_t)row * 1024 + kc * 64 + sub * 8];
      *(uint4*)&Bst[row * 64 + ((sub ^ (row & 7)) << 3)] = v;
    }
    __syncthreads();
    #pragma unroll
    for (int ks = 0; ks < 2; ks++) {
      bfrag a = RD(Ast, lane & 15, ks);
      #pragma unroll
      for (int j = 0; j < 4; j++) {
        bfrag bj = RD(Bst, wn + j * 16 + (lane & 15), ks);
        acc[j] = __builtin_amdgcn_mfma_f32_16x16x32_bf16(a, bj, acc[j], 0, 0, 0);
      }
    }
    __syncthreads();
  }
  #pragma unroll
  for (int j = 0; j < 4; j++) {
    int c = wn + j * 16 + (lane & 15);
    float bias = b2[c];
    #pragma unroll
    for (int r = 0; r < 4; r++) {
      int t = (lane >> 4) * 4 + r;
      size_t o = (size_t)(m0 + t) * 256 + c;
      float v = acc[j][r] + bias + xtok[o];
      xtok[o] = v;
      xbf[o] = f2b(v);
    }
  }
}

// ---------------- final LN(cls) @ Wh + bh ----------------
__global__ __launch_bounds__(256) void k_head(const float* __restrict__ x,
    const float* __restrict__ g, const float* __restrict__ bb,
    const float* __restrict__ Wh, const float* __restrict__ bh, float* __restrict__ out)
{
  int bidx = blockIdx.x >> 2, nc = blockIdx.x & 3;
  int tid = threadIdx.x;
  const float* xr = x + (size_t)bidx * TT * 256;
  float v = xr[tid];
  float s = v, q = v * v;
  #pragma unroll
  for (int m = 1; m < 64; m <<= 1) { s += __shfl_xor(s, m, 64); q += __shfl_xor(q, m, 64); }
  __shared__ float ps[4], pq[4];
  __shared__ float h[256];
  if ((tid & 63) == 0) { ps[tid >> 6] = s; pq[tid >> 6] = q; }
  __syncthreads();
  float S = ps[0] + ps[1] + ps[2] + ps[3];
  float Q = pq[0] + pq[1] + pq[2] + pq[3];
  float mean = S * (1.f / 256.f);
  float var = fmaxf(Q * (1.f / 256.f) - mean * mean, 0.f);
  float inv = 1.f / sqrtf(var + EPSV);
  h[tid] = (v - mean) * inv * g[tid] + bb[tid];
  __syncthreads();
  int n = nc * 256 + tid;
  if (n < 1000) {
    float acc = bh[n];
    for (int k = 0; k < 256; k++) acc += h[k] * Wh[(size_t)k * 1000 + n];
    out[bidx * 1000 + n] = acc;
  }
}

extern "C" void kernel_launch(void* const* d_in, const int* in_sizes, int n_in,
                              void* d_out, int out_size, void* d_ws, size_t ws_size,
                              hipStream_t stream)
{
  (void)in_sizes; (void)n_in; (void)out_size;
  const float* img     = (const float*)d_in[0];
  const float* conv1_w = (const float*)d_in[1];
  const float* bn1_g   = (const float*)d_in[3];
  const float* bn1_b   = (const float*)d_in[4];
  const float* conv2_w = (const float*)d_in[5];
  const float* bn2_g   = (const float*)d_in[7];
  const float* bn2_b   = (const float*)d_in[8];
  const float* conv3_w = (const float*)d_in[9];
  const float* bn3_g   = (const float*)d_in[11];
  const float* bn3_b   = (const float*)d_in[12];
  const float* cls     = (const float*)d_in[13];
  const float* Wq      = (const float*)d_in[14];
  const float* bq      = (const float*)d_in[15];
  const float* Wk      = (const float*)d_in[16];
  const float* bk      = (const float*)d_in[17];
  const float* Wv      = (const float*)d_in[18];
  const float* bv      = (const float*)d_in[19];
  const float* rel     = (const float*)d_in[20];
  const float* Wo      = (const float*)d_in[21];
  const float* bo      = (const float*)d_in[22];
  const float* ln_g    = (const float*)d_in[23];
  const float* ln_b    = (const float*)d_in[24];
  const float* W1      = (const float*)d_in[25];
  const float* b1      = (const float*)d_in[26];
  const float* W2      = (const float*)d_in[27];
  const float* b2      = (const float*)d_in[28];
  const float* hln_g   = (const float*)d_in[29];
  const float* hln_b   = (const float*)d_in[30];
  const float* Wh      = (const float*)d_in[31];
  const float* bhp     = (const float*)d_in[32];

  char* base = (char*)d_ws;
  size_t off = 0;
  auto alloc = [&](size_t bytes) -> void* {
    void* p = base + off;
    off = (off + bytes + 255) & ~(size_t)255;
    return p;
  };
  // ---- region A: small persistent ----
  u16* wr2 = (u16*)alloc((size_t)64 * 288 * 2);
  u16* wr3 = (u16*)alloc((size_t)256 * 576 * 2);
  float* stats = (float*)alloc(5696 * 4);
  float* st1 = stats;
  float* st2 = stats + 512;
  float* st3 = stats + 1536;
  u16* zbuf = (u16*)(stats + 5632);
  float* scsh = (float*)alloc(704 * 4);
  float* sc1 = scsh,        *sh1 = scsh + 32;
  float* sc2 = scsh + 64,   *sh2 = scsh + 128;
  float* sc3 = scsh + 192,  *sh3 = scsh + 448;
  float* grid8 = (float*)alloc((size_t)8 * 64 * 256 * 4);
  float* xtok  = (float*)alloc((size_t)688 * 256 * 4);
  u16* xbf   = (u16*)alloc((size_t)688 * 256 * 2);
  u16* hbb   = (u16*)alloc((size_t)688 * 256 * 2);
  u16* Obb   = (u16*)alloc((size_t)688 * 512 * 2);
  u16* h2b   = (u16*)alloc((size_t)688 * 1024 * 2);
  u16* relbuf= (u16*)alloc((size_t)6 * 8 * TT * 64 * 2);
  // ---- region B: X2 ----
  u16* X2  = (u16*)alloc((size_t)MTOT * 64 * 2);
  // ---- region C: X1 | X3 (or X3c) | transformer weights (lifetimes disjoint)
  size_t offC = off;
  const size_t sizeX1  = (size_t)MTOT * 32 * 2;
  const size_t sizeX3  = (size_t)MTOT * 256 * 2;
  const size_t sizeX3c = (size_t)8 * BAND * 256 * 2;
  const size_t sizeW   = (size_t)(2359296 + 786432 + 1572864 + 1572864) * 2;
  size_t cT = sizeX1 > sizeX3c ? sizeX1 : sizeX3c;
  if (cT < sizeW) cT = sizeW;
  const size_t needS = offC + sizeX3;
  const size_t needT = offC + cT;
  const bool planS = ws_size >= needS;
  u16* X1    = (u16*)(base + offC);
  u16* X3    = (u16*)(base + offC);
  u16* X3c   = (u16*)(base + offC);
  u16* Wqkvb = (u16*)(base + offC);                  // written AFTER pool (X3 dead)
  u16* Wob   = Wqkvb + (size_t)2359296;
  u16* W1b   = Wob   + (size_t)786432;
  u16* W2b   = W1b   + (size_t)1572864;
  if (ws_size < needT)
    fprintf(stderr, "ATHENA-HIP: ws too small, need %zu have %zu\n", needT, ws_size);

  (void)hipMemsetAsync(stats, 0, 5696 * 4, stream);

  // conv stem
  k_conv1<<<1568, 256, 0, stream>>>(img, conv1_w, X1, st1);
  k_bnfin<<<1, 256, 0, stream>>>(st1, bn1_g, bn1_b, sc1, sh1, 32, 1.f / (float)MTOT);
  k_norm<32><<<6272, 256, 0, stream>>>(X1, sc1, sh1);
  k_wreord<<<(64 * 288 + 255) / 256, 256, 0, stream>>>(conv2_w, wr2, 64, 32);
  k_convhalo<32, 64, 64, 1, 16, 16, 1, 1><<<1568, 256, 0, stream>>>(
      X1, wr2, X2, zbuf, st2);
  k_bnfin<<<1, 256, 0, stream>>>(st2, bn2_g, bn2_b, sc2, sh2, 64, 1.f / (float)MTOT);
  k_norm<64><<<12544, 256, 0, stream>>>(X2, sc2, sh2);
  k_wreord<<<(256 * 576 + 255) / 256, 256, 0, stream>>>(conv3_w, wr3, 256, 64);
  if (planS) {
    k_convhalo<64, 256, 128, 2, 8, 16, 1, 1><<<6272, 256, 0, stream>>>(
        X2, wr3, X3, zbuf, st3);
    k_bnfin<<<1, 256, 0, stream>>>(st3, bn3_g, bn3_b, sc3, sh3, 256, 1.f / (float)MTOT);
    k_pool2<0><<<512, 256, 0, stream>>>(X3, sc3, sh3, grid8, 0);
  } else {
    k_convhalo<64, 256, 128, 2, 8, 16, 1, 0><<<6272, 256, 0, stream>>>(
        X2, wr3, X3c, zbuf, st3);
    k_bnfin<<<1, 256, 0, stream>>>(st3, bn3_g, bn3_b, sc3, sh3, 256, 1.f / (float)MTOT);
    for (int cy = 0; cy < 8; cy++) {
      k_convgemm<64, 256, 128, 128, 2, 0, 1, 1><<<784, 256, 0, stream>>>(
          X2, wr3, X3c, zbuf, st3, cy);
      k_pool2<1><<<64, 256, 0, stream>>>(X3c, sc3, sh3, grid8, cy);
    }
  }
  k_tokens<<<688, 256, 0, stream>>>(grid8, cls, xtok, xbf);

  // weight prep AFTER pool: region C reuse (X3 dead)
  k_trans2<<<192, 256, 0, stream>>>(Wq, Wqkvb,         256, 64,  16384, 49152, 4, 1);
  k_trans2<<<192, 256, 0, stream>>>(Wk, Wqkvb + 16384, 256, 64,  16384, 49152, 4, 1);
  k_trans2<<<192, 256, 0, stream>>>(Wv, Wqkvb + 32768, 256, 64,  16384, 49152, 4, 1);
  k_trans2<<<192, 256, 0, stream>>>(Wo, Wob, 512, 256,  131072, 131072, 8, 4);
  k_trans2<<<384, 256, 0, stream>>>(W1, W1b, 256, 1024, 262144, 262144, 4, 16);
  k_trans2<<<384, 256, 0, stream>>>(W2, W2b, 1024, 256, 262144, 262144, 16, 4);
  k_cvt<<<(6 * 8 * TT * 64 + 255) / 256, 256, 0, stream>>>(rel, relbuf, 6 * 8 * TT * 64);

  // transformer
  for (int l = 0; l < 6; l++) {
    k_qkvattn<<<64, 256, 0, stream>>>(
        xbf, Wqkvb + (size_t)l * 8 * 3 * 64 * 256,
        relbuf + (size_t)l * 8 * TT * 64,
        bq + l * 512, bk + l * 512, bv + l * 512, zbuf, Obb);
    k_projln<<<43, 256, 0, stream>>>(
        Obb, Wob + (size_t)l * 131072, bo + l * 256,
        ln_g + l * 256, ln_b + l * 256, xtok, hbb);
    k_mlp1<<<dim3(11, 8), 256, 0, stream>>>(
        hbb, W1b + (size_t)l * 262144, b1 + l * 1024, h2b);
    k_mlp2<<<43, 256, 0, stream>>>(
        h2b, W2b + (size_t)l * 262144, b2 + l * 256, xtok, xbf);
  }
  k_head<<<32, 256, 0, stream>>>(xtok, hln_g, hln_b, Wh, bhp, (float*)d_out);
}

// Round 12
// 894.120 us; speedup vs baseline: 1.2873x; 1.0204x over previous
//
#include <hip/hip_runtime.h>
#include <math.h>
#include <cstdio>
#include <cstdint>

typedef unsigned short u16;
typedef __attribute__((ext_vector_type(8))) short bfrag;   // 8 bf16 (MFMA A/B operand)
typedef __attribute__((ext_vector_type(4))) float ffrag;   // MFMA C/D

#define IMGPIX 50176      // 224*224
#define MTOT   401408     // 8*IMGPIX
#define BAND   6272       // 28*224 (one pool row-band per batch)
#define TT     86
#define EPSV   1e-5f

__device__ __forceinline__ float b2f(u16 v) {
  union { unsigned u; float f; } x; x.u = ((unsigned)v) << 16; return x.f;
}
__device__ __forceinline__ u16 f2b(float f) {
  union { float f; unsigned u; } x; x.f = f;
  unsigned r = (x.u + 0x7FFFu + ((x.u >> 16) & 1u)) >> 16;
  return (u16)r;
}

typedef const unsigned int __attribute__((address_space(1)))* as1cu32;
typedef unsigned int __attribute__((address_space(3)))* as3u32;

__device__ __forceinline__ void async16(const u16* g, u16* l) {
  __builtin_amdgcn_global_load_lds((as1cu32)g, (as3u32)l, 16, 0, 0);
}

// swizzled fragment read from LDS tile with row stride 64 u16
#define RD(buf, r, ks) (*(const bfrag*)&(buf)[(r)*64 + ((((ks)*4 + (lane>>4)) ^ ((r)&7)) << 3)])

// ---------------- conv1: direct 3->32 (fp32 in), bf16 NHWC out + fused stats --
__global__ __launch_bounds__(256) void k_conv1(const float* __restrict__ img,
    const float* __restrict__ w, u16* __restrict__ X1, float* __restrict__ st)
{
  int blk = blockIdx.x;
  int b = blk / 196, tile = blk % 196;
  int ty0 = (tile / 14) * 16, tx0 = (tile % 14) * 16;
  __shared__ float timg[3][18][18];
  __shared__ float tw[32][27];
  int tid = threadIdx.x;
  for (int i = tid; i < 864; i += 256) tw[i / 27][i % 27] = w[i];
  for (int i = tid; i < 972; i += 256) {
    int c = i / 324, rem = i % 324, yy = rem / 18, xx = rem % 18;
    int y = ty0 + yy - 1, x = tx0 + xx - 1;
    float v = 0.f;
    if ((unsigned)y < 224u && (unsigned)x < 224u)
      v = img[((size_t)(b * 3 + c) * 224 + y) * 224 + x];
    timg[c][yy][xx] = v;
  }
  __syncthreads();
  int ly = tid / 16, lx = tid % 16;
  float acc[32];
  #pragma unroll
  for (int o = 0; o < 32; o++) acc[o] = 0.f;
  #pragma unroll
  for (int c = 0; c < 3; c++)
    #pragma unroll
    for (int ky = 0; ky < 3; ky++)
      #pragma unroll
      for (int kx = 0; kx < 3; kx++) {
        float t = timg[c][ly + ky][lx + kx];
        int tap = c * 9 + ky * 3 + kx;
        #pragma unroll
        for (int o = 0; o < 32; o++) acc[o] += t * tw[o][tap];
      }
  int m = b * IMGPIX + (ty0 + ly) * 224 + (tx0 + lx);
  uint4* dst = (uint4*)(X1 + (size_t)m * 32);
  #pragma unroll
  for (int q = 0; q < 4; q++) {
    uint4 pk;
    pk.x = (unsigned)f2b(acc[q*8+0]) | ((unsigned)f2b(acc[q*8+1]) << 16);
    pk.y = (unsigned)f2b(acc[q*8+2]) | ((unsigned)f2b(acc[q*8+3]) << 16);
    pk.z = (unsigned)f2b(acc[q*8+4]) | ((unsigned)f2b(acc[q*8+5]) << 16);
    pk.w = (unsigned)f2b(acc[q*8+6]) | ((unsigned)f2b(acc[q*8+7]) << 16);
    dst[q] = pk;
  }
  __syncthreads();
  float* red = &timg[0][0][0];
  int wave = tid >> 6, lane = tid & 63;
  #pragma unroll
  for (int c = 0; c < 32; c++) {
    float s = acc[c], q = acc[c] * acc[c];
    #pragma unroll
    for (int o2 = 1; o2 < 64; o2 <<= 1) { s += __shfl_xor(s, o2, 64); q += __shfl_xor(q, o2, 64); }
    if (lane == 0) { red[wave * 64 + c] = s; red[wave * 64 + 32 + c] = q; }
  }
  __syncthreads();
  if (tid < 32) {
    float s = red[tid] + red[64 + tid] + red[128 + tid] + red[192 + tid];
    float q = red[32 + tid] + red[96 + tid] + red[160 + tid] + red[224 + tid];
    int slot = blockIdx.x & 7;
    atomicAdd(&st[slot * 64 + tid], s);
    atomicAdd(&st[slot * 64 + 32 + tid], q);
  }
}

// ---------------- prep0: wreord2 + wreord3 + zero stats (merged) ----------------
__global__ __launch_bounds__(256) void k_prep0(const float* __restrict__ w2,
    const float* __restrict__ w3, u16* __restrict__ wr2, u16* __restrict__ wr3,
    float* __restrict__ stats)
{
  int blk = blockIdx.x, tid = threadIdx.x;
  if (blk < 72) {
    int i = blk * 256 + tid;
    if (i < 64 * 288) {
      int rem = i % 288, oc = i / 288;
      int tap = rem / 32, ic = rem % 32;
      wr2[i] = f2b(w2[(oc * 32 + ic) * 9 + tap]);
    }
  } else if (blk < 648) {
    int i = (blk - 72) * 256 + tid;
    int rem = i % 576, oc = i / 576;
    int tap = rem / 64, ic = rem % 64;
    wr3[i] = f2b(w3[(oc * 64 + ic) * 9 + tap]);
  } else {
    int i = (blk - 648) * 256 + tid;
    if (i < 5696) stats[i] = 0.f;
  }
}

// ---------------- in-place bn+relu normalize (bnfin inlined) ----------------
template<int C>
__global__ __launch_bounds__(256) void k_norm(u16* __restrict__ X,
    const float* __restrict__ st, const float* __restrict__ g,
    const float* __restrict__ beta)
{
  __shared__ float scs[C], shs[C];
  int tid = threadIdx.x;
  if (tid < C) {
    float s = 0.f, q = 0.f;
    for (int k = 0; k < 8; k++) { s += st[k * 2 * C + tid]; q += st[k * 2 * C + C + tid]; }
    float mean = s * (1.f / (float)MTOT);
    float var = fmaxf(q * (1.f / (float)MTOT) - mean * mean, 0.f);
    float sv = g[tid] / sqrtf(var + EPSV);
    scs[tid] = sv;
    shs[tid] = beta[tid] - mean * sv;
  }
  __syncthreads();
  size_t i = (size_t)blockIdx.x * 256 + tid;   // unit = 8 elems
  size_t tot = (size_t)MTOT * C / 8;
  if (i >= tot) return;
  uint4 v = ((uint4*)X)[i];
  int c0 = (int)((i * 8) % C);
  u16* e = (u16*)&v;
  #pragma unroll
  for (int k = 0; k < 8; k++) {
    float f = b2f(e[k]) * scs[c0 + k] + shs[c0 + k];
    e[k] = f2b(fmaxf(f, 0.f));
  }
  ((uint4*)X)[i] = v;
}

// ---------------- halo implicit-GEMM conv (bf16 MFMA) ----------------
template<int CIN, int COUT, int BN, int WGN, int TY, int TX, int STATS, int STORE>
__global__ __launch_bounds__(256) void k_convhalo(
    const u16* __restrict__ Xin, const u16* __restrict__ wr,
    u16* __restrict__ Xout, const u16* __restrict__ zbuf, float* __restrict__ st)
{
  constexpr int CRA = CIN / 8;
  constexpr int BM  = (4 / WGN) * 64;
  constexpr int HX  = TX + 2, HY = TY + 2;
  constexpr int HPIX = HX * HY;
  constexpr int HITER = (HPIX * CRA + 255) / 256;
  constexpr int HP  = HITER * 256 / CRA;
  constexpr int IB  = BN * CRA / 256;
  constexpr int NT  = COUT / BN;
  constexpr int TGX = 224 / TX, TGY = 224 / TY;

  __shared__ u16 Ah[HP * CIN];
  __shared__ u16 Bs[2][BN * CIN];

  const int tid = threadIdx.x;
  const int lane = tid & 63, wave = tid >> 6;
  const int nt = blockIdx.x % NT, mt = blockIdx.x / NT;
  const int b = mt / (TGX * TGY);
  const int tr = mt % (TGX * TGY);
  const int ty0 = (tr / TGX) * TY, tx0 = (tr % TGX) * TX;
  const int n0 = nt * BN;

  #pragma unroll
  for (int it = 0; it < HITER; it++) {
    int c = (wave * HITER + it) * 64 + lane;
    int pix = c / CRA, s = c % CRA;
    int hy = pix / HX, hx = pix % HX;
    int y = ty0 + hy - 1, x = tx0 + hx - 1;
    int swz = (CRA == 8) ? (pix & 7) : ((pix >> 1) & 3);
    const u16* g = (pix < HPIX && (unsigned)y < 224u && (unsigned)x < 224u)
        ? (Xin + ((size_t)(b * IMGPIX + y * 224 + x)) * CIN + ((s ^ swz) << 3))
        : zbuf;
    async16(g, &Ah[(size_t)c * 8]);
  }
  #pragma unroll
  for (int i = 0; i < IB; i++) {
    int c = (wave * IB + i) * 64 + lane;
    int row = c / CRA, s = c % CRA;
    int swz = (CRA == 8) ? (row & 7) : ((row >> 1) & 3);
    async16(wr + ((size_t)(n0 + row) * 9 + 0) * CIN + ((s ^ swz) << 3),
            &Bs[0][(size_t)c * 8]);
  }
  __syncthreads();

  const int wm = (wave / WGN) * 64;
  const int wn = (wave % WGN) * 64;
  int hbase[4];
  #pragma unroll
  for (int i = 0; i < 4; i++) {
    int row = wm + i * 16 + (lane & 15);
    hbase[i] = ((row / TX) + 1) * HX + (row % TX) + 1;
  }

  ffrag acc[4][4];
  #pragma unroll
  for (int i = 0; i < 4; i++)
    #pragma unroll
    for (int j = 0; j < 4; j++)
      #pragma unroll
      for (int e = 0; e < 4; e++) acc[i][j][e] = 0.f;

  for (int tap = 0; tap < 9; tap++) {
    if (tap < 8) {
      #pragma unroll
      for (int i = 0; i < IB; i++) {
        int c = (wave * IB + i) * 64 + lane;
        int row = c / CRA, s = c % CRA;
        int swz = (CRA == 8) ? (row & 7) : ((row >> 1) & 3);
        async16(wr + ((size_t)(n0 + row) * 9 + tap + 1) * CIN + ((s ^ swz) << 3),
                &Bs[(tap + 1) & 1][(size_t)c * 8]);
      }
    }
    const int doff = (tap / 3 - 1) * HX + (tap % 3 - 1);
    const u16* bb = Bs[tap & 1];
    #pragma unroll
    for (int ks = 0; ks < CIN / 32; ks++) {
      const int sub = ks * 4 + (lane >> 4);
      bfrag af[4], bfr[4];
      #pragma unroll
      for (int i = 0; i < 4; i++) {
        int hp = hbase[i] + doff;
        int swz = (CRA == 8) ? (hp & 7) : ((hp >> 1) & 3);
        af[i] = *(const bfrag*)&Ah[hp * CIN + ((sub ^ swz) << 3)];
      }
      #pragma unroll
      for (int j = 0; j < 4; j++) {
        int r = wn + j * 16 + (lane & 15);
        int swz = (CRA == 8) ? (r & 7) : ((r >> 1) & 3);
        bfr[j] = *(const bfrag*)&bb[r * CIN + ((sub ^ swz) << 3)];
      }
      #pragma unroll
      for (int i = 0; i < 4; i++)
        #pragma unroll
        for (int j = 0; j < 4; j++)
          acc[i][j] = __builtin_amdgcn_mfma_f32_16x16x32_bf16(af[i], bfr[j], acc[i][j], 0, 0, 0);
    }
    __syncthreads();
  }

  if (STORE) {
    #pragma unroll
    for (int i = 0; i < 4; i++)
      #pragma unroll
      for (int r = 0; r < 4; r++) {
        int row = wm + i * 16 + (lane >> 4) * 4 + r;
        int m = b * IMGPIX + (ty0 + row / TX) * 224 + tx0 + row % TX;
        u16* orow = Xout + (size_t)m * COUT + n0 + wn + (lane & 15);
        #pragma unroll
        for (int j = 0; j < 4; j++) orow[j * 16] = f2b(acc[i][j][r]);
      }
  }

  if (STATS) {
    float s[4], q[4];
    #pragma unroll
    for (int j = 0; j < 4; j++) {
      s[j] = 0.f; q[j] = 0.f;
      #pragma unroll
      for (int i = 0; i < 4; i++)
        #pragma unroll
        for (int r = 0; r < 4; r++) { float v = acc[i][j][r]; s[j] += v; q[j] += v * v; }
    }
    #pragma unroll
    for (int j = 0; j < 4; j++)
      #pragma unroll
      for (int o2 = 16; o2 < 64; o2 <<= 1) {
        s[j] += __shfl_xor(s[j], o2, 64);
        q[j] += __shfl_xor(q[j], o2, 64);
      }
    float* red = (float*)Ah;
    if (lane < 16) {
      #pragma unroll
      for (int j = 0; j < 4; j++) {
        red[(wave * 2 + 0) * 64 + j * 16 + lane] = s[j];
        red[(wave * 2 + 1) * 64 + j * 16 + lane] = q[j];
      }
    }
    __syncthreads();
    int slot = blockIdx.x & 7;
    for (int c = tid; c < BN; c += 256) {
      int grp = c >> 6, idx = c & 63;
      float ss = 0.f, qq = 0.f;
      for (int w = grp; w < 4; w += WGN) {
        ss += red[(w * 2 + 0) * 64 + idx];
        qq += red[(w * 2 + 1) * 64 + idx];
      }
      atomicAdd(&st[slot * 2 * COUT + n0 + c], ss);
      atomicAdd(&st[slot * 2 * COUT + COUT + n0 + c], qq);
    }
  }
}

// ---------------- legacy implicit-GEMM conv (plan-T chunked passes only) ------
template<int CIN, int COUT, int BM, int BN, int WGN, int STATS, int STORE, int CHUNK>
__global__ __launch_bounds__(256) void k_convgemm(
    const u16* __restrict__ Xin, const u16* __restrict__ wr,
    u16* __restrict__ Xout, const u16* __restrict__ zbuf,
    float* __restrict__ st, int cy)
{
  constexpr int CRA = CIN / 8;
  constexpr int IA  = BM * CRA / 256;
  constexpr int IB  = BN * CRA / 256;
  constexpr int NT  = COUT / BN;

  __shared__ u16 As[BM * CIN];
  __shared__ u16 Bs[BN * CIN];

  const int tid = threadIdx.x;
  const int lane = tid & 63, wave = tid >> 6;
  const int nt = blockIdx.x % NT, mt = blockIdx.x / NT;
  const int m0 = mt * BM, n0 = nt * BN;

  int am[IA], ay[IA], ax[IA], asub[IA];
  #pragma unroll
  for (int i = 0; i < IA; i++) {
    int c = (wave * IA + i) * 64 + lane;
    int row = c / CRA, s = c % CRA;
    int swz = ((CRA == 8) ? row : (row >> 1)) & (CRA - 1);
    asub[i] = s ^ swz;
    int ml = m0 + row;
    int b, y, x;
    if (CHUNK) {
      b = ml / BAND; int rem = ml % BAND;
      y = cy * 28 + rem / 224; x = rem % 224;
    } else {
      b = ml / IMGPIX; int rem = ml % IMGPIX;
      y = rem / 224; x = rem % 224;
    }
    am[i] = b * IMGPIX + y * 224 + x;
    ay[i] = y; ax[i] = x;
  }
  int bn_[IB], bsub[IB];
  #pragma unroll
  for (int i = 0; i < IB; i++) {
    int c = (wave * IB + i) * 64 + lane;
    int row = c / CRA, s = c % CRA;
    int swz = ((CRA == 8) ? row : (row >> 1)) & (CRA - 1);
    bn_[i] = n0 + row;
    bsub[i] = s ^ swz;
  }

  ffrag acc[4][4];
  #pragma unroll
  for (int i = 0; i < 4; i++)
    #pragma unroll
    for (int j = 0; j < 4; j++)
      #pragma unroll
      for (int e = 0; e < 4; e++) acc[i][j][e] = 0.f;

  const int wm = (wave / WGN) * 64;
  const int wn = (wave % WGN) * 64;

  for (int tap = 0; tap < 9; tap++) {
    const int dy = tap / 3 - 1, dx = tap % 3 - 1;
    const int doff = dy * 224 + dx;
    #pragma unroll
    for (int i = 0; i < IA; i++) {
      unsigned yy = (unsigned)(ay[i] + dy), xx = (unsigned)(ax[i] + dx);
      const u16* g = (yy < 224u && xx < 224u)
          ? (Xin + (size_t)(am[i] + doff) * CIN + asub[i] * 8)
          : zbuf;
      async16(g, &As[(size_t)((wave * IA + i) * 64 + lane) * 8]);
    }
    #pragma unroll
    for (int i = 0; i < IB; i++) {
      const u16* g = wr + ((size_t)bn_[i] * 9 + tap) * CIN + bsub[i] * 8;
      async16(g, &Bs[(size_t)((wave * IB + i) * 64 + lane) * 8]);
    }
    __syncthreads();
    #pragma unroll
    for (int ks = 0; ks < CIN / 32; ks++) {
      bfrag af[4], bfr[4];
      #pragma unroll
      for (int i = 0; i < 4; i++) {
        int r = wm + i * 16 + (lane & 15);
        int sub = ks * 4 + (lane >> 4);
        int swz = ((CRA == 8) ? r : (r >> 1)) & (CRA - 1);
        af[i] = *(const bfrag*)&As[r * CIN + (sub ^ swz) * 8];
      }
      #pragma unroll
      for (int j = 0; j < 4; j++) {
        int r = wn + j * 16 + (lane & 15);
        int sub = ks * 4 + (lane >> 4);
        int swz = ((CRA == 8) ? r : (r >> 1)) & (CRA - 1);
        bfr[j] = *(const bfrag*)&Bs[r * CIN + (sub ^ swz) * 8];
      }
      #pragma unroll
      for (int i = 0; i < 4; i++)
        #pragma unroll
        for (int j = 0; j < 4; j++)
          acc[i][j] = __builtin_amdgcn_mfma_f32_16x16x32_bf16(af[i], bfr[j], acc[i][j], 0, 0, 0);
    }
    __syncthreads();
  }

  if (STORE) {
    #pragma unroll
    for (int i = 0; i < 4; i++)
      #pragma unroll
      for (int r = 0; r < 4; r++) {
        int m = m0 + wm + i * 16 + (lane >> 4) * 4 + r;
        u16* orow = Xout + (size_t)m * COUT + n0 + wn + (lane & 15);
        #pragma unroll
        for (int j = 0; j < 4; j++) orow[j * 16] = f2b(acc[i][j][r]);
      }
  }

  if (STATS) {
    float s[4], q[4];
    #pragma unroll
    for (int j = 0; j < 4; j++) {
      s[j] = 0.f; q[j] = 0.f;
      #pragma unroll
      for (int i = 0; i < 4; i++)
        #pragma unroll
        for (int r = 0; r < 4; r++) { float v = acc[i][j][r]; s[j] += v; q[j] += v * v; }
    }
    #pragma unroll
    for (int j = 0; j < 4; j++)
      #pragma unroll
      for (int o2 = 16; o2 < 64; o2 <<= 1) {
        s[j] += __shfl_xor(s[j], o2, 64);
        q[j] += __shfl_xor(q[j], o2, 64);
      }
    float* red = (float*)As;
    if (lane < 16) {
      #pragma unroll
      for (int j = 0; j < 4; j++) {
        red[(wave * 2 + 0) * 64 + j * 16 + lane] = s[j];
        red[(wave * 2 + 1) * 64 + j * 16 + lane] = q[j];
      }
    }
    __syncthreads();
    int slot = blockIdx.x & 7;
    for (int c = tid; c < BN; c += 256) {
      int grp = c >> 6, idx = c & 63;
      float ss = 0.f, qq = 0.f;
      for (int w = grp; w < 4; w += WGN) {
        ss += red[(w * 2 + 0) * 64 + idx];
        qq += red[(w * 2 + 1) * 64 + idx];
      }
      atomicAdd(&st[slot * 2 * COUT + n0 + c], ss);
      atomicAdd(&st[slot * 2 * COUT + COUT + n0 + c], qq);
    }
  }
}

// ---------------- SPP pool (vectorized, bn3fin inlined) ----------------
template<int CHUNK>
__global__ __launch_bounds__(256) void k_pool2(const u16* __restrict__ X3,
    const float* __restrict__ st, const float* __restrict__ g,
    const float* __restrict__ beta, float* __restrict__ grid8, int cy_arg)
{
  __shared__ float scs[256], shs[256];
  const int tid = threadIdx.x;
  {
    float s = 0.f, q = 0.f;
    for (int k = 0; k < 8; k++) { s += st[k * 512 + tid]; q += st[k * 512 + 256 + tid]; }
    float mean = s * (1.f / (float)MTOT);
    float var = fmaxf(q * (1.f / (float)MTOT) - mean * mean, 0.f);
    float sv = g[tid] / sqrtf(var + EPSV);
    scs[tid] = sv;
    shs[tid] = beta[tid] - mean * sv;
  }
  __syncthreads();
  int b, cy, cx;
  if (CHUNK) { b = blockIdx.x >> 3; cy = cy_arg; cx = blockIdx.x & 7; }
  else { b = blockIdx.x >> 6; cy = (blockIdx.x >> 3) & 7; cx = blockIdx.x & 7; }
  const int cslot = tid & 31, prow = tid >> 5;
  const int ch = cslot * 8;
  float s[8], hh[8], acc[8];
  #pragma unroll
  for (int e = 0; e < 8; e++) { s[e] = scs[ch + e]; hh[e] = shs[ch + e]; acc[e] = 0.f; }
  for (int yy = prow; yy < 28; yy += 8) {
    size_t pix;
    if (CHUNK) pix = (size_t)b * BAND + (size_t)yy * 224 + cx * 28;
    else       pix = (size_t)b * IMGPIX + (size_t)(cy * 28 + yy) * 224 + cx * 28;
    for (int xx = 0; xx < 28; xx++) {
      uint4 v = *(const uint4*)&X3[(pix + xx) * 256 + ch];
      u16* e = (u16*)&v;
      #pragma unroll
      for (int k = 0; k < 8; k++)
        acc[k] += fmaxf(b2f(e[k]) * s[k] + hh[k], 0.f);
    }
  }
  __shared__ float red[8][256];
  #pragma unroll
  for (int e = 0; e < 8; e++) red[prow][ch + e] = acc[e];
  __syncthreads();
  float t = 0.f;
  #pragma unroll
  for (int p = 0; p < 8; p++) t += red[p][tid];
  grid8[(size_t)((b * 8 + cy) * 8 + cx) * 256 + tid] = t;
}

// ---------------- build tokens x[8][86][256] (fp32 + bf16) ----------------
__global__ __launch_bounds__(256) void k_tokens(const float* __restrict__ grid8,
    const float* __restrict__ cls, float* __restrict__ x, u16* __restrict__ xb)
{
  int b = blockIdx.x / 86, t = blockIdx.x % 86, d = threadIdx.x;
  float v;
  if (t == 0) v = cls[d];
  else {
    int u = t - 1, l;
    if (u < 1) { l = 1; }
    else if (u < 5) { u -= 1; l = 2; }
    else if (u < 21) { u -= 5; l = 4; }
    else { u -= 21; l = 8; }
    int i = u / l, j = u % l, span = 8 / l;
    float s = 0.f;
    for (int cy = i * span; cy < (i + 1) * span; cy++)
      for (int cx = j * span; cx < (j + 1) * span; cx++)
        s += grid8[(size_t)((b * 8 + cy) * 8 + cx) * 256 + d];
    v = s / (float)(span * span * 784);
  }
  size_t o = ((size_t)b * 86 + t) * 256 + d;
  x[o] = v;
  xb[o] = f2b(v);
}

// ---------------- merged one-time weight prep (transposes + rel cvt) ----------
__device__ __forceinline__ void trans_tile(u16 (*tile)[65],
    const float* __restrict__ src, u16* __restrict__ dst, int K, int N,
    size_t sStride, size_t dStride, int tilesK, int tpm, int t, int tid)
{
  const int mat = t / tpm;
  const int tt = t % tpm;
  const int k0 = (tt % tilesK) * 64, n0 = (tt / tilesK) * 64;
  const float* s = src + (size_t)mat * sStride;
  u16* d = dst + (size_t)mat * dStride;
  const int col = tid & 63, rowb = tid >> 6;
  #pragma unroll
  for (int r = 0; r < 16; r++) {
    int kk = r * 4 + rowb;
    tile[kk][col] = f2b(s[(size_t)(k0 + kk) * N + n0 + col]);
  }
  __syncthreads();
  #pragma unroll
  for (int r = 0; r < 16; r++) {
    int nn = r * 4 + rowb;
    d[(size_t)(n0 + nn) * K + k0 + col] = tile[col][nn];
  }
}

__global__ __launch_bounds__(256) void k_transall(
    const float* __restrict__ Wq, const float* __restrict__ Wk,
    const float* __restrict__ Wv, const float* __restrict__ Wo,
    const float* __restrict__ W1, const float* __restrict__ W2,
    const float* __restrict__ rel,
    u16* __restrict__ Wqkvb, u16* __restrict__ Wob,
    u16* __restrict__ W1b, u16* __restrict__ W2b, u16* __restrict__ relbuf)
{
  __shared__ u16 tile[64][65];
  const int blk = blockIdx.x, tid = threadIdx.x;
  if (blk < 192)
    trans_tile(tile, Wq, Wqkvb,         256, 64,   16384, 49152, 4, 4, blk, tid);
  else if (blk < 384)
    trans_tile(tile, Wk, Wqkvb + 16384, 256, 64,   16384, 49152, 4, 4, blk - 192, tid);
  else if (blk < 576)
    trans_tile(tile, Wv, Wqkvb + 32768, 256, 64,   16384, 49152, 4, 4, blk - 384, tid);
  else if (blk < 768)
    trans_tile(tile, Wo, Wob, 512, 256,  131072, 131072, 8, 32, blk - 576, tid);
  else if (blk < 1152)
    trans_tile(tile, W1, W1b, 256, 1024, 262144, 262144, 4, 64, blk - 768, tid);
  else if (blk < 1536)
    trans_tile(tile, W2, W2b, 1024, 256, 262144, 262144, 16, 64, blk - 1152, tid);
  else {
    int i = (blk - 1536) * 256 + tid;
    if (i < 6 * 8 * TT * 64) relbuf[i] = f2b(rel[i]);
  }
}

// ---------------- fused QKV + relative attention per (b,h) ----------------
// phase a computes Q|K|V (N=192) in one GEMM; V kept in registers, written as
// V^T after Qs dies (post phase d). Staging via global_load_lds.
__global__ __launch_bounds__(256) void k_qkvattn(
    const u16* __restrict__ xbf, const u16* __restrict__ wqkv,
    const u16* __restrict__ relb, const float* __restrict__ bq,
    const float* __restrict__ bk, const float* __restrict__ bv,
    const u16* __restrict__ zbuf, u16* __restrict__ Obb)
{
  const int bh = blockIdx.x, b = bh >> 3, h = bh & 7;
  const int tid = threadIdx.x, lane = tid & 63, wave = tid >> 6;
  __shared__ float S[9600];
  __shared__ u16 Qs[96 * 64];
  __shared__ u16 Ks[96 * 64];
  u16* Ast = (u16*)S;                 // 96*64 u16
  u16* Bst = (u16*)S + 96 * 64;       // 192*64 u16 (total 36.9KB <= 38.4KB)
  const u16* wblk = wqkv + (size_t)h * 3 * 64 * 256;
  const u16* relh = relb + (size_t)h * TT * 64;
  const int wm = (wave >> 1) * 48;
  const int wnA = (wave & 1) * 96;

  for (int i = tid; i < 640; i += 256) { Qs[86 * 64 + i] = 0; Ks[86 * 64 + i] = 0; }

  // ---- phase a: [Q|K|V] = x @ W (M=96, N=192, K=256) ----
  ffrag accA[3][6];
  #pragma unroll
  for (int i = 0; i < 3; i++)
    #pragma unroll
    for (int j = 0; j < 6; j++)
      #pragma unroll
      for (int e = 0; e < 4; e++) accA[i][j][e] = 0.f;
  for (int kc = 0; kc < 4; kc++) {
    #pragma unroll
    for (int i = 0; i < 3; i++) {
      int c = tid + i * 256; int row = c >> 3, sub = c & 7;
      const u16* g = (row < TT)
          ? xbf + ((size_t)(b * TT + row)) * 256 + kc * 64 + ((sub ^ (row & 7)) << 3)
          : zbuf;
      async16(g, &Ast[c * 8]);
    }
    #pragma unroll
    for (int i = 0; i < 6; i++) {
      int c = tid + i * 256; int row = c >> 3, sub = c & 7;
      async16(wblk + (size_t)row * 256 + kc * 64 + ((sub ^ (row & 7)) << 3), &Bst[c * 8]);
    }
    __syncthreads();
    #pragma unroll
    for (int ks = 0; ks < 2; ks++) {
      bfrag af[3], bf[6];
      #pragma unroll
      for (int i = 0; i < 3; i++) af[i] = RD(Ast, wm + i * 16 + (lane & 15), ks);
      #pragma unroll
      for (int j = 0; j < 6; j++) bf[j] = RD(Bst, wnA + j * 16 + (lane & 15), ks);
      #pragma unroll
      for (int i = 0; i < 3; i++)
        #pragma unroll
        for (int j = 0; j < 6; j++)
          accA[i][j] = __builtin_amdgcn_mfma_f32_16x16x32_bf16(af[i], bf[j], accA[i][j], 0, 0, 0);
    }
    __syncthreads();
  }
  // epilogue: Q,K (+bias) into Qs/Ks; V (cols 128..191) stays in registers
  #pragma unroll
  for (int i = 0; i < 3; i++)
    #pragma unroll
    for (int j = 0; j < 6; j++) {
      int c = wnA + j * 16 + (lane & 15);
      if (c < 128) {
        int mat = c >> 6, d = c & 63;
        float bias = mat ? bk[h * 64 + d] : bq[h * 64 + d];
        u16* dstb = mat ? Ks : Qs;
        #pragma unroll
        for (int r = 0; r < 4; r++) {
          int t = wm + i * 16 + (lane >> 4) * 4 + r;
          if (t < TT)
            dstb[t * 64 + (((d >> 3) ^ (t & 7)) << 3) + (d & 7)] = f2b(accA[i][j][r] + bias);
        }
      }
    }
  __syncthreads();

  const int wn = (wave & 1) * 48;
  // ---- phase b: QK^T in registers ----
  ffrag accQK[3][3];
  #pragma unroll
  for (int i = 0; i < 3; i++)
    #pragma unroll
    for (int j = 0; j < 3; j++)
      #pragma unroll
      for (int e = 0; e < 4; e++) accQK[i][j][e] = 0.f;
  #pragma unroll
  for (int ks = 0; ks < 2; ks++) {
    bfrag af[3], bf[3];
    #pragma unroll
    for (int i = 0; i < 3; i++) af[i] = RD(Qs, wm + i * 16 + (lane & 15), ks);
    #pragma unroll
    for (int j = 0; j < 3; j++) bf[j] = RD(Ks, wn + j * 16 + (lane & 15), ks);
    #pragma unroll
    for (int i = 0; i < 3; i++)
      #pragma unroll
      for (int j = 0; j < 3; j++)
        accQK[i][j] = __builtin_amdgcn_mfma_f32_16x16x32_bf16(af[i], bf[j], accQK[i][j], 0, 0, 0);
  }
  __syncthreads();
  // ---- phase c: stage rel over Ks (async DMA; rows>=TT read zeros) ----
  #pragma unroll
  for (int i = 0; i < 3; i++) {
    int c = tid + i * 256; int row = c >> 3, sub = c & 7;
    const u16* g = (row < TT)
        ? relh + (size_t)row * 64 + ((sub ^ (row & 7)) << 3)
        : zbuf;
    async16(g, &Ks[c * 8]);
  }
  __syncthreads();
  // ---- phase d: qrel + skew scatter into S ----
  {
    ffrag accR[3][3];
    #pragma unroll
    for (int i = 0; i < 3; i++)
      #pragma unroll
      for (int j = 0; j < 3; j++)
        #pragma unroll
        for (int e = 0; e < 4; e++) accR[i][j][e] = 0.f;
    #pragma unroll
    for (int ks = 0; ks < 2; ks++) {
      bfrag af[3], bf[3];
      #pragma unroll
      for (int i = 0; i < 3; i++) af[i] = RD(Qs, wm + i * 16 + (lane & 15), ks);
      #pragma unroll
      for (int j = 0; j < 3; j++) bf[j] = RD(Ks, wn + j * 16 + (lane & 15), ks);
      #pragma unroll
      for (int i = 0; i < 3; i++)
        #pragma unroll
        for (int j = 0; j < 3; j++)
          accR[i][j] = __builtin_amdgcn_mfma_f32_16x16x32_bf16(af[i], bf[j], accR[i][j], 0, 0, 0);
    }
    #pragma unroll
    for (int i = 0; i < 3; i++)
      #pragma unroll
      for (int j = 0; j < 3; j++)
        #pragma unroll
        for (int r = 0; r < 4; r++) {
          int t = wm + i * 16 + (lane >> 4) * 4 + r;
          int l = wn + j * 16 + (lane & 15);
          if (t < TT && l < TT) {
            int jj = t * (TT + 1) + l + 1;
            if (jj >= TT) S[(jj / TT - 1) * 100 + (jj % TT)] = accR[i][j][r];
          }
        }
    for (int t = 1 + tid; t < TT; t += 256) {
      int jj = t * (TT + 1);
      S[(jj / TT - 1) * 100 + (jj % TT)] = 0.f;
    }
  }
  __syncthreads();
  // ---- phase e: logits = (S + QK^T)/8; Qs now dead -> write V^T there ----
  #pragma unroll
  for (int i = 0; i < 3; i++)
    #pragma unroll
    for (int j = 0; j < 3; j++)
      #pragma unroll
      for (int r = 0; r < 4; r++) {
        int t = wm + i * 16 + (lane >> 4) * 4 + r;
        int s2 = wn + j * 16 + (lane & 15);
        if (t < TT && s2 < TT) {
          int o = t * 100 + s2;
          S[o] = (S[o] + accQK[i][j][r]) * 0.125f;
        }
      }
  // V^T into Qs (Vt[d][t]); stale entries at t>=TT are multiplied by P==0.
  if (wnA == 96) {
    #pragma unroll
    for (int i = 0; i < 3; i++)
      #pragma unroll
      for (int j = 2; j < 6; j++) {
        int d = (wnA + j * 16 + (lane & 15)) - 128;
        float bias = bv[h * 64 + d];
        #pragma unroll
        for (int r = 0; r < 4; r++) {
          int t = wm + i * 16 + (lane >> 4) * 4 + r;
          if (t < TT) Qs[d * 96 + t] = f2b(accA[i][j][r] + bias);
        }
      }
  }
  __syncthreads();
  // ---- softmax rows; zero pads ----
  for (int t = wave; t < TT; t += 4) {
    float v0 = S[t * 100 + lane];
    float v1 = (lane + 64 < TT) ? S[t * 100 + lane + 64] : -3.0e38f;
    float mx = fmaxf(v0, v1);
    #pragma unroll
    for (int m = 1; m < 64; m <<= 1) mx = fmaxf(mx, __shfl_xor(mx, m, 64));
    float e0 = expf(v0 - mx);
    float e1 = (lane + 64 < TT) ? expf(v1 - mx) : 0.f;
    float sm = e0 + e1;
    #pragma unroll
    for (int m = 1; m < 64; m <<= 1) sm += __shfl_xor(sm, m, 64);
    float inv = 1.f / sm;
    S[t * 100 + lane] = e0 * inv;
    if (lane + 64 < 96) S[t * 100 + lane + 64] = (lane + 64 < TT) ? e1 * inv : 0.f;
  }
  for (int idx = tid; idx < 1000; idx += 256)
    S[(86 + idx / 100) * 100 + idx % 100] = 0.f;
  __syncthreads();
  // ---- PV ----
  {
    const int wn2 = (wave & 1) * 32;
    ffrag accO[3][2];
    #pragma unroll
    for (int i = 0; i < 3; i++)
      #pragma unroll
      for (int j = 0; j < 2; j++)
        #pragma unroll
        for (int e = 0; e < 4; e++) accO[i][j][e] = 0.f;
    #pragma unroll
    for (int ks = 0; ks < 3; ks++) {
      bfrag af[3], bf[2];
      #pragma unroll
      for (int i = 0; i < 3; i++) {
        const float* sp = &S[(wm + i * 16 + (lane & 15)) * 100 + ks * 32 + (lane >> 4) * 8];
        bfrag v;
        #pragma unroll
        for (int e = 0; e < 8; e++) v[e] = (short)f2b(sp[e]);
        af[i] = v;
      }
      #pragma unroll
      for (int j = 0; j < 2; j++)
        bf[j] = *(const bfrag*)&Qs[(wn2 + j * 16 + (lane & 15)) * 96 + ks * 32 + (lane >> 4) * 8];
      #pragma unroll
      for (int i = 0; i < 3; i++)
        #pragma unroll
        for (int j = 0; j < 2; j++)
          accO[i][j] = __builtin_amdgcn_mfma_f32_16x16x32_bf16(af[i], bf[j], accO[i][j], 0, 0, 0);
    }
    #pragma unroll
    for (int i = 0; i < 3; i++)
      #pragma unroll
      for (int j = 0; j < 2; j++)
        #pragma unroll
        for (int r = 0; r < 4; r++) {
          int t = wm + i * 16 + (lane >> 4) * 4 + r;
          int d = wn2 + j * 16 + (lane & 15);
          if (t < TT)
            Obb[((size_t)(b * TT + t)) * 512 + h * 64 + d] = f2b(accO[i][j][r]);
        }
  }
}

// ---------------- proj + residual + LN ----------------
__global__ __launch_bounds__(256) void k_projln(
    const u16* __restrict__ Obb, const u16* __restrict__ Wob,
    const float* __restrict__ bo, const float* __restrict__ lg,
    const float* __restrict__ lb, float* __restrict__ xtok, u16* __restrict__ hb)
{
  const int m0 = blockIdx.x * 16;
  const int tid = threadIdx.x, lane = tid & 63, wave = tid >> 6;
  __shared__ u16 Ast[16 * 64];
  __shared__ u16 Bst[256 * 64];
  __shared__ float rowbuf[16 * 256];
  const int wn = wave * 64;
  ffrag acc[4];
  #pragma unroll
  for (int j = 0; j < 4; j++)
    #pragma unroll
    for (int e = 0; e < 4; e++) acc[j][e] = 0.f;
  for (int kc = 0; kc < 8; kc++) {
    if (tid < 128) {
      int row = tid >> 3, sub = tid & 7;
      uint4 v = *(const uint4*)&Obb[(size_t)(m0 + row) * 512 + kc * 64 + sub * 8];
      *(uint4*)&Ast[row * 64 + ((sub ^ (row & 7)) << 3)] = v;
    }
    #pragma unroll
    for (int i = 0; i < 8; i++) {
      int u = tid + i * 256; int row = u >> 3, sub = u & 7;
      uint4 v = *(const uint4*)&Wob[(size_t)row * 512 + kc * 64 + sub * 8];
      *(uint4*)&Bst[row * 64 + ((sub ^ (row & 7)) << 3)] = v;
    }
    __syncthreads();
    #pragma unroll
    for (int ks = 0; ks < 2; ks++) {
      bfrag a = RD(Ast, lane & 15, ks);
      #pragma unroll
      for (int j = 0; j < 4; j++) {
        bfrag bj = RD(Bst, wn + j * 16 + (lane & 15), ks);
        acc[j] = __builtin_amdgcn_mfma_f32_16x16x32_bf16(a, bj, acc[j], 0, 0, 0);
      }
    }
    __syncthreads();
  }
  #pragma unroll
  for (int j = 0; j < 4; j++) {
    int c = wn + j * 16 + (lane & 15);
    #pragma unroll
    for (int r = 0; r < 4; r++) {
      int t = (lane >> 4) * 4 + r;
      rowbuf[t * 256 + c] = acc[j][r] + bo[c] + xtok[(size_t)(m0 + t) * 256 + c];
    }
  }
  __syncthreads();
  for (int row = wave; row < 16; row += 4) {
    float v0 = rowbuf[row * 256 + lane];
    float v1 = rowbuf[row * 256 + 64 + lane];
    float v2 = rowbuf[row * 256 + 128 + lane];
    float v3 = rowbuf[row * 256 + 192 + lane];
    float s = v0 + v1 + v2 + v3;
    float q = v0 * v0 + v1 * v1 + v2 * v2 + v3 * v3;
    #pragma unroll
    for (int m = 1; m < 64; m <<= 1) { s += __shfl_xor(s, m, 64); q += __shfl_xor(q, m, 64); }
    float mean = s * (1.f / 256.f);
    float var = fmaxf(q * (1.f / 256.f) - mean * mean, 0.f);
    float inv = 1.f / sqrtf(var + EPSV);
    size_t base = (size_t)(m0 + row) * 256;
    float vv[4] = {v0, v1, v2, v3};
    #pragma unroll
    for (int k = 0; k < 4; k++) {
      int c = lane + 64 * k;
      xtok[base + c] = vv[k];
      hb[base + c] = f2b((vv[k] - mean) * inv * lg[c] + lb[c]);
    }
  }
}

// ---------------- MLP1: h2 = gelu(h @ W1 + b1) ----------------
__global__ __launch_bounds__(256) void k_mlp1(
    const u16* __restrict__ hb, const u16* __restrict__ W1b,
    const float* __restrict__ b1, u16* __restrict__ h2b)
{
  const int m0 = blockIdx.x * 64, n0 = blockIdx.y * 128;
  const int tid = threadIdx.x, lane = tid & 63, wave = tid >> 6;
  __shared__ u16 Ast[64 * 64];
  __shared__ u16 Bst[128 * 64];
  const int wm = (wave >> 1) * 32, wn = (wave & 1) * 64;
  ffrag acc[2][4];
  #pragma unroll
  for (int i = 0; i < 2; i++)
    #pragma unroll
    for (int j = 0; j < 4; j++)
      #pragma unroll
      for (int e = 0; e < 4; e++) acc[i][j][e] = 0.f;
  for (int kc = 0; kc < 4; kc++) {
    #pragma unroll
    for (int i = 0; i < 2; i++) {
      int u = tid + i * 256; int row = u >> 3, sub = u & 7;
      int gm = m0 + row;
      uint4 v = make_uint4(0, 0, 0, 0);
      if (gm < 688) v = *(const uint4*)&hb[(size_t)gm * 256 + kc * 64 + sub * 8];
      *(uint4*)&Ast[row * 64 + ((sub ^ (row & 7)) << 3)] = v;
    }
    #pragma unroll
    for (int i = 0; i < 4; i++) {
      int u = tid + i * 256; int row = u >> 3, sub = u & 7;
      uint4 v = *(const uint4*)&W1b[(size_t)(n0 + row) * 256 + kc * 64 + sub * 8];
      *(uint4*)&Bst[row * 64 + ((sub ^ (row & 7)) << 3)] = v;
    }
    __syncthreads();
    #pragma unroll
    for (int ks = 0; ks < 2; ks++) {
      bfrag af[2], bf[4];
      #pragma unroll
      for (int i = 0; i < 2; i++) af[i] = RD(Ast, wm + i * 16 + (lane & 15), ks);
      #pragma unroll
      for (int j = 0; j < 4; j++) bf[j] = RD(Bst, wn + j * 16 + (lane & 15), ks);
      #pragma unroll
      for (int i = 0; i < 2; i++)
        #pragma unroll
        for (int j = 0; j < 4; j++)
          acc[i][j] = __builtin_amdgcn_mfma_f32_16x16x32_bf16(af[i], bf[j], acc[i][j], 0, 0, 0);
    }
    __syncthreads();
  }
  #pragma unroll
  for (int i = 0; i < 2; i++)
    #pragma unroll
    for (int j = 0; j < 4; j++) {
      int n = n0 + wn + j * 16 + (lane & 15);
      float bias = b1[n];
      #pragma unroll
      for (int r = 0; r < 4; r++) {
        int m = m0 + wm + i * 16 + (lane >> 4) * 4 + r;
        if (m < 688) {
          float v = acc[i][j][r] + bias;
          v = 0.5f * v * (1.f + erff(v * 0.7071067811865475f));
          h2b[(size_t)m * 1024 + n] = f2b(v);
        }
      }
    }
}

// ---------------- MLP2 + residual ----------------
__global__ __launch_bounds__(256) void k_mlp2(
    const u16* __restrict__ h2b, const u16* __restrict__ W2b,
    const float* __restrict__ b2, float* __restrict__ xtok, u16* __restrict__ xbf)
{
  const int m0 = blockIdx.x * 16;
  const int tid = threadIdx.x, lane = tid & 63, wave = tid >> 6;
  __shared__ u16 Ast[16 * 64];
  __shared__ u16 Bst[256 * 64];
  const int wn = wave * 64;
  ffrag acc[4];
  #pragma unroll
  for (int j = 0; j < 4; j++)
    #pragma unroll
    for (int e = 0; e < 4; e++) acc[j][e] = 0.f;
  for (int kc = 0; kc < 16; kc++) {
    if (tid < 128) {
      int row = tid >> 3, sub = tid & 7;
      uint4 v = *(const uint4*)&h2b[(size_t)(m0 + row) * 1024 + kc * 64 + sub * 8];
      *(uint4*)&Ast[row * 64 + ((sub ^ (row & 7)) << 3)] = v;
    }
    #pragma unroll
    for (int i = 0; i < 8; i++) {
      int u = tid + i * 256; int row = u >> 3, sub = u & 7;
      uint4 v = *(const uint4*)&W2b[(size_t)row * 1024 + kc * 64 + sub * 8];
      *(uint4*)&Bst[row * 64 + ((sub ^ (row & 7)) << 3)] = v;
    }
    __syncthreads();
    #pragma unroll
    for (int ks = 0; ks < 2; ks++) {
      bfrag a = RD(Ast, lane & 15, ks);
      #pragma unroll
      for (int j = 0; j < 4; j++) {
        bfrag bj = RD(Bst, wn + j * 16 + (lane & 15), ks);
        acc[j] = __builtin_amdgcn_mfma_f32_16x16x32_bf16(a, bj, acc[j], 0, 0, 0);
      }
    }
    __syncthreads();
  }
  #pragma unroll
  for (int j = 0; j < 4; j++) {
    int c = wn + j * 16 + (lane & 15);
    float bias = b2[c];
    #pragma unroll
    for (int r = 0; r < 4; r++) {
      int t = (lane >> 4) * 4 + r;
      size_t o = (size_t)(m0 + t) * 256 + c;
      float v = acc[j][r] + bias + xtok[o];
      xtok[o] = v;
      xbf[o] = f2b(v);
    }
  }
}

// ---------------- final LN(cls) @ Wh + bh ----------------
__global__ __launch_bounds__(256) void k_head(const float* __restrict__ x,
    const float* __restrict__ g, const float* __restrict__ bb,
    const float* __restrict__ Wh, const float* __restrict__ bh, float* __restrict__ out)
{
  int bidx = blockIdx.x >> 2, nc = blockIdx.x & 3;
  int tid = threadIdx.x;
  const float* xr = x + (size_t)bidx * TT * 256;
  float v = xr[tid];
  float s = v, q = v * v;
  #pragma unroll
  for (int m = 1; m < 64; m <<= 1) { s += __shfl_xor(s, m, 64); q += __shfl_xor(q, m, 64); }
  __shared__ float ps[4], pq[4];
  __shared__ float h[256];
  if ((tid & 63) == 0) { ps[tid >> 6] = s; pq[tid >> 6] = q; }
  __syncthreads();
  float S = ps[0] + ps[1] + ps[2] + ps[3];
  float Q = pq[0] + pq[1] + pq[2] + pq[3];
  float mean = S * (1.f / 256.f);
  float var = fmaxf(Q * (1.f / 256.f) - mean * mean, 0.f);
  float inv = 1.f / sqrtf(var + EPSV);
  h[tid] = (v - mean) * inv * g[tid] + bb[tid];
  __syncthreads();
  int n = nc * 256 + tid;
  if (n < 1000) {
    float acc = bh[n];
    for (int k = 0; k < 256; k++) acc += h[k] * Wh[(size_t)k * 1000 + n];
    out[bidx * 1000 + n] = acc;
  }
}

extern "C" void kernel_launch(void* const* d_in, const int* in_sizes, int n_in,
                              void* d_out, int out_size, void* d_ws, size_t ws_size,
                              hipStream_t stream)
{
  (void)in_sizes; (void)n_in; (void)out_size;
  const float* img     = (const float*)d_in[0];
  const float* conv1_w = (const float*)d_in[1];
  const float* bn1_g   = (const float*)d_in[3];
  const float* bn1_b   = (const float*)d_in[4];
  const float* conv2_w = (const float*)d_in[5];
  const float* bn2_g   = (const float*)d_in[7];
  const float* bn2_b   = (const float*)d_in[8];
  const float* conv3_w = (const float*)d_in[9];
  const float* bn3_g   = (const float*)d_in[11];
  const float* bn3_b   = (const float*)d_in[12];
  const float* cls     = (const float*)d_in[13];
  const float* Wq      = (const float*)d_in[14];
  const float* bq      = (const float*)d_in[15];
  const float* Wk      = (const float*)d_in[16];
  const float* bk      = (const float*)d_in[17];
  const float* Wv      = (const float*)d_in[18];
  const float* bv      = (const float*)d_in[19];
  const float* rel     = (const float*)d_in[20];
  const float* Wo      = (const float*)d_in[21];
  const float* bo      = (const float*)d_in[22];
  const float* ln_g    = (const float*)d_in[23];
  const float* ln_b    = (const float*)d_in[24];
  const float* W1      = (const float*)d_in[25];
  const float* b1      = (const float*)d_in[26];
  const float* W2      = (const float*)d_in[27];
  const float* b2      = (const float*)d_in[28];
  const float* hln_g   = (const float*)d_in[29];
  const float* hln_b   = (const float*)d_in[30];
  const float* Wh      = (const float*)d_in[31];
  const float* bhp     = (const float*)d_in[32];

  char* base = (char*)d_ws;
  size_t off = 0;
  auto alloc = [&](size_t bytes) -> void* {
    void* p = base + off;
    off = (off + bytes + 255) & ~(size_t)255;
    return p;
  };
  // ---- region A: small persistent ----
  u16* wr2 = (u16*)alloc((size_t)64 * 288 * 2);
  u16* wr3 = (u16*)alloc((size_t)256 * 576 * 2);
  float* stats = (float*)alloc(5696 * 4);
  float* st1 = stats;
  float* st2 = stats + 512;
  float* st3 = stats + 1536;
  u16* zbuf = (u16*)(stats + 5632);
  float* scsh = (float*)alloc(704 * 4);   // kept for layout stability (unused)
  (void)scsh;
  float* grid8 = (float*)alloc((size_t)8 * 64 * 256 * 4);
  float* xtok  = (float*)alloc((size_t)688 * 256 * 4);
  u16* xbf   = (u16*)alloc((size_t)688 * 256 * 2);
  u16* hbb   = (u16*)alloc((size_t)688 * 256 * 2);
  u16* Obb   = (u16*)alloc((size_t)688 * 512 * 2);
  u16* h2b   = (u16*)alloc((size_t)688 * 1024 * 2);
  u16* relbuf= (u16*)alloc((size_t)6 * 8 * TT * 64 * 2);
  // ---- region B: X2 ----
  u16* X2  = (u16*)alloc((size_t)MTOT * 64 * 2);
  // ---- region C: X1 | X3 (or X3c) | transformer weights (lifetimes disjoint)
  size_t offC = off;
  const size_t sizeX1  = (size_t)MTOT * 32 * 2;
  const size_t sizeX3  = (size_t)MTOT * 256 * 2;
  const size_t sizeX3c = (size_t)8 * BAND * 256 * 2;
  const size_t sizeW   = (size_t)(2359296 + 786432 + 1572864 + 1572864) * 2;
  size_t cT = sizeX1 > sizeX3c ? sizeX1 : sizeX3c;
  if (cT < sizeW) cT = sizeW;
  const size_t needS = offC + sizeX3;
  const size_t needT = offC + cT;
  const bool planS = ws_size >= needS;
  u16* X1    = (u16*)(base + offC);
  u16* X3    = (u16*)(base + offC);
  u16* X3c   = (u16*)(base + offC);
  u16* Wqkvb = (u16*)(base + offC);                  // written AFTER pool (X3 dead)
  u16* Wob   = Wqkvb + (size_t)2359296;
  u16* W1b   = Wob   + (size_t)786432;
  u16* W2b   = W1b   + (size_t)1572864;
  if (ws_size < needT)
    fprintf(stderr, "ATHENA-HIP: ws too small, need %zu have %zu\n", needT, ws_size);

  // prep: wreord2 + wreord3 + zero stats (one kernel)
  k_prep0<<<671, 256, 0, stream>>>(conv2_w, conv3_w, wr2, wr3, stats);

  // conv stem
  k_conv1<<<1568, 256, 0, stream>>>(img, conv1_w, X1, st1);
  k_norm<32><<<6272, 256, 0, stream>>>(X1, st1, bn1_g, bn1_b);
  k_convhalo<32, 64, 64, 1, 16, 16, 1, 1><<<1568, 256, 0, stream>>>(
      X1, wr2, X2, zbuf, st2);
  k_norm<64><<<12544, 256, 0, stream>>>(X2, st2, bn2_g, bn2_b);
  if (planS) {
    k_convhalo<64, 256, 128, 2, 8, 16, 1, 1><<<6272, 256, 0, stream>>>(
        X2, wr3, X3, zbuf, st3);
    k_pool2<0><<<512, 256, 0, stream>>>(X3, st3, bn3_g, bn3_b, grid8, 0);
  } else {
    k_convhalo<64, 256, 128, 2, 8, 16, 1, 0><<<6272, 256, 0, stream>>>(
        X2, wr3, X3c, zbuf, st3);
    for (int cy = 0; cy < 8; cy++) {
      k_convgemm<64, 256, 128, 128, 2, 0, 1, 1><<<784, 256, 0, stream>>>(
          X2, wr3, X3c, zbuf, st3, cy);
      k_pool2<1><<<64, 256, 0, stream>>>(X3c, st3, bn3_g, bn3_b, grid8, cy);
    }
  }
  k_tokens<<<688, 256, 0, stream>>>(grid8, cls, xtok, xbf);

  // weight prep AFTER pool (region C reuse, X3 dead): one merged kernel
  k_transall<<<2568, 256, 0, stream>>>(Wq, Wk, Wv, Wo, W1, W2, rel,
                                       Wqkvb, Wob, W1b, W2b, relbuf);

  // transformer
  for (int l = 0; l < 6; l++) {
    k_qkvattn<<<64, 256, 0, stream>>>(
        xbf, Wqkvb + (size_t)l * 8 * 3 * 64 * 256,
        relbuf + (size_t)l * 8 * TT * 64,
        bq + l * 512, bk + l * 512, bv + l * 512, zbuf, Obb);
    k_projln<<<43, 256, 0, stream>>>(
        Obb, Wob + (size_t)l * 131072, bo + l * 256,
        ln_g + l * 256, ln_b + l * 256, xtok, hbb);
    k_mlp1<<<dim3(11, 8), 256, 0, stream>>>(
        hbb, W1b + (size_t)l * 262144, b1 + l * 1024, h2b);
    k_mlp2<<<43, 256, 0, stream>>>(
        h2b, W2b + (size_t)l * 262144, b2 + l * 256, xtok, xbf);
  }
  k_head<<<32, 256, 0, stream>>>(xtok, hln_g, hln_b, Wh, bhp, (float*)d_out);
}

// Round 14
// 893.839 us; speedup vs baseline: 1.2877x; 1.0003x over previous
//
#include <hip/hip_runtime.h>
#include <math.h>
#include <cstdio>
#include <cstdint>

typedef unsigned short u16;
typedef __attribute__((ext_vector_type(8))) short bfrag;   // 8 bf16 (MFMA A/B operand)
typedef __attribute__((ext_vector_type(4))) float ffrag;   // MFMA C/D

#define IMGPIX 50176      // 224*224
#define MTOT   401408     // 8*IMGPIX
#define BAND   6272       // 28*224 (one pool row-band per batch)
#define TT     86
#define EPSV   1e-5f

__device__ __forceinline__ float b2f(u16 v) {
  union { unsigned u; float f; } x; x.u = ((unsigned)v) << 16; return x.f;
}
__device__ __forceinline__ u16 f2b(float f) {
  union { float f; unsigned u; } x; x.f = f;
  unsigned r = (x.u + 0x7FFFu + ((x.u >> 16) & 1u)) >> 16;
  return (u16)r;
}

typedef const unsigned int __attribute__((address_space(1)))* as1cu32;
typedef unsigned int __attribute__((address_space(3)))* as3u32;

__device__ __forceinline__ void async16(const u16* g, u16* l) {
  __builtin_amdgcn_global_load_lds((as1cu32)g, (as3u32)l, 16, 0, 0);
}

// swizzled fragment read from LDS tile with row stride 64 u16
#define RD(buf, r, ks) (*(const bfrag*)&(buf)[(r)*64 + ((((ks)*4 + (lane>>4)) ^ ((r)&7)) << 3)])

// ---------------- conv1: direct 3->32 (fp32 in), bf16 NHWC out + fused stats --
__global__ __launch_bounds__(256) void k_conv1(const float* __restrict__ img,
    const float* __restrict__ w, u16* __restrict__ X1, float* __restrict__ st)
{
  int blk = blockIdx.x;
  int b = blk / 196, tile = blk % 196;
  int ty0 = (tile / 14) * 16, tx0 = (tile % 14) * 16;
  __shared__ float timg[3][18][18];
  __shared__ float tw[32][27];
  int tid = threadIdx.x;
  for (int i = tid; i < 864; i += 256) tw[i / 27][i % 27] = w[i];
  for (int i = tid; i < 972; i += 256) {
    int c = i / 324, rem = i % 324, yy = rem / 18, xx = rem % 18;
    int y = ty0 + yy - 1, x = tx0 + xx - 1;
    float v = 0.f;
    if ((unsigned)y < 224u && (unsigned)x < 224u)
      v = img[((size_t)(b * 3 + c) * 224 + y) * 224 + x];
    timg[c][yy][xx] = v;
  }
  __syncthreads();
  int ly = tid / 16, lx = tid % 16;
  float acc[32];
  #pragma unroll
  for (int o = 0; o < 32; o++) acc[o] = 0.f;
  #pragma unroll
  for (int c = 0; c < 3; c++)
    #pragma unroll
    for (int ky = 0; ky < 3; ky++)
      #pragma unroll
      for (int kx = 0; kx < 3; kx++) {
        float t = timg[c][ly + ky][lx + kx];
        int tap = c * 9 + ky * 3 + kx;
        #pragma unroll
        for (int o = 0; o < 32; o++) acc[o] += t * tw[o][tap];
      }
  int m = b * IMGPIX + (ty0 + ly) * 224 + (tx0 + lx);
  uint4* dst = (uint4*)(X1 + (size_t)m * 32);
  #pragma unroll
  for (int q = 0; q < 4; q++) {
    uint4 pk;
    pk.x = (unsigned)f2b(acc[q*8+0]) | ((unsigned)f2b(acc[q*8+1]) << 16);
    pk.y = (unsigned)f2b(acc[q*8+2]) | ((unsigned)f2b(acc[q*8+3]) << 16);
    pk.z = (unsigned)f2b(acc[q*8+4]) | ((unsigned)f2b(acc[q*8+5]) << 16);
    pk.w = (unsigned)f2b(acc[q*8+6]) | ((unsigned)f2b(acc[q*8+7]) << 16);
    dst[q] = pk;
  }
  __syncthreads();
  float* red = &timg[0][0][0];
  int wave = tid >> 6, lane = tid & 63;
  #pragma unroll
  for (int c = 0; c < 32; c++) {
    float s = acc[c], q = acc[c] * acc[c];
    #pragma unroll
    for (int o2 = 1; o2 < 64; o2 <<= 1) { s += __shfl_xor(s, o2, 64); q += __shfl_xor(q, o2, 64); }
    if (lane == 0) { red[wave * 64 + c] = s; red[wave * 64 + 32 + c] = q; }
  }
  __syncthreads();
  if (tid < 32) {
    float s = red[tid] + red[64 + tid] + red[128 + tid] + red[192 + tid];
    float q = red[32 + tid] + red[96 + tid] + red[160 + tid] + red[224 + tid];
    int slot = blockIdx.x & 7;
    atomicAdd(&st[slot * 64 + tid], s);
    atomicAdd(&st[slot * 64 + 32 + tid], q);
  }
}

// ---------------- prep0: wreord2 + wreord3 + zero stats (merged) ----------------
__global__ __launch_bounds__(256) void k_prep0(const float* __restrict__ w2,
    const float* __restrict__ w3, u16* __restrict__ wr2, u16* __restrict__ wr3,
    float* __restrict__ stats)
{
  int blk = blockIdx.x, tid = threadIdx.x;
  if (blk < 72) {
    int i = blk * 256 + tid;
    if (i < 64 * 288) {
      int rem = i % 288, oc = i / 288;
      int tap = rem / 32, ic = rem % 32;
      wr2[i] = f2b(w2[(oc * 32 + ic) * 9 + tap]);
    }
  } else if (blk < 648) {
    int i = (blk - 72) * 256 + tid;
    int rem = i % 576, oc = i / 576;
    int tap = rem / 64, ic = rem % 64;
    wr3[i] = f2b(w3[(oc * 64 + ic) * 9 + tap]);
  } else {
    int i = (blk - 648) * 256 + tid;
    if (i < 5696) stats[i] = 0.f;
  }
}

// ---------------- in-place bn+relu normalize (bnfin inlined) ----------------
template<int C>
__global__ __launch_bounds__(256) void k_norm(u16* __restrict__ X,
    const float* __restrict__ st, const float* __restrict__ g,
    const float* __restrict__ beta)
{
  __shared__ float scs[C], shs[C];
  int tid = threadIdx.x;
  if (tid < C) {
    float s = 0.f, q = 0.f;
    for (int k = 0; k < 8; k++) { s += st[k * 2 * C + tid]; q += st[k * 2 * C + C + tid]; }
    float mean = s * (1.f / (float)MTOT);
    float var = fmaxf(q * (1.f / (float)MTOT) - mean * mean, 0.f);
    float sv = g[tid] / sqrtf(var + EPSV);
    scs[tid] = sv;
    shs[tid] = beta[tid] - mean * sv;
  }
  __syncthreads();
  size_t i = (size_t)blockIdx.x * 256 + tid;   // unit = 8 elems
  size_t tot = (size_t)MTOT * C / 8;
  if (i >= tot) return;
  uint4 v = ((uint4*)X)[i];
  int c0 = (int)((i * 8) % C);
  u16* e = (u16*)&v;
  #pragma unroll
  for (int k = 0; k < 8; k++) {
    float f = b2f(e[k]) * scs[c0 + k] + shs[c0 + k];
    e[k] = f2b(fmaxf(f, 0.f));
  }
  ((uint4*)X)[i] = v;
}

// ---------------- halo implicit-GEMM conv (bf16 MFMA) ----------------
template<int CIN, int COUT, int BN, int WGN, int TY, int TX, int STATS, int STORE>
__global__ __launch_bounds__(256) void k_convhalo(
    const u16* __restrict__ Xin, const u16* __restrict__ wr,
    u16* __restrict__ Xout, const u16* __restrict__ zbuf, float* __restrict__ st)
{
  constexpr int CRA = CIN / 8;
  constexpr int BM  = (4 / WGN) * 64;
  constexpr int HX  = TX + 2, HY = TY + 2;
  constexpr int HPIX = HX * HY;
  constexpr int HITER = (HPIX * CRA + 255) / 256;
  constexpr int HP  = HITER * 256 / CRA;
  constexpr int IB  = BN * CRA / 256;
  constexpr int NT  = COUT / BN;
  constexpr int TGX = 224 / TX, TGY = 224 / TY;

  __shared__ u16 Ah[HP * CIN];
  __shared__ u16 Bs[2][BN * CIN];

  const int tid = threadIdx.x;
  const int lane = tid & 63, wave = tid >> 6;
  const int nt = blockIdx.x % NT, mt = blockIdx.x / NT;
  const int b = mt / (TGX * TGY);
  const int tr = mt % (TGX * TGY);
  const int ty0 = (tr / TGX) * TY, tx0 = (tr % TGX) * TX;
  const int n0 = nt * BN;

  #pragma unroll
  for (int it = 0; it < HITER; it++) {
    int c = (wave * HITER + it) * 64 + lane;
    int pix = c / CRA, s = c % CRA;
    int hy = pix / HX, hx = pix % HX;
    int y = ty0 + hy - 1, x = tx0 + hx - 1;
    int swz = (CRA == 8) ? (pix & 7) : ((pix >> 1) & 3);
    const u16* g = (pix < HPIX && (unsigned)y < 224u && (unsigned)x < 224u)
        ? (Xin + ((size_t)(b * IMGPIX + y * 224 + x)) * CIN + ((s ^ swz) << 3))
        : zbuf;
    async16(g, &Ah[(size_t)c * 8]);
  }
  #pragma unroll
  for (int i = 0; i < IB; i++) {
    int c = (wave * IB + i) * 64 + lane;
    int row = c / CRA, s = c % CRA;
    int swz = (CRA == 8) ? (row & 7) : ((row >> 1) & 3);
    async16(wr + ((size_t)(n0 + row) * 9 + 0) * CIN + ((s ^ swz) << 3),
            &Bs[0][(size_t)c * 8]);
  }
  __syncthreads();

  const int wm = (wave / WGN) * 64;
  const int wn = (wave % WGN) * 64;
  int hbase[4];
  #pragma unroll
  for (int i = 0; i < 4; i++) {
    int row = wm + i * 16 + (lane & 15);
    hbase[i] = ((row / TX) + 1) * HX + (row % TX) + 1;
  }

  ffrag acc[4][4];
  #pragma unroll
  for (int i = 0; i < 4; i++)
    #pragma unroll
    for (int j = 0; j < 4; j++)
      #pragma unroll
      for (int e = 0; e < 4; e++) acc[i][j][e] = 0.f;

  for (int tap = 0; tap < 9; tap++) {
    if (tap < 8) {
      #pragma unroll
      for (int i = 0; i < IB; i++) {
        int c = (wave * IB + i) * 64 + lane;
        int row = c / CRA, s = c % CRA;
        int swz = (CRA == 8) ? (row & 7) : ((row >> 1) & 3);
        async16(wr + ((size_t)(n0 + row) * 9 + tap + 1) * CIN + ((s ^ swz) << 3),
                &Bs[(tap + 1) & 1][(size_t)c * 8]);
      }
    }
    const int doff = (tap / 3 - 1) * HX + (tap % 3 - 1);
    const u16* bb = Bs[tap & 1];
    #pragma unroll
    for (int ks = 0; ks < CIN / 32; ks++) {
      const int sub = ks * 4 + (lane >> 4);
      bfrag af[4], bfr[4];
      #pragma unroll
      for (int i = 0; i < 4; i++) {
        int hp = hbase[i] + doff;
        int swz = (CRA == 8) ? (hp & 7) : ((hp >> 1) & 3);
        af[i] = *(const bfrag*)&Ah[hp * CIN + ((sub ^ swz) << 3)];
      }
      #pragma unroll
      for (int j = 0; j < 4; j++) {
        int r = wn + j * 16 + (lane & 15);
        int swz = (CRA == 8) ? (r & 7) : ((r >> 1) & 3);
        bfr[j] = *(const bfrag*)&bb[r * CIN + ((sub ^ swz) << 3)];
      }
      #pragma unroll
      for (int i = 0; i < 4; i++)
        #pragma unroll
        for (int j = 0; j < 4; j++)
          acc[i][j] = __builtin_amdgcn_mfma_f32_16x16x32_bf16(af[i], bfr[j], acc[i][j], 0, 0, 0);
    }
    __syncthreads();
  }

  if (STORE) {
    #pragma unroll
    for (int i = 0; i < 4; i++)
      #pragma unroll
      for (int r = 0; r < 4; r++) {
        int row = wm + i * 16 + (lane >> 4) * 4 + r;
        int m = b * IMGPIX + (ty0 + row / TX) * 224 + tx0 + row % TX;
        u16* orow = Xout + (size_t)m * COUT + n0 + wn + (lane & 15);
        #pragma unroll
        for (int j = 0; j < 4; j++) orow[j * 16] = f2b(acc[i][j][r]);
      }
  }

  if (STATS) {
    float s[4], q[4];
    #pragma unroll
    for (int j = 0; j < 4; j++) {
      s[j] = 0.f; q[j] = 0.f;
      #pragma unroll
      for (int i = 0; i < 4; i++)
        #pragma unroll
        for (int r = 0; r < 4; r++) { float v = acc[i][j][r]; s[j] += v; q[j] += v * v; }
    }
    #pragma unroll
    for (int j = 0; j < 4; j++)
      #pragma unroll
      for (int o2 = 16; o2 < 64; o2 <<= 1) {
        s[j] += __shfl_xor(s[j], o2, 64);
        q[j] += __shfl_xor(q[j], o2, 64);
      }
    float* red = (float*)Ah;
    if (lane < 16) {
      #pragma unroll
      for (int j = 0; j < 4; j++) {
        red[(wave * 2 + 0) * 64 + j * 16 + lane] = s[j];
        red[(wave * 2 + 1) * 64 + j * 16 + lane] = q[j];
      }
    }
    __syncthreads();
    int slot = blockIdx.x & 7;
    for (int c = tid; c < BN; c += 256) {
      int grp = c >> 6, idx = c & 63;
      float ss = 0.f, qq = 0.f;
      for (int w = grp; w < 4; w += WGN) {
        ss += red[(w * 2 + 0) * 64 + idx];
        qq += red[(w * 2 + 1) * 64 + idx];
      }
      atomicAdd(&st[slot * 2 * COUT + n0 + c], ss);
      atomicAdd(&st[slot * 2 * COUT + COUT + n0 + c], qq);
    }
  }
}

// ---------------- legacy implicit-GEMM conv (plan-T chunked passes only) ------
template<int CIN, int COUT, int BM, int BN, int WGN, int STATS, int STORE, int CHUNK>
__global__ __launch_bounds__(256) void k_convgemm(
    const u16* __restrict__ Xin, const u16* __restrict__ wr,
    u16* __restrict__ Xout, const u16* __restrict__ zbuf,
    float* __restrict__ st, int cy)
{
  constexpr int CRA = CIN / 8;
  constexpr int IA  = BM * CRA / 256;
  constexpr int IB  = BN * CRA / 256;
  constexpr int NT  = COUT / BN;

  __shared__ u16 As[BM * CIN];
  __shared__ u16 Bs[BN * CIN];

  const int tid = threadIdx.x;
  const int lane = tid & 63, wave = tid >> 6;
  const int nt = blockIdx.x % NT, mt = blockIdx.x / NT;
  const int m0 = mt * BM, n0 = nt * BN;

  int am[IA], ay[IA], ax[IA], asub[IA];
  #pragma unroll
  for (int i = 0; i < IA; i++) {
    int c = (wave * IA + i) * 64 + lane;
    int row = c / CRA, s = c % CRA;
    int swz = ((CRA == 8) ? row : (row >> 1)) & (CRA - 1);
    asub[i] = s ^ swz;
    int ml = m0 + row;
    int b, y, x;
    if (CHUNK) {
      b = ml / BAND; int rem = ml % BAND;
      y = cy * 28 + rem / 224; x = rem % 224;
    } else {
      b = ml / IMGPIX; int rem = ml % IMGPIX;
      y = rem / 224; x = rem % 224;
    }
    am[i] = b * IMGPIX + y * 224 + x;
    ay[i] = y; ax[i] = x;
  }
  int bn_[IB], bsub[IB];
  #pragma unroll
  for (int i = 0; i < IB; i++) {
    int c = (wave * IB + i) * 64 + lane;
    int row = c / CRA, s = c % CRA;
    int swz = ((CRA == 8) ? row : (row >> 1)) & (CRA - 1);
    bn_[i] = n0 + row;
    bsub[i] = s ^ swz;
  }

  ffrag acc[4][4];
  #pragma unroll
  for (int i = 0; i < 4; i++)
    #pragma unroll
    for (int j = 0; j < 4; j++)
      #pragma unroll
      for (int e = 0; e < 4; e++) acc[i][j][e] = 0.f;

  const int wm = (wave / WGN) * 64;
  const int wn = (wave % WGN) * 64;

  for (int tap = 0; tap < 9; tap++) {
    const int dy = tap / 3 - 1, dx = tap % 3 - 1;
    const int doff = dy * 224 + dx;
    #pragma unroll
    for (int i = 0; i < IA; i++) {
      unsigned yy = (unsigned)(ay[i] + dy), xx = (unsigned)(ax[i] + dx);
      const u16* g = (yy < 224u && xx < 224u)
          ? (Xin + (size_t)(am[i] + doff) * CIN + asub[i] * 8)
          : zbuf;
      async16(g, &As[(size_t)((wave * IA + i) * 64 + lane) * 8]);
    }
    #pragma unroll
    for (int i = 0; i < IB; i++) {
      const u16* g = wr + ((size_t)bn_[i] * 9 + tap) * CIN + bsub[i] * 8;
      async16(g, &Bs[(size_t)((wave * IB + i) * 64 + lane) * 8]);
    }
    __syncthreads();
    #pragma unroll
    for (int ks = 0; ks < CIN / 32; ks++) {
      bfrag af[4], bfr[4];
      #pragma unroll
      for (int i = 0; i < 4; i++) {
        int r = wm + i * 16 + (lane & 15);
        int sub = ks * 4 + (lane >> 4);
        int swz = ((CRA == 8) ? r : (r >> 1)) & (CRA - 1);
        af[i] = *(const bfrag*)&As[r * CIN + (sub ^ swz) * 8];
      }
      #pragma unroll
      for (int j = 0; j < 4; j++) {
        int r = wn + j * 16 + (lane & 15);
        int sub = ks * 4 + (lane >> 4);
        int swz = ((CRA == 8) ? r : (r >> 1)) & (CRA - 1);
        bfr[j] = *(const bfrag*)&Bs[r * CIN + (sub ^ swz) * 8];
      }
      #pragma unroll
      for (int i = 0; i < 4; i++)
        #pragma unroll
        for (int j = 0; j < 4; j++)
          acc[i][j] = __builtin_amdgcn_mfma_f32_16x16x32_bf16(af[i], bfr[j], acc[i][j], 0, 0, 0);
    }
    __syncthreads();
  }

  if (STORE) {
    #pragma unroll
    for (int i = 0; i < 4; i++)
      #pragma unroll
      for (int r = 0; r < 4; r++) {
        int m = m0 + wm + i * 16 + (lane >> 4) * 4 + r;
        u16* orow = Xout + (size_t)m * COUT + n0 + wn + (lane & 15);
        #pragma unroll
        for (int j = 0; j < 4; j++) orow[j * 16] = f2b(acc[i][j][r]);
      }
  }

  if (STATS) {
    float s[4], q[4];
    #pragma unroll
    for (int j = 0; j < 4; j++) {
      s[j] = 0.f; q[j] = 0.f;
      #pragma unroll
      for (int i = 0; i < 4; i++)
        #pragma unroll
        for (int r = 0; r < 4; r++) { float v = acc[i][j][r]; s[j] += v; q[j] += v * v; }
    }
    #pragma unroll
    for (int j = 0; j < 4; j++)
      #pragma unroll
      for (int o2 = 16; o2 < 64; o2 <<= 1) {
        s[j] += __shfl_xor(s[j], o2, 64);
        q[j] += __shfl_xor(q[j], o2, 64);
      }
    float* red = (float*)As;
    if (lane < 16) {
      #pragma unroll
      for (int j = 0; j < 4; j++) {
        red[(wave * 2 + 0) * 64 + j * 16 + lane] = s[j];
        red[(wave * 2 + 1) * 64 + j * 16 + lane] = q[j];
      }
    }
    __syncthreads();
    int slot = blockIdx.x & 7;
    for (int c = tid; c < BN; c += 256) {
      int grp = c >> 6, idx = c & 63;
      float ss = 0.f, qq = 0.f;
      for (int w = grp; w < 4; w += WGN) {
        ss += red[(w * 2 + 0) * 64 + idx];
        qq += red[(w * 2 + 1) * 64 + idx];
      }
      atomicAdd(&st[slot * 2 * COUT + n0 + c], ss);
      atomicAdd(&st[slot * 2 * COUT + COUT + n0 + c], qq);
    }
  }
}

// ---------------- SPP pool (vectorized, bn3fin inlined) ----------------
template<int CHUNK>
__global__ __launch_bounds__(256) void k_pool2(const u16* __restrict__ X3,
    const float* __restrict__ st, const float* __restrict__ g,
    const float* __restrict__ beta, float* __restrict__ grid8, int cy_arg)
{
  __shared__ float scs[256], shs[256];
  const int tid = threadIdx.x;
  {
    float s = 0.f, q = 0.f;
    for (int k = 0; k < 8; k++) { s += st[k * 512 + tid]; q += st[k * 512 + 256 + tid]; }
    float mean = s * (1.f / (float)MTOT);
    float var = fmaxf(q * (1.f / (float)MTOT) - mean * mean, 0.f);
    float sv = g[tid] / sqrtf(var + EPSV);
    scs[tid] = sv;
    shs[tid] = beta[tid] - mean * sv;
  }
  __syncthreads();
  int b, cy, cx;
  if (CHUNK) { b = blockIdx.x >> 3; cy = cy_arg; cx = blockIdx.x & 7; }
  else { b = blockIdx.x >> 6; cy = (blockIdx.x >> 3) & 7; cx = blockIdx.x & 7; }
  const int cslot = tid & 31, prow = tid >> 5;
  const int ch = cslot * 8;
  float s[8], hh[8], acc[8];
  #pragma unroll
  for (int e = 0; e < 8; e++) { s[e] = scs[ch + e]; hh[e] = shs[ch + e]; acc[e] = 0.f; }
  for (int yy = prow; yy < 28; yy += 8) {
    size_t pix;
    if (CHUNK) pix = (size_t)b * BAND + (size_t)yy * 224 + cx * 28;
    else       pix = (size_t)b * IMGPIX + (size_t)(cy * 28 + yy) * 224 + cx * 28;
    for (int xx = 0; xx < 28; xx++) {
      uint4 v = *(const uint4*)&X3[(pix + xx) * 256 + ch];
      u16* e = (u16*)&v;
      #pragma unroll
      for (int k = 0; k < 8; k++)
        acc[k] += fmaxf(b2f(e[k]) * s[k] + hh[k], 0.f);
    }
  }
  __shared__ float red[8][256];
  #pragma unroll
  for (int e = 0; e < 8; e++) red[prow][ch + e] = acc[e];
  __syncthreads();
  float t = 0.f;
  #pragma unroll
  for (int p = 0; p < 8; p++) t += red[p][tid];
  grid8[(size_t)((b * 8 + cy) * 8 + cx) * 256 + tid] = t;
}

// ---------------- build tokens x[8][86][256] (fp32 + bf16) ----------------
__global__ __launch_bounds__(256) void k_tokens(const float* __restrict__ grid8,
    const float* __restrict__ cls, float* __restrict__ x, u16* __restrict__ xb)
{
  int b = blockIdx.x / 86, t = blockIdx.x % 86, d = threadIdx.x;
  float v;
  if (t == 0) v = cls[d];
  else {
    int u = t - 1, l;
    if (u < 1) { l = 1; }
    else if (u < 5) { u -= 1; l = 2; }
    else if (u < 21) { u -= 5; l = 4; }
    else { u -= 21; l = 8; }
    int i = u / l, j = u % l, span = 8 / l;
    float s = 0.f;
    for (int cy = i * span; cy < (i + 1) * span; cy++)
      for (int cx = j * span; cx < (j + 1) * span; cx++)
        s += grid8[(size_t)((b * 8 + cy) * 8 + cx) * 256 + d];
    v = s / (float)(span * span * 784);
  }
  size_t o = ((size_t)b * 86 + t) * 256 + d;
  x[o] = v;
  xb[o] = f2b(v);
}

// ---------------- merged one-time weight prep (transposes + rel cvt) ----------
__device__ __forceinline__ void trans_tile(u16 (*tile)[65],
    const float* __restrict__ src, u16* __restrict__ dst, int K, int N,
    size_t sStride, size_t dStride, int tilesK, int tpm, int t, int tid)
{
  const int mat = t / tpm;
  const int tt = t % tpm;
  const int k0 = (tt % tilesK) * 64, n0 = (tt / tilesK) * 64;
  const float* s = src + (size_t)mat * sStride;
  u16* d = dst + (size_t)mat * dStride;
  const int col = tid & 63, rowb = tid >> 6;
  #pragma unroll
  for (int r = 0; r < 16; r++) {
    int kk = r * 4 + rowb;
    tile[kk][col] = f2b(s[(size_t)(k0 + kk) * N + n0 + col]);
  }
  __syncthreads();
  #pragma unroll
  for (int r = 0; r < 16; r++) {
    int nn = r * 4 + rowb;
    d[(size_t)(n0 + nn) * K + k0 + col] = tile[col][nn];
  }
}

__global__ __launch_bounds__(256) void k_transall(
    const float* __restrict__ Wq, const float* __restrict__ Wk,
    const float* __restrict__ Wv, const float* __restrict__ Wo,
    const float* __restrict__ W1, const float* __restrict__ W2,
    const float* __restrict__ rel,
    u16* __restrict__ Wqkvb, u16* __restrict__ Wob,
    u16* __restrict__ W1b, u16* __restrict__ W2b, u16* __restrict__ relbuf)
{
  __shared__ u16 tile[64][65];
  const int blk = blockIdx.x, tid = threadIdx.x;
  if (blk < 192)
    trans_tile(tile, Wq, Wqkvb,         256, 64,   16384, 49152, 4, 4, blk, tid);
  else if (blk < 384)
    trans_tile(tile, Wk, Wqkvb + 16384, 256, 64,   16384, 49152, 4, 4, blk - 192, tid);
  else if (blk < 576)
    trans_tile(tile, Wv, Wqkvb + 32768, 256, 64,   16384, 49152, 4, 4, blk - 384, tid);
  else if (blk < 768)
    trans_tile(tile, Wo, Wob, 512, 256,  131072, 131072, 8, 32, blk - 576, tid);
  else if (blk < 1152)
    trans_tile(tile, W1, W1b, 256, 1024, 262144, 262144, 4, 64, blk - 768, tid);
  else if (blk < 1536)
    trans_tile(tile, W2, W2b, 1024, 256, 262144, 262144, 16, 64, blk - 1152, tid);
  else {
    int i = (blk - 1536) * 256 + tid;
    if (i < 6 * 8 * TT * 64) relbuf[i] = f2b(rel[i]);
  }
}

// ---------------- fused QKV + relative attention per (b,h) ----------------
// phase a computes Q|K|V (N=192) in one GEMM; V kept in registers, written as
// V^T after Qs dies (post phase d). Staging via global_load_lds.
__global__ __launch_bounds__(256) void k_qkvattn(
    const u16* __restrict__ xbf, const u16* __restrict__ wqkv,
    const u16* __restrict__ relb, const float* __restrict__ bq,
    const float* __restrict__ bk, const float* __restrict__ bv,
    const u16* __restrict__ zbuf, u16* __restrict__ Obb)
{
  const int bh = blockIdx.x, b = bh >> 3, h = bh & 7;
  const int tid = threadIdx.x, lane = tid & 63, wave = tid >> 6;
  __shared__ float S[9600];
  __shared__ u16 Qs[96 * 64];
  __shared__ u16 Ks[96 * 64];
  u16* Ast = (u16*)S;                 // 96*64 u16
  u16* Bst = (u16*)S + 96 * 64;       // 192*64 u16 (total 36.9KB <= 38.4KB)
  const u16* wblk = wqkv + (size_t)h * 3 * 64 * 256;
  const u16* relh = relb + (size_t)h * TT * 64;
  const int wm = (wave >> 1) * 48;
  const int wnA = (wave & 1) * 96;

  for (int i = tid; i < 640; i += 256) { Qs[86 * 64 + i] = 0; Ks[86 * 64 + i] = 0; }

  // ---- phase a: [Q|K|V] = x @ W (M=96, N=192, K=256) ----
  ffrag accA[3][6];
  #pragma unroll
  for (int i = 0; i < 3; i++)
    #pragma unroll
    for (int j = 0; j < 6; j++)
      #pragma unroll
      for (int e = 0; e < 4; e++) accA[i][j][e] = 0.f;
  for (int kc = 0; kc < 4; kc++) {
    #pragma unroll
    for (int i = 0; i < 3; i++) {
      int c = tid + i * 256; int row = c >> 3, sub = c & 7;
      const u16* g = (row < TT)
          ? xbf + ((size_t)(b * TT + row)) * 256 + kc * 64 + ((sub ^ (row & 7)) << 3)
          : zbuf;
      async16(g, &Ast[c * 8]);
    }
    #pragma unroll
    for (int i = 0; i < 6; i++) {
      int c = tid + i * 256; int row = c >> 3, sub = c & 7;
      async16(wblk + (size_t)row * 256 + kc * 64 + ((sub ^ (row & 7)) << 3), &Bst[c * 8]);
    }
    __syncthreads();
    #pragma unroll
    for (int ks = 0; ks < 2; ks++) {
      bfrag af[3], bf[6];
      #pragma unroll
      for (int i = 0; i < 3; i++) af[i] = RD(Ast, wm + i * 16 + (lane & 15), ks);
      #pragma unroll
      for (int j = 0; j < 6; j++) bf[j] = RD(Bst, wnA + j * 16 + (lane & 15), ks);
      #pragma unroll
      for (int i = 0; i < 3; i++)
        #pragma unroll
        for (int j = 0; j < 6; j++)
          accA[i][j] = __builtin_amdgcn_mfma_f32_16x16x32_bf16(af[i], bf[j], accA[i][j], 0, 0, 0);
    }
    __syncthreads();
  }
  // epilogue: Q,K (+bias) into Qs/Ks; V (cols 128..191) stays in registers
  #pragma unroll
  for (int i = 0; i < 3; i++)
    #pragma unroll
    for (int j = 0; j < 6; j++) {
      int c = wnA + j * 16 + (lane & 15);
      if (c < 128) {
        int mat = c >> 6, d = c & 63;
        float bias = mat ? bk[h * 64 + d] : bq[h * 64 + d];
        u16* dstb = mat ? Ks : Qs;
        #pragma unroll
        for (int r = 0; r < 4; r++) {
          int t = wm + i * 16 + (lane >> 4) * 4 + r;
          if (t < TT)
            dstb[t * 64 + (((d >> 3) ^ (t & 7)) << 3) + (d & 7)] = f2b(accA[i][j][r] + bias);
        }
      }
    }
  __syncthreads();

  const int wn = (wave & 1) * 48;
  // ---- phase b: QK^T in registers ----
  ffrag accQK[3][3];
  #pragma unroll
  for (int i = 0; i < 3; i++)
    #pragma unroll
    for (int j = 0; j < 3; j++)
      #pragma unroll
      for (int e = 0; e < 4; e++) accQK[i][j][e] = 0.f;
  #pragma unroll
  for (int ks = 0; ks < 2; ks++) {
    bfrag af[3], bf[3];
    #pragma unroll
    for (int i = 0; i < 3; i++) af[i] = RD(Qs, wm + i * 16 + (lane & 15), ks);
    #pragma unroll
    for (int j = 0; j < 3; j++) bf[j] = RD(Ks, wn + j * 16 + (lane & 15), ks);
    #pragma unroll
    for (int i = 0; i < 3; i++)
      #pragma unroll
      for (int j = 0; j < 3; j++)
        accQK[i][j] = __builtin_amdgcn_mfma_f32_16x16x32_bf16(af[i], bf[j], accQK[i][j], 0, 0, 0);
  }
  __syncthreads();
  // ---- phase c: stage rel over Ks (async DMA; rows>=TT read zeros) ----
  #pragma unroll
  for (int i = 0; i < 3; i++) {
    int c = tid + i * 256; int row = c >> 3, sub = c & 7;
    const u16* g = (row < TT)
        ? relh + (size_t)row * 64 + ((sub ^ (row & 7)) << 3)
        : zbuf;
    async16(g, &Ks[c * 8]);
  }
  __syncthreads();
  // ---- phase d: qrel + skew scatter into S ----
  {
    ffrag accR[3][3];
    #pragma unroll
    for (int i = 0; i < 3; i++)
      #pragma unroll
      for (int j = 0; j < 3; j++)
        #pragma unroll
        for (int e = 0; e < 4; e++) accR[i][j][e] = 0.f;
    #pragma unroll
    for (int ks = 0; ks < 2; ks++) {
      bfrag af[3], bf[3];
      #pragma unroll
      for (int i = 0; i < 3; i++) af[i] = RD(Qs, wm + i * 16 + (lane & 15), ks);
      #pragma unroll
      for (int j = 0; j < 3; j++) bf[j] = RD(Ks, wn + j * 16 + (lane & 15), ks);
      #pragma unroll
      for (int i = 0; i < 3; i++)
        #pragma unroll
        for (int j = 0; j < 3; j++)
          accR[i][j] = __builtin_amdgcn_mfma_f32_16x16x32_bf16(af[i], bf[j], accR[i][j], 0, 0, 0);
    }
    #pragma unroll
    for (int i = 0; i < 3; i++)
      #pragma unroll
      for (int j = 0; j < 3; j++)
        #pragma unroll
        for (int r = 0; r < 4; r++) {
          int t = wm + i * 16 + (lane >> 4) * 4 + r;
          int l = wn + j * 16 + (lane & 15);
          if (t < TT && l < TT) {
            int jj = t * (TT + 1) + l + 1;
            if (jj >= TT) S[(jj / TT - 1) * 100 + (jj % TT)] = accR[i][j][r];
          }
        }
    for (int t = 1 + tid; t < TT; t += 256) {
      int jj = t * (TT + 1);
      S[(jj / TT - 1) * 100 + (jj % TT)] = 0.f;
    }
  }
  __syncthreads();
  // ---- phase e: logits = (S + QK^T)/8; Qs now dead -> write V^T there ----
  #pragma unroll
  for (int i = 0; i < 3; i++)
    #pragma unroll
    for (int j = 0; j < 3; j++)
      #pragma unroll
      for (int r = 0; r < 4; r++) {
        int t = wm + i * 16 + (lane >> 4) * 4 + r;
        int s2 = wn + j * 16 + (lane & 15);
        if (t < TT && s2 < TT) {
          int o = t * 100 + s2;
          S[o] = (S[o] + accQK[i][j][r]) * 0.125f;
        }
      }
  // V^T into Qs (Vt[d][t]); stale entries at t>=TT are multiplied by P==0.
  if (wnA == 96) {
    #pragma unroll
    for (int i = 0; i < 3; i++)
      #pragma unroll
      for (int j = 2; j < 6; j++) {
        int d = (wnA + j * 16 + (lane & 15)) - 128;
        float bias = bv[h * 64 + d];
        #pragma unroll
        for (int r = 0; r < 4; r++) {
          int t = wm + i * 16 + (lane >> 4) * 4 + r;
          if (t < TT) Qs[d * 96 + t] = f2b(accA[i][j][r] + bias);
        }
      }
  }
  __syncthreads();
  // ---- softmax rows; zero pads ----
  for (int t = wave; t < TT; t += 4) {
    float v0 = S[t * 100 + lane];
    float v1 = (lane + 64 < TT) ? S[t * 100 + lane + 64] : -3.0e38f;
    float mx = fmaxf(v0, v1);
    #pragma unroll
    for (int m = 1; m < 64; m <<= 1) mx = fmaxf(mx, __shfl_xor(mx, m, 64));
    float e0 = expf(v0 - mx);
    float e1 = (lane + 64 < TT) ? expf(v1 - mx) : 0.f;
    float sm = e0 + e1;
    #pragma unroll
    for (int m = 1; m < 64; m <<= 1) sm += __shfl_xor(sm, m, 64);
    float inv = 1.f / sm;
    S[t * 100 + lane] = e0 * inv;
    if (lane + 64 < 96) S[t * 100 + lane + 64] = (lane + 64 < TT) ? e1 * inv : 0.f;
  }
  for (int idx = tid; idx < 1000; idx += 256)
    S[(86 + idx / 100) * 100 + idx % 100] = 0.f;
  __syncthreads();
  // ---- PV ----
  {
    const int wn2 = (wave & 1) * 32;
    ffrag accO[3][2];
    #pragma unroll
    for (int i = 0; i < 3; i++)
      #pragma unroll
      for (int j = 0; j < 2; j++)
        #pragma unroll
        for (int e = 0; e < 4; e++) accO[i][j][e] = 0.f;
    #pragma unroll
    for (int ks = 0; ks < 3; ks++) {
      bfrag af[3], bf[2];
      #pragma unroll
      for (int i = 0; i < 3; i++) {
        const float* sp = &S[(wm + i * 16 + (lane & 15)) * 100 + ks * 32 + (lane >> 4) * 8];
        bfrag v;
        #pragma unroll
        for (int e = 0; e < 8; e++) v[e] = (short)f2b(sp[e]);
        af[i] = v;
      }
      #pragma unroll
      for (int j = 0; j < 2; j++)
        bf[j] = *(const bfrag*)&Qs[(wn2 + j * 16 + (lane & 15)) * 96 + ks * 32 + (lane >> 4) * 8];
      #pragma unroll
      for (int i = 0; i < 3; i++)
        #pragma unroll
        for (int j = 0; j < 2; j++)
          accO[i][j] = __builtin_amdgcn_mfma_f32_16x16x32_bf16(af[i], bf[j], accO[i][j], 0, 0, 0);
    }
    #pragma unroll
    for (int i = 0; i < 3; i++)
      #pragma unroll
      for (int j = 0; j < 2; j++)
        #pragma unroll
        for (int r = 0; r < 4; r++) {
          int t = wm + i * 16 + (lane >> 4) * 4 + r;
          int d = wn2 + j * 16 + (lane & 15);
          if (t < TT)
            Obb[((size_t)(b * TT + t)) * 512 + h * 64 + d] = f2b(accO[i][j][r]);
        }
  }
}

// ---------------- proj + residual + LN ----------------
__global__ __launch_bounds__(256) void k_projln(
    const u16* __restrict__ Obb, const u16* __restrict__ Wob,
    const float* __restrict__ bo, const float* __restrict__ lg,
    const float* __restrict__ lb, float* __restrict__ xtok, u16* __restrict__ hb)
{
  const int m0 = blockIdx.x * 16;
  const int tid = threadIdx.x, lane = tid & 63, wave = tid >> 6;
  __shared__ u16 Ast[16 * 64];
  __shared__ u16 Bst[256 * 64];
  __shared__ float rowbuf[16 * 256];
  const int wn = wave * 64;
  ffrag acc[4];
  #pragma unroll
  for (int j = 0; j < 4; j++)
    #pragma unroll
    for (int e = 0; e < 4; e++) acc[j][e] = 0.f;
  for (int kc = 0; kc < 8; kc++) {
    if (tid < 128) {
      int row = tid >> 3, sub = tid & 7;
      uint4 v = *(const uint4*)&Obb[(size_t)(m0 + row) * 512 + kc * 64 + sub * 8];
      *(uint4*)&Ast[row * 64 + ((sub ^ (row & 7)) << 3)] = v;
    }
    #pragma unroll
    for (int i = 0; i < 8; i++) {
      int u = tid + i * 256; int row = u >> 3, sub = u & 7;
      uint4 v = *(const uint4*)&Wob[(size_t)row * 512 + kc * 64 + sub * 8];
      *(uint4*)&Bst[row * 64 + ((sub ^ (row & 7)) << 3)] = v;
    }
    __syncthreads();
    #pragma unroll
    for (int ks = 0; ks < 2; ks++) {
      bfrag a = RD(Ast, lane & 15, ks);
      #pragma unroll
      for (int j = 0; j < 4; j++) {
        bfrag bj = RD(Bst, wn + j * 16 + (lane & 15), ks);
        acc[j] = __builtin_amdgcn_mfma_f32_16x16x32_bf16(a, bj, acc[j], 0, 0, 0);
      }
    }
    __syncthreads();
  }
  #pragma unroll
  for (int j = 0; j < 4; j++) {
    int c = wn + j * 16 + (lane & 15);
    #pragma unroll
    for (int r = 0; r < 4; r++) {
      int t = (lane >> 4) * 4 + r;
      rowbuf[t * 256 + c] = acc[j][r] + bo[c] + xtok[(size_t)(m0 + t) * 256 + c];
    }
  }
  __syncthreads();
  for (int row = wave; row < 16; row += 4) {
    float v0 = rowbuf[row * 256 + lane];
    float v1 = rowbuf[row * 256 + 64 + lane];
    float v2 = rowbuf[row * 256 + 128 + lane];
    float v3 = rowbuf[row * 256 + 192 + lane];
    float s = v0 + v1 + v2 + v3;
    float q = v0 * v0 + v1 * v1 + v2 * v2 + v3 * v3;
    #pragma unroll
    for (int m = 1; m < 64; m <<= 1) { s += __shfl_xor(s, m, 64); q += __shfl_xor(q, m, 64); }
    float mean = s * (1.f / 256.f);
    float var = fmaxf(q * (1.f / 256.f) - mean * mean, 0.f);
    float inv = 1.f / sqrtf(var + EPSV);
    size_t base = (size_t)(m0 + row) * 256;
    float vv[4] = {v0, v1, v2, v3};
    #pragma unroll
    for (int k = 0; k < 4; k++) {
      int c = lane + 64 * k;
      xtok[base + c] = vv[k];
      hb[base + c] = f2b((vv[k] - mean) * inv * lg[c] + lb[c]);
    }
  }
}

// ---------------- MLP1: h2 = gelu(h @ W1 + b1) ----------------
__global__ __launch_bounds__(256) void k_mlp1(
    const u16* __restrict__ hb, const u16* __restrict__ W1b,
    const float* __restrict__ b1, u16* __restrict__ h2b)
{
  const int m0 = blockIdx.x * 64, n0 = blockIdx.y * 128;
  const int tid = threadIdx.x, lane = tid & 63, wave = tid >> 6;
  __shared__ u16 Ast[64 * 64];
  __shared__ u16 Bst[128 * 64];
  const int wm = (wave >> 1) * 32, wn = (wave & 1) * 64;
  ffrag acc[2][4];
  #pragma unroll
  for (int i = 0; i < 2; i++)
    #pragma unroll
    for (int j = 0; j < 4; j++)
      #pragma unroll
      for (int e = 0; e < 4; e++) acc[i][j][e] = 0.f;
  for (int kc = 0; kc < 4; kc++) {
    #pragma unroll
    for (int i = 0; i < 2; i++) {
      int u = tid + i * 256; int row = u >> 3, sub = u & 7;
      int gm = m0 + row;
      uint4 v = make_uint4(0, 0, 0, 0);
      if (gm < 688) v = *(const uint4*)&hb[(size_t)gm * 256 + kc * 64 + sub * 8];
      *(uint4*)&Ast[row * 64 + ((sub ^ (row & 7)) << 3)] = v;
    }
    #pragma unroll
    for (int i = 0; i < 4; i++) {
      int u = tid + i * 256; int row = u >> 3, sub = u & 7;
      uint4 v = *(const uint4*)&W1b[(size_t)(n0 + row) * 256 + kc * 64 + sub * 8];
      *(uint4*)&Bst[row * 64 + ((sub ^ (row & 7)) << 3)] = v;
    }
    __syncthreads();
    #pragma unroll
    for (int ks = 0; ks < 2; ks++) {
      bfrag af[2], bf[4];
      #pragma unroll
      for (int i = 0; i < 2; i++) af[i] = RD(Ast, wm + i * 16 + (lane & 15), ks);
      #pragma unroll
      for (int j = 0; j < 4; j++) bf[j] = RD(Bst, wn + j * 16 + (lane & 15), ks);
      #pragma unroll
      for (int i = 0; i < 2; i++)
        #pragma unroll
        for (int j = 0; j < 4; j++)
          acc[i][j] = __builtin_amdgcn_mfma_f32_16x16x32_bf16(af[i], bf[j], acc[i][j], 0, 0, 0);
    }
    __syncthreads();
  }
  #pragma unroll
  for (int i = 0; i < 2; i++)
    #pragma unroll
    for (int j = 0; j < 4; j++) {
      int n = n0 + wn + j * 16 + (lane & 15);
      float bias = b1[n];
      #pragma unroll
      for (int r = 0; r < 4; r++) {
        int m = m0 + wm + i * 16 + (lane >> 4) * 4 + r;
        if (m < 688) {
          float v = acc[i][j][r] + bias;
          v = 0.5f * v * (1.f + erff(v * 0.7071067811865475f));
          h2b[(size_t)m * 1024 + n] = f2b(v);
        }
      }
    }
}

// ---------------- MLP2 + residual ----------------
__global__ __launch_bounds__(256) void k_mlp2(
    const u16* __restrict__ h2b, const u16* __restrict__ W2b,
    const float* __restrict__ b2, float* __restrict__ xtok, u16* __restrict__ xbf)
{
  const int m0 = blockIdx.x * 16;
  const int tid = threadIdx.x, lane = tid & 63, wave = tid >> 6;
  __shared__ u16 Ast[16 * 64];
  __shared__ u16 Bst[256 * 64];
  const int wn = wave * 64;
  ffrag acc[4];
  #pragma unroll
  for (int j = 0; j < 4; j++)
    #pragma unroll
    for (int e = 0; e < 4; e++) acc[j][e] = 0.f;
  for (int kc = 0; kc < 16; kc++) {
    if (tid < 128) {
      int row = tid >> 3, sub = tid & 7;
      uint4 v = *(const uint4*)&h2b[(size_t)(m0 + row) * 1024 + kc * 64 + sub * 8];
      *(uint4*)&Ast[row * 64 + ((sub ^ (row & 7)) << 3)] = v;
    }
    #pragma unroll
    for (int i = 0; i < 8; i++) {
      int u = tid + i * 256; int row = u >> 3, sub = u & 7;
      uint4 v = *(const uint4*)&W2b[(size_t)row * 1024 + kc * 64 + sub * 8];
      *(uint4*)&Bst[row * 64 + ((sub ^ (row & 7)) << 3)] = v;
    }
    __syncthreads();
    #pragma unroll
    for (int ks = 0; ks < 2; ks++) {
      bfrag a = RD(Ast, lane & 15, ks);
      #pragma unroll
      for (int j = 0; j < 4; j++) {
        bfrag bj = RD(Bst, wn + j * 16 + (lane & 15), ks);
        acc[j] = __builtin_amdgcn_mfma_f32_16x16x32_bf16(a, bj, acc[j], 0, 0, 0);
      }
    }
    __syncthreads();
  }
  #pragma unroll
  for (int j = 0; j < 4; j++) {
    int c = wn + j * 16 + (lane & 15);
    float bias = b2[c];
    #pragma unroll
    for (int r = 0; r < 4; r++) {
      int t = (lane >> 4) * 4 + r;
      size_t o = (size_t)(m0 + t) * 256 + c;
      float v = acc[j][r] + bias + xtok[o];
      xtok[o] = v;
      xbf[o] = f2b(v);
    }
  }
}

// ---------------- final LN(cls) @ Wh + bh ----------------
__global__ __launch_bounds__(256) void k_head(const float* __restrict__ x,
    const float* __restrict__ g, const float* __restrict__ bb,
    const float* __restrict__ Wh, const float* __restrict__ bh, float* __restrict__ out)
{
  int bidx = blockIdx.x >> 2, nc = blockIdx.x & 3;
  int tid = threadIdx.x;
  const float* xr = x + (size_t)bidx * TT * 256;
  float v = xr[tid];
  float s = v, q = v * v;
  #pragma unroll
  for (int m = 1; m < 64; m <<= 1) { s += __shfl_xor(s, m, 64); q += __shfl_xor(q, m, 64); }
  __shared__ float ps[4], pq[4];
  __shared__ float h[256];
  if ((tid & 63) == 0) { ps[tid >> 6] = s; pq[tid >> 6] = q; }
  __syncthreads();
  float S = ps[0] + ps[1] + ps[2] + ps[3];
  float Q = pq[0] + pq[1] + pq[2] + pq[3];
  float mean = S * (1.f / 256.f);
  float var = fmaxf(Q * (1.f / 256.f) - mean * mean, 0.f);
  float inv = 1.f / sqrtf(var + EPSV);
  h[tid] = (v - mean) * inv * g[tid] + bb[tid];
  __syncthreads();
  int n = nc * 256 + tid;
  if (n < 1000) {
    float acc = bh[n];
    for (int k = 0; k < 256; k++) acc += h[k] * Wh[(size_t)k * 1000 + n];
    out[bidx * 1000 + n] = acc;
  }
}

extern "C" void kernel_launch(void* const* d_in, const int* in_sizes, int n_in,
                              void* d_out, int out_size, void* d_ws, size_t ws_size,
                              hipStream_t stream)
{
  (void)in_sizes; (void)n_in; (void)out_size;
  const float* img     = (const float*)d_in[0];
  const float* conv1_w = (const float*)d_in[1];
  const float* bn1_g   = (const float*)d_in[3];
  const float* bn1_b   = (const float*)d_in[4];
  const float* conv2_w = (const float*)d_in[5];
  const float* bn2_g   = (const float*)d_in[7];
  const float* bn2_b   = (const float*)d_in[8];
  const float* conv3_w = (const float*)d_in[9];
  const float* bn3_g   = (const float*)d_in[11];
  const float* bn3_b   = (const float*)d_in[12];
  const float* cls     = (const float*)d_in[13];
  const float* Wq      = (const float*)d_in[14];
  const float* bq      = (const float*)d_in[15];
  const float* Wk      = (const float*)d_in[16];
  const float* bk      = (const float*)d_in[17];
  const float* Wv      = (const float*)d_in[18];
  const float* bv      = (const float*)d_in[19];
  const float* rel     = (const float*)d_in[20];
  const float* Wo      = (const float*)d_in[21];
  const float* bo      = (const float*)d_in[22];
  const float* ln_g    = (const float*)d_in[23];
  const float* ln_b    = (const float*)d_in[24];
  const float* W1      = (const float*)d_in[25];
  const float* b1      = (const float*)d_in[26];
  const float* W2      = (const float*)d_in[27];
  const float* b2      = (const float*)d_in[28];
  const float* hln_g   = (const float*)d_in[29];
  const float* hln_b   = (const float*)d_in[30];
  const float* Wh      = (const float*)d_in[31];
  const float* bhp     = (const float*)d_in[32];

  char* base = (char*)d_ws;
  size_t off = 0;
  auto alloc = [&](size_t bytes) -> void* {
    void* p = base + off;
    off = (off + bytes + 255) & ~(size_t)255;
    return p;
  };
  // ---- region A: small persistent ----
  u16* wr2 = (u16*)alloc((size_t)64 * 288 * 2);
  u16* wr3 = (u16*)alloc((size_t)256 * 576 * 2);
  float* stats = (float*)alloc(5696 * 4);
  float* st1 = stats;
  float* st2 = stats + 512;
  float* st3 = stats + 1536;
  u16* zbuf = (u16*)(stats + 5632);
  float* scsh = (float*)alloc(704 * 4);   // kept for layout stability (unused)
  (void)scsh;
  float* grid8 = (float*)alloc((size_t)8 * 64 * 256 * 4);
  float* xtok  = (float*)alloc((size_t)688 * 256 * 4);
  u16* xbf   = (u16*)alloc((size_t)688 * 256 * 2);
  u16* hbb   = (u16*)alloc((size_t)688 * 256 * 2);
  u16* Obb   = (u16*)alloc((size_t)688 * 512 * 2);
  u16* h2b   = (u16*)alloc((size_t)688 * 1024 * 2);
  u16* relbuf= (u16*)alloc((size_t)6 * 8 * TT * 64 * 2);
  // ---- region B: X2 ----
  u16* X2  = (u16*)alloc((size_t)MTOT * 64 * 2);
  // ---- region C: X1 | X3 (or X3c) | transformer weights (lifetimes disjoint)
  size_t offC = off;
  const size_t sizeX1  = (size_t)MTOT * 32 * 2;
  const size_t sizeX3  = (size_t)MTOT * 256 * 2;
  const size_t sizeX3c = (size_t)8 * BAND * 256 * 2;
  const size_t sizeW   = (size_t)(2359296 + 786432 + 1572864 + 1572864) * 2;
  size_t cT = sizeX1 > sizeX3c ? sizeX1 : sizeX3c;
  if (cT < sizeW) cT = sizeW;
  const size_t needS = offC + sizeX3;
  const size_t needT = offC + cT;
  const bool planS = ws_size >= needS;
  u16* X1    = (u16*)(base + offC);
  u16* X3    = (u16*)(base + offC);
  u16* X3c   = (u16*)(base + offC);
  u16* Wqkvb = (u16*)(base + offC);                  // written AFTER pool (X3 dead)
  u16* Wob   = Wqkvb + (size_t)2359296;
  u16* W1b   = Wob   + (size_t)786432;
  u16* W2b   = W1b   + (size_t)1572864;
  if (ws_size < needT)
    fprintf(stderr, "ATHENA-HIP: ws too small, need %zu have %zu\n", needT, ws_size);

  // prep: wreord2 + wreord3 + zero stats (one kernel)
  k_prep0<<<671, 256, 0, stream>>>(conv2_w, conv3_w, wr2, wr3, stats);

  // conv stem
  k_conv1<<<1568, 256, 0, stream>>>(img, conv1_w, X1, st1);
  k_norm<32><<<6272, 256, 0, stream>>>(X1, st1, bn1_g, bn1_b);
  k_convhalo<32, 64, 64, 1, 16, 16, 1, 1><<<1568, 256, 0, stream>>>(
      X1, wr2, X2, zbuf, st2);
  k_norm<64><<<12544, 256, 0, stream>>>(X2, st2, bn2_g, bn2_b);
  if (planS) {
    k_convhalo<64, 256, 128, 2, 8, 16, 1, 1><<<6272, 256, 0, stream>>>(
        X2, wr3, X3, zbuf, st3);
    k_pool2<0><<<512, 256, 0, stream>>>(X3, st3, bn3_g, bn3_b, grid8, 0);
  } else {
    k_convhalo<64, 256, 128, 2, 8, 16, 1, 0><<<6272, 256, 0, stream>>>(
        X2, wr3, X3c, zbuf, st3);
    for (int cy = 0; cy < 8; cy++) {
      k_convgemm<64, 256, 128, 128, 2, 0, 1, 1><<<784, 256, 0, stream>>>(
          X2, wr3, X3c, zbuf, st3, cy);
      k_pool2<1><<<64, 256, 0, stream>>>(X3c, st3, bn3_g, bn3_b, grid8, cy);
    }
  }
  k_tokens<<<688, 256, 0, stream>>>(grid8, cls, xtok, xbf);

  // weight prep AFTER pool (region C reuse, X3 dead): one merged kernel
  k_transall<<<2568, 256, 0, stream>>>(Wq, Wk, Wv, Wo, W1, W2, rel,
                                       Wqkvb, Wob, W1b, W2b, relbuf);

  // transformer
  for (int l = 0; l < 6; l++) {
    k_qkvattn<<<64, 256, 0, stream>>>(
        xbf, Wqkvb + (size_t)l * 8 * 3 * 64 * 256,
        relbuf + (size_t)l * 8 * TT * 64,
        bq + l * 512, bk + l * 512, bv + l * 512, zbuf, Obb);
    k_projln<<<43, 256, 0, stream>>>(
        Obb, Wob + (size_t)l * 131072, bo + l * 256,
        ln_g + l * 256, ln_b + l * 256, xtok, hbb);
    k_mlp1<<<dim3(11, 8), 256, 0, stream>>>(
        hbb, W1b + (size_t)l * 262144, b1 + l * 1024, h2b);
    k_mlp2<<<43, 256, 0, stream>>>(
        h2b, W2b + (size_t)l * 262144, b2 + l * 256, xtok, xbf);
  }
  k_head<<<32, 256, 0, stream>>>(xtok, hln_g, hln_b, Wh, bhp, (float*)d_out);
}